// Round 13
// baseline (793.328 us; speedup 1.0000x reference)
//
#include <hip/hip_runtime.h>
#include <math.h>

#define NATOMS 16384
#define NEDGES 524288
#define NLAYERS 4
#define TE 128     // edges per block in msg kernel

typedef __bf16 bf16x8 __attribute__((ext_vector_type(8)));
typedef __bf16 bf16x4 __attribute__((ext_vector_type(4)));
typedef __bf16 bf16x2 __attribute__((ext_vector_type(2)));
typedef float f32x4 __attribute__((ext_vector_type(4)));

// fast silu: x * rcp(1+exp(-x))
__device__ __forceinline__ float silu_f(float x) {
  return x * __builtin_amdgcn_rcpf(1.0f + __expf(-x));
}

// ---------------- CSR preprocessing ----------------
__global__ __launch_bounds__(256) void hist_kernel(
    const int* __restrict__ dst, int* __restrict__ counts)
{
  int e = blockIdx.x * 256 + threadIdx.x;
  atomicAdd(&counts[dst[e]], 1);
}

__global__ __launch_bounds__(1024) void scan_kernel(
    const int* __restrict__ counts, int* __restrict__ cursor,
    float* __restrict__ degf)
{
  __shared__ int s_tot[1024];
  int tid = threadIdx.x;
  int v[16];
  {
    const int4* cp = (const int4*)(counts + tid * 16);
    int4 a = cp[0], b = cp[1], c = cp[2], d = cp[3];
    v[0]=a.x; v[1]=a.y; v[2]=a.z; v[3]=a.w;
    v[4]=b.x; v[5]=b.y; v[6]=b.z; v[7]=b.w;
    v[8]=c.x; v[9]=c.y; v[10]=c.z; v[11]=c.w;
    v[12]=d.x; v[13]=d.y; v[14]=d.z; v[15]=d.w;
  }
  int tot = 0;
  #pragma unroll
  for (int i = 0; i < 16; i++) tot += v[i];
  s_tot[tid] = tot;
  __syncthreads();
  for (int off = 1; off < 1024; off <<= 1) {
    int t = (tid >= off) ? s_tot[tid - off] : 0;
    __syncthreads();
    s_tot[tid] += t;
    __syncthreads();
  }
  int run = s_tot[tid] - tot;   // exclusive prefix
  #pragma unroll
  for (int i = 0; i < 16; i++) {
    cursor[tid * 16 + i] = run;
    degf[tid * 16 + i] = (float)v[i];
    run += v[i];
  }
}

__global__ __launch_bounds__(256) void scatter_kernel(
    const int* __restrict__ src, const int* __restrict__ dst,
    int* __restrict__ cursor, int* __restrict__ esrc, int* __restrict__ edst)
{
  int e = blockIdx.x * 256 + threadIdx.x;
  int d = dst[e];
  int p = atomicAdd(&cursor[d], 1);
  esrc[p] = src[e];
  edst[p] = d;
}

// ---------------- merged weight prep ----------------
__global__ __launch_bounds__(256) void prep_kernel(
    const float* __restrict__ mW1, const float* __restrict__ mW2,
    const float* __restrict__ uW1, const float* __restrict__ uW2,
    const float* __restrict__ mb2,
    __bf16* __restrict__ W1at, __bf16* __restrict__ W1bt,
    __bf16* __restrict__ B2c, __bf16* __restrict__ uW1ft,
    __bf16* __restrict__ uW2t, float* __restrict__ b2u)
{
  long l = blockIdx.y;
  int bx = blockIdx.x, tid = threadIdx.x;
  if (bx < 128) {
    int i = bx * 256 + tid;              // 256*128
    int n = i >> 7, k = i & 127;
    W1at[l * (256L * 128) + i] = (__bf16)mW1[l * (272L * 256) + (size_t)k * 256 + n];
  } else if (bx < 256) {
    int i = (bx - 128) * 256 + tid;
    int n = i >> 7, k = i & 127;
    W1bt[l * (256L * 128) + i] = (__bf16)mW1[l * (272L * 256) + (size_t)(128 + k) * 256 + n];
  } else if (bx < 288) {
    int i = (bx - 256) * 256 + tid;      // 256*32
    int c = i >> 5, k = i & 31;
    float v = (k < 16) ? mW1[l * (272L * 256) + (size_t)(256 + k) * 256 + c] : 0.0f;
    B2c[l * (256L * 32) + i] = (__bf16)v;
  } else if (bx < 672) {
    int i = (bx - 288) * 256 + tid;      // 256*384
    int n = i / 384, k = i - n * 384;
    float v;
    if (k < 128) {
      v = uW1[l * 65536 + (size_t)k * 256 + n];
    } else {
      int r = k - 128;
      v = 0.0f;
      for (int j = 0; j < 128; j++)
        v += mW2[(l * 256 + r) * 128 + j] * uW1[l * 65536 + (size_t)(128 + j) * 256 + n];
    }
    uW1ft[l * (256L * 384) + i] = (__bf16)v;
  } else if (bx < 800) {
    int i = (bx - 672) * 256 + tid;      // 128*256
    int n = i >> 8, k = i & 255;
    uW2t[l * (128L * 256) + i] = (__bf16)uW2[l * (256L * 128) + (size_t)k * 128 + n];
  } else {
    int c = tid;
    float acc = 0.0f;
    for (int j = 0; j < 128; j++)
      acc += mb2[l * 128 + j] * uW1[l * 65536 + (size_t)(128 + j) * 256 + c];
    b2u[l * 256 + c] = acc;
  }
}

// ---------------- edge RBF (sorted slot order) ----------------
__global__ __launch_bounds__(256) void rbf_kernel(
    const float* __restrict__ pos, const int* __restrict__ esrc,
    const int* __restrict__ edst, __bf16* __restrict__ efb)
{
  int e = blockIdx.x * 256 + threadIdx.x;
  int s = esrc[e], d = edst[e];
  float dx = pos[d * 3 + 0] - pos[s * 3 + 0];
  float dy = pos[d * 3 + 1] - pos[s * 3 + 1];
  float dz = pos[d * 3 + 2] - pos[s * 3 + 2];
  float dist = sqrtf(dx * dx + dy * dy + dz * dz + 1e-12f);
  float env = (dist < 10.0f)
                  ? 0.5f * (cosf(3.14159265358979f * dist * 0.1f) + 1.0f)
                  : 0.0f;
  bf16x8 o0, o1;
  #pragma unroll
  for (int i = 0; i < 16; i++) {
    float c = (10.0f / 15.0f) * (float)i;
    float t = dist - c;
    float v = env * __expf(-t * t * 1.28f);
    if (i < 8) o0[i] = (__bf16)v; else o1[i - 8] = (__bf16)v;
  }
  *(bf16x8*)(efb + (size_t)e * 16 + 0) = o0;
  *(bf16x8*)(efb + (size_t)e * 16 + 8) = o1;
}

// ---------------- fused embed + layer-0 zprep (64 nodes/block) ----------------
__global__ __launch_bounds__(256) void embed_zprep_kernel(
    const float* __restrict__ x, const float* __restrict__ eW1,
    const float* __restrict__ eb1, const float* __restrict__ eW2,
    const float* __restrict__ eb2, const float* __restrict__ b1,
    const __bf16* __restrict__ W1at, const __bf16* __restrict__ W1bt,
    float* __restrict__ h, __bf16* __restrict__ hb,
    __bf16* __restrict__ z1b, __bf16* __restrict__ z2b,
    float* __restrict__ aggH)
{
  __shared__ float s_x[64][28];
  __shared__ float s_hid[64][132];
  __shared__ __bf16 s_n[64][136];
  int tid = threadIdx.x, n0 = blockIdx.x * 64;
  for (int i = tid; i < 64 * 26; i += 256) {
    int n = i / 26, c = i - n * 26;
    s_x[n][c] = x[(size_t)(n0 + n) * 26 + c];
  }
  {
    float4 zz = make_float4(0.f, 0.f, 0.f, 0.f);
    float4* ap = (float4*)(aggH + (size_t)n0 * 256);
    for (int i = tid; i < 64 * 256 / 4; i += 256) ap[i] = zz;
  }
  __syncthreads();
  {
    int n = tid >> 2, j0 = (tid & 3) * 32;
    float acc[32];
    #pragma unroll
    for (int jj = 0; jj < 32; jj++) acc[jj] = eb1[j0 + jj];
    for (int k = 0; k < 26; k++) {
      float xv = s_x[n][k];
      #pragma unroll
      for (int jj = 0; jj < 32; jj++)
        acc[jj] += xv * eW1[k * 128 + j0 + jj];
    }
    #pragma unroll
    for (int jj = 0; jj < 32; jj++) s_hid[n][j0 + jj] = silu_f(acc[jj]);
    __syncthreads();
    #pragma unroll
    for (int jj = 0; jj < 32; jj++) acc[jj] = eb2[j0 + jj];
    for (int k = 0; k < 128; k++) {
      float hv = s_hid[n][k];
      #pragma unroll
      for (int jj = 0; jj < 32; jj++)
        acc[jj] += hv * eW2[k * 128 + j0 + jj];
    }
    #pragma unroll
    for (int jj = 0; jj < 32; jj++) {
      float v = acc[jj];
      h[(size_t)(n0 + n) * 128 + j0 + jj] = v;
      hb[(size_t)(n0 + n) * 128 + j0 + jj] = (__bf16)v;
      s_n[n][j0 + jj] = (__bf16)v;
    }
  }
  __syncthreads();

  const int wv = tid >> 6, ln = tid & 63, lc = ln & 15, qd = ln >> 4;
  for (int cp = 0; cp < 2; cp++) {
    f32x4 aA[4][2], aB[4][2];
    #pragma unroll
    for (int nt = 0; nt < 2; nt++) {
      float bv = b1[cp * 128 + wv * 32 + nt * 16 + lc];
      #pragma unroll
      for (int mt = 0; mt < 4; mt++) {
        aA[mt][nt][0] = 0.f; aA[mt][nt][1] = 0.f;
        aA[mt][nt][2] = 0.f; aA[mt][nt][3] = 0.f;
        aB[mt][nt][0] = bv; aB[mt][nt][1] = bv;
        aB[mt][nt][2] = bv; aB[mt][nt][3] = bv;
      }
    }
    #pragma unroll
    for (int kt = 0; kt < 4; kt++) {
      bf16x8 af[4];
      #pragma unroll
      for (int mt = 0; mt < 4; mt++)
        af[mt] = *(const bf16x8*)&s_n[mt * 16 + lc][kt * 32 + qd * 8];
      bf16x8 bwA[2], bwB[2];
      #pragma unroll
      for (int nt = 0; nt < 2; nt++) {
        int c = cp * 128 + wv * 32 + nt * 16 + lc;
        bwA[nt] = *(const bf16x8*)(W1at + (size_t)c * 128 + kt * 32 + qd * 8);
        bwB[nt] = *(const bf16x8*)(W1bt + (size_t)c * 128 + kt * 32 + qd * 8);
      }
      #pragma unroll
      for (int mt = 0; mt < 4; mt++)
        #pragma unroll
        for (int nt = 0; nt < 2; nt++) {
          aA[mt][nt] = __builtin_amdgcn_mfma_f32_16x16x32_bf16(af[mt], bwA[nt], aA[mt][nt], 0, 0, 0);
          aB[mt][nt] = __builtin_amdgcn_mfma_f32_16x16x32_bf16(af[mt], bwB[nt], aB[mt][nt], 0, 0, 0);
        }
    }
    #pragma unroll
    for (int mt = 0; mt < 4; mt++)
      #pragma unroll
      for (int nt = 0; nt < 2; nt++) {
        int c = cp * 128 + wv * 32 + nt * 16 + lc;
        #pragma unroll
        for (int r = 0; r < 4; r++) {
          int n = n0 + mt * 16 + qd * 4 + r;
          z1b[(size_t)n * 256 + c] = (__bf16)aA[mt][nt][r];
          z2b[(size_t)n * 256 + c] = (__bf16)aB[mt][nt][r];
        }
      }
  }
}

// ---------------- fused message kernel v8: TE=128, 512 threads, 2 blocks/CU ----------------
// s_hT: bf16 [256 cols][130] (65-dword stride). One barrier; scan = 512 threads x
// (col, 64-row half) with 128-bit boundary mask in SGPRs.
#define MS_EF_OFF   66560                 // s_hT 256*130*2 = 66560
#define MS_SRC_OFF  72704                 // s_ef 128*24*2 = 6144
#define MS_DST_OFF  73216
#define MS_MASK_OFF 73728
#define MS_BYTES    73744

__global__ __launch_bounds__(512, 2) void msg_mfma_kernel(
    const __bf16* __restrict__ z1b, const __bf16* __restrict__ z2b,
    const __bf16* __restrict__ efb,
    const int* __restrict__ esrc, const int* __restrict__ edst,
    const __bf16* __restrict__ B2c, float* __restrict__ aggH)
{
  __shared__ __align__(16) char smem[MS_BYTES];
  __bf16 (*s_hT)[130] = (__bf16(*)[130])(smem);        // [256 cols][128 rows + 2 pad]
  __bf16 (*s_ef)[24] = (__bf16(*)[24])(smem + MS_EF_OFF);
  int* s_src = (int*)(smem + MS_SRC_OFF);
  int* s_dst = (int*)(smem + MS_DST_OFF);
  unsigned int* s_mask = (unsigned int*)(smem + MS_MASK_OFF);

  int tid = threadIdx.x, e0 = blockIdx.x * TE;

  if (tid < TE) {
    int d = edst[e0 + tid];
    s_dst[tid] = d;
    int dp = (tid == 0) ? (d ^ 1) : edst[e0 + tid - 1];
    unsigned long long mb = __ballot(d != dp);
    if ((tid & 63) == 0) {
      int w = (tid >> 6) * 2;
      s_mask[w] = (unsigned int)mb;
      s_mask[w + 1] = (unsigned int)(mb >> 32);
    }
  } else if (tid < 2 * TE) {
    s_src[tid - TE] = esrc[e0 + tid - TE];
  }
  {
    int e = tid >> 2, t4 = tid & 3;
    if (t4 < 2)
      *(bf16x8*)&s_ef[e][t4 * 8] =
          *(const bf16x8*)(efb + (size_t)(e0 + e) * 16 + t4 * 8);
  }
  __syncthreads();

  const int wv = tid >> 6, ln = tid & 63, lc = ln & 15, qd = ln >> 4;

  bf16x8 bI;
  #pragma unroll
  for (int j = 0; j < 8; j++)
    bI[j] = (__bf16)((lc == (qd & 1) * 8 + j) ? 1.0f : 0.0f);

  const __bf16* pz[8];
  #pragma unroll
  for (int mt = 0; mt < 8; mt++) {
    int m = mt * 16 + lc;
    int row = (qd < 2) ? s_src[m] : s_dst[m];
    pz[mt] = ((qd < 2) ? z1b : z2b) + (size_t)row * 256 + (qd & 1) * 8;
  }

  // ---- wave wv owns cols cb..cb+31 (8 waves cover all 256), 8 M-tiles ----
  const int cb = wv * 32;
  bf16x8 bw[2];
  #pragma unroll
  for (int nt = 0; nt < 2; nt++)
    bw[nt] = *(const bf16x8*)(B2c + (size_t)(cb + nt * 16 + lc) * 32 + qd * 8);

  #pragma unroll
  for (int mt = 0; mt < 8; mt++) {
    bf16x8 aef = *(const bf16x8*)&s_ef[mt * 16 + lc][(qd & 1) * 8];
    #pragma unroll
    for (int nt = 0; nt < 2; nt++) {
      bf16x8 az = *(const bf16x8*)(pz[mt] + cb + nt * 16);
      f32x4 z; z[0] = 0.f; z[1] = 0.f; z[2] = 0.f; z[3] = 0.f;
      f32x4 acc = __builtin_amdgcn_mfma_f32_16x16x32_bf16(az, bI, z, 0, 0, 0);
      acc = __builtin_amdgcn_mfma_f32_16x16x32_bf16(aef, bw[nt], acc, 0, 0, 0);
      bf16x2 p0, p1;
      p0[0] = (__bf16)silu_f(acc[0]); p0[1] = (__bf16)silu_f(acc[1]);
      p1[0] = (__bf16)silu_f(acc[2]); p1[1] = (__bf16)silu_f(acc[3]);
      __bf16* wp = &s_hT[cb + nt * 16 + lc][mt * 16 + qd * 4];
      *(bf16x2*)wp = p0;
      *(bf16x2*)(wp + 2) = p1;
    }
  }
  __syncthreads();

  // ---- scan: 512 threads = 256 cols x 2 row-halves ----
  {
    int col = tid & 255, half = tid >> 8, r0 = half * 64;
    const unsigned int mlo = __builtin_amdgcn_readfirstlane(s_mask[half * 2]);
    const unsigned int mhi = __builtin_amdgcn_readfirstlane(s_mask[half * 2 + 1]);
    float acc = 0.0f;
    int cur = s_dst[r0];
    #pragma unroll 8
    for (int i = 0; i < 64; i += 2) {
      bf16x2 p = *(const bf16x2*)&s_hT[col][r0 + i];
      bool b0 = (i < 32) ? ((mlo >> i) & 1u) : ((mhi >> (i - 32)) & 1u);
      int i1 = i + 1;
      bool b1 = (i1 < 32) ? ((mlo >> i1) & 1u) : ((mhi >> (i1 - 32)) & 1u);
      if (i > 0 && b0) {
        atomicAdd(&aggH[(size_t)cur * 256 + col], acc);
        acc = 0.0f; cur = s_dst[r0 + i];
      }
      acc += (float)p[0];
      if (b1) {
        atomicAdd(&aggH[(size_t)cur * 256 + col], acc);
        acc = 0.0f; cur = s_dst[r0 + i1];
      }
      acc += (float)p[1];
    }
    atomicAdd(&aggH[(size_t)cur * 256 + col], acc);
  }
}

// ---------------- fused node update MLP v4: 512 threads, 64 nodes + next-layer zprep ----------------
__global__ __launch_bounds__(512, 2) void upd_mfma_kernel(
    float* __restrict__ h, __bf16* __restrict__ hb,
    float* __restrict__ aggH, const float* __restrict__ degf,
    const __bf16* __restrict__ uW1ft, const float* __restrict__ b1,
    const float* __restrict__ b2u,
    const __bf16* __restrict__ uW2t, const float* __restrict__ b2,
    int do_z, const float* __restrict__ nb1,
    const __bf16* __restrict__ nW1at, const __bf16* __restrict__ nW1bt,
    __bf16* __restrict__ z1b, __bf16* __restrict__ z2b)
{
  __shared__ __bf16 s_u[64][392];    // [h(128) | agg(256)] + 8 pad
  __shared__ __bf16 s_uh[64][264];   // 256 hidden cols + 8 pad
  int tid = threadIdx.x, n0 = blockIdx.x * 64;
  {
    int n = tid >> 3, t8 = tid & 7;  // 8 threads per node
    const bf16x8* hr = (const bf16x8*)(hb + (size_t)(n0 + n) * 128);
    #pragma unroll
    for (int i = 0; i < 2; i++)
      *(bf16x8*)&s_u[n][t8 * 8 + 64 * i] = hr[t8 + 8 * i];
    const float* sr = aggH + (size_t)(n0 + n) * 256;
    #pragma unroll
    for (int i = 0; i < 4; i++) {
      int col = t8 * 8 + i * 64;
      float4 a = *(const float4*)(sr + col);
      float4 b = *(const float4*)(sr + col + 4);
      bf16x8 o;
      o[0] = (__bf16)a.x; o[1] = (__bf16)a.y; o[2] = (__bf16)a.z; o[3] = (__bf16)a.w;
      o[4] = (__bf16)b.x; o[5] = (__bf16)b.y; o[6] = (__bf16)b.z; o[7] = (__bf16)b.w;
      *(bf16x8*)&s_u[n][128 + col] = o;
    }
  }
  __syncthreads();
  const int wv = tid >> 6, ln = tid & 63, lc = ln & 15, qd = ln >> 4;  // wv 0..7

  float dg[4][4];
  #pragma unroll
  for (int mt = 0; mt < 4; mt++)
    #pragma unroll
    for (int r = 0; r < 4; r++)
      dg[mt][r] = degf[n0 + mt * 16 + qd * 4 + r];

  // ---- GEMM1: K=384, wave owns cols wv*32 + nt*16 + lc ----
  {
    f32x4 acc1[4][2];
    #pragma unroll
    for (int nt = 0; nt < 2; nt++) {
      int c = wv * 32 + nt * 16 + lc;
      float bv = b1[c];
      float b2uv = b2u[c];
      #pragma unroll
      for (int mt = 0; mt < 4; mt++)
        #pragma unroll
        for (int r = 0; r < 4; r++)
          acc1[mt][nt][r] = bv + dg[mt][r] * b2uv;
    }
    #pragma unroll
    for (int kt = 0; kt < 12; kt++) {
      bf16x8 af[4];
      #pragma unroll
      for (int mt = 0; mt < 4; mt++)
        af[mt] = *(const bf16x8*)&s_u[mt * 16 + lc][kt * 32 + qd * 8];
      bf16x8 bw[2];
      #pragma unroll
      for (int nt = 0; nt < 2; nt++)
        bw[nt] = *(const bf16x8*)(uW1ft +
                 (size_t)(wv * 32 + nt * 16 + lc) * 384 + kt * 32 + qd * 8);
      #pragma unroll
      for (int mt = 0; mt < 4; mt++)
        #pragma unroll
        for (int nt = 0; nt < 2; nt++)
          acc1[mt][nt] = __builtin_amdgcn_mfma_f32_16x16x32_bf16(af[mt], bw[nt], acc1[mt][nt], 0, 0, 0);
    }
    #pragma unroll
    for (int mt = 0; mt < 4; mt++)
      #pragma unroll
      for (int nt = 0; nt < 2; nt++) {
        int cc = wv * 32 + nt * 16 + lc;
        #pragma unroll
        for (int r = 0; r < 4; r++)
          s_uh[mt * 16 + qd * 4 + r][cc] = (__bf16)silu_f(acc1[mt][nt][r]);
      }
  }
  __syncthreads();

  // ---- GEMM2: K=256, wave owns output cols ow = wv*16 + lc ----
  const int ow = wv * 16 + lc;
  f32x4 acc2[4];
  {
    float bv = b2[ow];
    #pragma unroll
    for (int mt = 0; mt < 4; mt++) {
      acc2[mt][0] = bv; acc2[mt][1] = bv; acc2[mt][2] = bv; acc2[mt][3] = bv;
    }
  }
  #pragma unroll
  for (int kt = 0; kt < 8; kt++) {
    bf16x8 a2[4];
    #pragma unroll
    for (int mt = 0; mt < 4; mt++)
      a2[mt] = *(const bf16x8*)&s_uh[mt * 16 + lc][kt * 32 + qd * 8];
    bf16x8 b2w = *(const bf16x8*)(uW2t + (size_t)ow * 256 + kt * 32 + qd * 8);
    #pragma unroll
    for (int mt = 0; mt < 4; mt++)
      acc2[mt] = __builtin_amdgcn_mfma_f32_16x16x32_bf16(a2[mt], b2w, acc2[mt], 0, 0, 0);
  }

  // residual epilogue
  #pragma unroll
  for (int mt = 0; mt < 4; mt++)
    #pragma unroll
    for (int r = 0; r < 4; r++) {
      int n = n0 + mt * 16 + qd * 4 + r;
      float v = h[(size_t)n * 128 + ow] + acc2[mt][r];
      h[(size_t)n * 128 + ow] = v;
      hb[(size_t)n * 128 + ow] = (__bf16)v;
    }

  // ---- fused zprep for next layer ----
  if (do_z) {
    __syncthreads();
    {
      float4 zz = make_float4(0.f, 0.f, 0.f, 0.f);
      float4* ap = (float4*)(aggH + (size_t)n0 * 256);
      for (int i = tid; i < 64 * 256 / 4; i += 512) ap[i] = zz;
      int n = tid >> 3, t8 = tid & 7;
      const bf16x8* hr = (const bf16x8*)(hb + (size_t)(n0 + n) * 128);
      #pragma unroll
      for (int i = 0; i < 2; i++)
        *(bf16x8*)&s_u[n][t8 * 8 + 64 * i] = hr[t8 + 8 * i];
    }
    __syncthreads();
    f32x4 aA[4][2], aB[4][2];
    #pragma unroll
    for (int nt = 0; nt < 2; nt++) {
      float bv = nb1[wv * 32 + nt * 16 + lc];
      #pragma unroll
      for (int mt = 0; mt < 4; mt++) {
        aA[mt][nt][0] = 0.f; aA[mt][nt][1] = 0.f;
        aA[mt][nt][2] = 0.f; aA[mt][nt][3] = 0.f;
        aB[mt][nt][0] = bv; aB[mt][nt][1] = bv;
        aB[mt][nt][2] = bv; aB[mt][nt][3] = bv;
      }
    }
    #pragma unroll
    for (int kt = 0; kt < 4; kt++) {
      bf16x8 af[4];
      #pragma unroll
      for (int mt = 0; mt < 4; mt++)
        af[mt] = *(const bf16x8*)&s_u[mt * 16 + lc][kt * 32 + qd * 8];
      bf16x8 bwA[2], bwB[2];
      #pragma unroll
      for (int nt = 0; nt < 2; nt++) {
        int c = wv * 32 + nt * 16 + lc;
        bwA[nt] = *(const bf16x8*)(nW1at + (size_t)c * 128 + kt * 32 + qd * 8);
        bwB[nt] = *(const bf16x8*)(nW1bt + (size_t)c * 128 + kt * 32 + qd * 8);
      }
      #pragma unroll
      for (int mt = 0; mt < 4; mt++)
        #pragma unroll
        for (int nt = 0; nt < 2; nt++) {
          aA[mt][nt] = __builtin_amdgcn_mfma_f32_16x16x32_bf16(af[mt], bwA[nt], aA[mt][nt], 0, 0, 0);
          aB[mt][nt] = __builtin_amdgcn_mfma_f32_16x16x32_bf16(af[mt], bwB[nt], aB[mt][nt], 0, 0, 0);
        }
    }
    #pragma unroll
    for (int mt = 0; mt < 4; mt++)
      #pragma unroll
      for (int nt = 0; nt < 2; nt++) {
        int c = wv * 32 + nt * 16 + lc;
        #pragma unroll
        for (int r = 0; r < 4; r++) {
          int n = n0 + mt * 16 + qd * 4 + r;
          z1b[(size_t)n * 256 + c] = (__bf16)aA[mt][nt][r];
          z2b[(size_t)n * 256 + c] = (__bf16)aB[mt][nt][r];
        }
      }
  }
}

// ---------------- readout ----------------
__global__ __launch_bounds__(128) void readout_sum_kernel(
    const float* __restrict__ h, const int* __restrict__ batch,
    float* __restrict__ gsum, float* __restrict__ gcnt)
{
  int j = threadIdx.x;
  int n0 = blockIdx.x * 128;
  float acc = 0.f, cacc = 0.f;
  int cur = batch[n0];
  for (int i = 0; i < 128; i++) {
    int b = batch[n0 + i];
    if (b != cur) {
      atomicAdd(&gsum[cur * 128 + j], acc);
      if (j == 0) atomicAdd(&gcnt[cur], cacc);
      acc = 0.f; cacc = 0.f; cur = b;
    }
    acc += h[(size_t)(n0 + i) * 128 + j];
    cacc += 1.f;
  }
  atomicAdd(&gsum[cur * 128 + j], acc);
  if (j == 0) atomicAdd(&gcnt[cur], cacc);
}

__global__ __launch_bounds__(256) void readout_mlp_kernel(
    const float* __restrict__ gsum, const float* __restrict__ gcnt,
    const float* __restrict__ W1, const float* __restrict__ b1,
    const float* __restrict__ W2, const float* __restrict__ b2,
    float* __restrict__ out)
{
  __shared__ float g[8][128];
  __shared__ float hid[8][256];
  int tid = threadIdx.x;
  for (int i = tid; i < 8 * 128; i += 256) {
    int b = i >> 7, c = i & 127;
    g[b][c] = gsum[i] / fmaxf(gcnt[b], 1.0f);
  }
  __syncthreads();
  {
    float bb = b1[tid];
    float a[8];
    #pragma unroll
    for (int b = 0; b < 8; b++) a[b] = bb;
    for (int k = 0; k < 128; k++) {
      float w = W1[k * 256 + tid];
      #pragma unroll
      for (int b = 0; b < 8; b++) a[b] += g[b][k] * w;
    }
    #pragma unroll
    for (int b = 0; b < 8; b++) hid[b][tid] = silu_f(a[b]);
  }
  __syncthreads();
  int j = tid & 63, bg = tid >> 6;
  float a0 = b2[j], a1 = b2[j];
  for (int k = 0; k < 256; k++) {
    float w = W2[k * 64 + j];
    a0 += hid[bg * 2 + 0][k] * w;
    a1 += hid[bg * 2 + 1][k] * w;
  }
  out[(bg * 2 + 0) * 64 + j] = a0;
  out[(bg * 2 + 1) * 64 + j] = a1;
}

extern "C" void kernel_launch(void* const* d_in, const int* in_sizes, int n_in,
                              void* d_out, int out_size, void* d_ws, size_t ws_size,
                              hipStream_t stream) {
  const float* pos   = (const float*)d_in[0];
  const float* xfeat = (const float*)d_in[1];
  const int*   eidx  = (const int*)d_in[2];
  const int*   batch = (const int*)d_in[3];
  const float* eW1 = (const float*)d_in[4];
  const float* eb1 = (const float*)d_in[5];
  const float* eW2 = (const float*)d_in[6];
  const float* eb2 = (const float*)d_in[7];
  const float* mW1 = (const float*)d_in[8];
  const float* mb1 = (const float*)d_in[9];
  const float* mW2 = (const float*)d_in[10];
  const float* mb2 = (const float*)d_in[11];
  const float* uW1 = (const float*)d_in[12];
  const float* ub1 = (const float*)d_in[13];
  const float* uW2 = (const float*)d_in[14];
  const float* ub2 = (const float*)d_in[15];
  const float* rW1 = (const float*)d_in[16];
  const float* rb1 = (const float*)d_in[17];
  const float* rW2 = (const float*)d_in[18];
  const float* rb2 = (const float*)d_in[19];

  const int* srcI = eidx;
  const int* dstI = eidx + NEDGES;

  char* base = (char*)d_ws;
  float* h    = (float*)base;  base += (size_t)NATOMS * 128 * 4;
  float* aggH = (float*)base;  base += (size_t)NATOMS * 256 * 4;
  __bf16* z1b = (__bf16*)base; base += (size_t)NATOMS * 256 * 2;
  __bf16* z2b = (__bf16*)base; base += (size_t)NATOMS * 256 * 2;
  __bf16* hb  = (__bf16*)base; base += (size_t)NATOMS * 128 * 2;
  __bf16* efb = (__bf16*)base; base += (size_t)NEDGES * 16 * 2;
  __bf16* W1at = (__bf16*)base; base += (size_t)NLAYERS * 256 * 128 * 2;
  __bf16* W1bt = (__bf16*)base; base += (size_t)NLAYERS * 256 * 128 * 2;
  __bf16* B2c  = (__bf16*)base; base += (size_t)NLAYERS * 256 * 32 * 2;
  __bf16* uW1ft = (__bf16*)base; base += (size_t)NLAYERS * 256 * 384 * 2;
  __bf16* uW2t = (__bf16*)base; base += (size_t)NLAYERS * 128 * 256 * 2;
  float* b2u  = (float*)base;  base += (size_t)NLAYERS * 256 * 4;
  float* degf = (float*)base;  base += (size_t)NATOMS * 4;
  float* gsum = (float*)base;  base += 8 * 128 * 4;
  float* gcnt = (float*)base;  base += 8 * 4;
  int* counts = (int*)base;    base += (size_t)NATOMS * 4;
  int* cursor = (int*)base;    base += (size_t)NATOMS * 4;
  int* esrc   = (int*)base;    base += (size_t)NEDGES * 4;
  int* edst   = (int*)base;    base += (size_t)NEDGES * 4;

  // --- CSR preprocessing ---
  hipMemsetAsync(counts, 0, NATOMS * sizeof(int), stream);
  hist_kernel<<<NEDGES / 256, 256, 0, stream>>>(dstI, counts);
  scan_kernel<<<1, 1024, 0, stream>>>(counts, cursor, degf);
  scatter_kernel<<<NEDGES / 256, 256, 0, stream>>>(srcI, dstI, cursor, esrc, edst);

  // --- merged weight prep ---
  prep_kernel<<<dim3(801, NLAYERS), 256, 0, stream>>>(
      mW1, mW2, uW1, uW2, mb2, W1at, W1bt, B2c, uW1ft, uW2t, b2u);

  rbf_kernel<<<NEDGES / 256, 256, 0, stream>>>(pos, esrc, edst, efb);

  // fused embed + layer-0 zprep (also zeros aggH)
  embed_zprep_kernel<<<NATOMS / 64, 256, 0, stream>>>(
      xfeat, eW1, eb1, eW2, eb2, mb1, W1at, W1bt, h, hb, z1b, z2b, aggH);

  for (int l = 0; l < NLAYERS; l++) {
    int ln = (l < NLAYERS - 1) ? (l + 1) : l;
    msg_mfma_kernel<<<NEDGES / TE, 512, 0, stream>>>(
        z1b, z2b, efb, esrc, edst,
        B2c + (size_t)l * 256 * 32, aggH);
    upd_mfma_kernel<<<NATOMS / 64, 512, 0, stream>>>(
        h, hb, aggH, degf,
        uW1ft + (size_t)l * 256 * 384, ub1 + (size_t)l * 256,
        b2u + (size_t)l * 256,
        uW2t + (size_t)l * 128 * 256, ub2 + (size_t)l * 128,
        (l < NLAYERS - 1) ? 1 : 0,
        mb1 + (size_t)ln * 256,
        W1at + (size_t)ln * 256 * 128, W1bt + (size_t)ln * 256 * 128,
        z1b, z2b);
  }

  hipMemsetAsync(gsum, 0, (8 * 128 + 8) * sizeof(float), stream);
  readout_sum_kernel<<<NATOMS / 128, 128, 0, stream>>>(h, batch, gsum, gcnt);
  readout_mlp_kernel<<<1, 256, 0, stream>>>(gsum, gcnt, rW1, rb1, rW2, rb2,
                                            (float*)d_out);
}

// Round 14
// 684.496 us; speedup vs baseline: 1.1590x; 1.1590x over previous
//
#include <hip/hip_runtime.h>
#include <math.h>

#define NATOMS 16384
#define NEDGES 524288
#define NLAYERS 4
#define TE 128     // edges per block in msg kernel

typedef __bf16 bf16x8 __attribute__((ext_vector_type(8)));
typedef __bf16 bf16x4 __attribute__((ext_vector_type(4)));
typedef __bf16 bf16x2 __attribute__((ext_vector_type(2)));
typedef float f32x4 __attribute__((ext_vector_type(4)));

// fast silu: x * rcp(1+exp(-x))
__device__ __forceinline__ float silu_f(float x) {
  return x * __builtin_amdgcn_rcpf(1.0f + __expf(-x));
}

// ---------------- CSR preprocessing ----------------
__global__ __launch_bounds__(256) void hist_kernel(
    const int* __restrict__ dst, int* __restrict__ counts)
{
  int e = blockIdx.x * 256 + threadIdx.x;
  atomicAdd(&counts[dst[e]], 1);
}

__global__ __launch_bounds__(1024) void scan_kernel(
    const int* __restrict__ counts, int* __restrict__ cursor,
    float* __restrict__ degf)
{
  __shared__ int s_tot[1024];
  int tid = threadIdx.x;
  int v[16];
  {
    const int4* cp = (const int4*)(counts + tid * 16);
    int4 a = cp[0], b = cp[1], c = cp[2], d = cp[3];
    v[0]=a.x; v[1]=a.y; v[2]=a.z; v[3]=a.w;
    v[4]=b.x; v[5]=b.y; v[6]=b.z; v[7]=b.w;
    v[8]=c.x; v[9]=c.y; v[10]=c.z; v[11]=c.w;
    v[12]=d.x; v[13]=d.y; v[14]=d.z; v[15]=d.w;
  }
  int tot = 0;
  #pragma unroll
  for (int i = 0; i < 16; i++) tot += v[i];
  s_tot[tid] = tot;
  __syncthreads();
  for (int off = 1; off < 1024; off <<= 1) {
    int t = (tid >= off) ? s_tot[tid - off] : 0;
    __syncthreads();
    s_tot[tid] += t;
    __syncthreads();
  }
  int run = s_tot[tid] - tot;   // exclusive prefix
  #pragma unroll
  for (int i = 0; i < 16; i++) {
    cursor[tid * 16 + i] = run;
    degf[tid * 16 + i] = (float)v[i];
    run += v[i];
  }
}

__global__ __launch_bounds__(256) void scatter_kernel(
    const int* __restrict__ src, const int* __restrict__ dst,
    int* __restrict__ cursor, int* __restrict__ esrc, int* __restrict__ edst)
{
  int e = blockIdx.x * 256 + threadIdx.x;
  int d = dst[e];
  int p = atomicAdd(&cursor[d], 1);
  esrc[p] = src[e];
  edst[p] = d;
}

// ---------------- merged weight prep ----------------
__global__ __launch_bounds__(256) void prep_kernel(
    const float* __restrict__ mW1, const float* __restrict__ mW2,
    const float* __restrict__ uW1, const float* __restrict__ uW2,
    const float* __restrict__ mb2,
    __bf16* __restrict__ W1at, __bf16* __restrict__ W1bt,
    __bf16* __restrict__ B2c, __bf16* __restrict__ uW1ft,
    __bf16* __restrict__ uW2t, float* __restrict__ b2u)
{
  long l = blockIdx.y;
  int bx = blockIdx.x, tid = threadIdx.x;
  if (bx < 128) {
    int i = bx * 256 + tid;              // 256*128
    int n = i >> 7, k = i & 127;
    W1at[l * (256L * 128) + i] = (__bf16)mW1[l * (272L * 256) + (size_t)k * 256 + n];
  } else if (bx < 256) {
    int i = (bx - 128) * 256 + tid;
    int n = i >> 7, k = i & 127;
    W1bt[l * (256L * 128) + i] = (__bf16)mW1[l * (272L * 256) + (size_t)(128 + k) * 256 + n];
  } else if (bx < 288) {
    int i = (bx - 256) * 256 + tid;      // 256*32
    int c = i >> 5, k = i & 31;
    float v = (k < 16) ? mW1[l * (272L * 256) + (size_t)(256 + k) * 256 + c] : 0.0f;
    B2c[l * (256L * 32) + i] = (__bf16)v;
  } else if (bx < 672) {
    int i = (bx - 288) * 256 + tid;      // 256*384
    int n = i / 384, k = i - n * 384;
    float v;
    if (k < 128) {
      v = uW1[l * 65536 + (size_t)k * 256 + n];
    } else {
      int r = k - 128;
      v = 0.0f;
      for (int j = 0; j < 128; j++)
        v += mW2[(l * 256 + r) * 128 + j] * uW1[l * 65536 + (size_t)(128 + j) * 256 + n];
    }
    uW1ft[l * (256L * 384) + i] = (__bf16)v;
  } else if (bx < 800) {
    int i = (bx - 672) * 256 + tid;      // 128*256
    int n = i >> 8, k = i & 255;
    uW2t[l * (128L * 256) + i] = (__bf16)uW2[l * (256L * 128) + (size_t)k * 128 + n];
  } else {
    int c = tid;
    float acc = 0.0f;
    for (int j = 0; j < 128; j++)
      acc += mb2[l * 128 + j] * uW1[l * 65536 + (size_t)(128 + j) * 256 + c];
    b2u[l * 256 + c] = acc;
  }
}

// ---------------- embedding (round-12 coalesced version) ----------------
__global__ __launch_bounds__(128) void embed_kernel(
    const float* __restrict__ x, const float* __restrict__ W1,
    const float* __restrict__ b1, const float* __restrict__ W2,
    const float* __restrict__ b2, float* __restrict__ h,
    __bf16* __restrict__ hb)
{
  int n = blockIdx.x;
  int j = threadIdx.x;
  __shared__ float xs[26];
  __shared__ float hid[128];
  if (j < 26) xs[j] = x[n * 26 + j];
  __syncthreads();
  float acc = b1[j];
  #pragma unroll
  for (int k = 0; k < 26; k++) acc += xs[k] * W1[k * 128 + j];
  hid[j] = silu_f(acc);
  __syncthreads();
  float acc2 = b2[j];
  #pragma unroll 8
  for (int k = 0; k < 128; k++) acc2 += hid[k] * W2[k * 128 + j];
  h[(size_t)n * 128 + j] = acc2;
  hb[(size_t)n * 128 + j] = (__bf16)acc2;
}

// ---------------- edge RBF (sorted slot order) ----------------
__global__ __launch_bounds__(256) void rbf_kernel(
    const float* __restrict__ pos, const int* __restrict__ esrc,
    const int* __restrict__ edst, __bf16* __restrict__ efb)
{
  int e = blockIdx.x * 256 + threadIdx.x;
  int s = esrc[e], d = edst[e];
  float dx = pos[d * 3 + 0] - pos[s * 3 + 0];
  float dy = pos[d * 3 + 1] - pos[s * 3 + 1];
  float dz = pos[d * 3 + 2] - pos[s * 3 + 2];
  float dist = sqrtf(dx * dx + dy * dy + dz * dz + 1e-12f);
  float env = (dist < 10.0f)
                  ? 0.5f * (cosf(3.14159265358979f * dist * 0.1f) + 1.0f)
                  : 0.0f;
  bf16x8 o0, o1;
  #pragma unroll
  for (int i = 0; i < 16; i++) {
    float c = (10.0f / 15.0f) * (float)i;
    float t = dist - c;
    float v = env * __expf(-t * t * 1.28f);
    if (i < 8) o0[i] = (__bf16)v; else o1[i - 8] = (__bf16)v;
  }
  *(bf16x8*)(efb + (size_t)e * 16 + 0) = o0;
  *(bf16x8*)(efb + (size_t)e * 16 + 8) = o1;
}

// ---------------- zprep (layer 0 only): z1b, z2b; zeros aggH ----------------
__global__ __launch_bounds__(256) void zprep_kernel(
    const __bf16* __restrict__ hb, const float* __restrict__ b1,
    const __bf16* __restrict__ W1at, const __bf16* __restrict__ W1bt,
    __bf16* __restrict__ z1b, __bf16* __restrict__ z2b, float* __restrict__ aggH)
{
  __shared__ __bf16 s_n[64][136];
  int tid = threadIdx.x, n0 = blockIdx.x * 64;
  {
    int n = tid >> 2, t4 = tid & 3;
    const bf16x8* hr = (const bf16x8*)(hb + (size_t)(n0 + n) * 128);
    #pragma unroll
    for (int i = 0; i < 4; i++)
      *(bf16x8*)&s_n[n][t4 * 8 + 32 * i] = hr[t4 + 4 * i];
  }
  {
    float4 zz = make_float4(0.f, 0.f, 0.f, 0.f);
    float4* ap = (float4*)(aggH + (size_t)n0 * 256);
    for (int i = tid; i < 64 * 256 / 4; i += 256) ap[i] = zz;
  }
  __syncthreads();
  const int wv = tid >> 6, ln = tid & 63, lc = ln & 15, qd = ln >> 4;
  for (int cp = 0; cp < 2; cp++) {
    f32x4 aA[4][2], aB[4][2];
    #pragma unroll
    for (int nt = 0; nt < 2; nt++) {
      float bv = b1[cp * 128 + wv * 32 + nt * 16 + lc];
      #pragma unroll
      for (int mt = 0; mt < 4; mt++) {
        aA[mt][nt][0] = 0.f; aA[mt][nt][1] = 0.f;
        aA[mt][nt][2] = 0.f; aA[mt][nt][3] = 0.f;
        aB[mt][nt][0] = bv; aB[mt][nt][1] = bv;
        aB[mt][nt][2] = bv; aB[mt][nt][3] = bv;
      }
    }
    #pragma unroll
    for (int kt = 0; kt < 4; kt++) {
      bf16x8 af[4];
      #pragma unroll
      for (int mt = 0; mt < 4; mt++)
        af[mt] = *(const bf16x8*)&s_n[mt * 16 + lc][kt * 32 + qd * 8];
      bf16x8 bwA[2], bwB[2];
      #pragma unroll
      for (int nt = 0; nt < 2; nt++) {
        int c = cp * 128 + wv * 32 + nt * 16 + lc;
        bwA[nt] = *(const bf16x8*)(W1at + (size_t)c * 128 + kt * 32 + qd * 8);
        bwB[nt] = *(const bf16x8*)(W1bt + (size_t)c * 128 + kt * 32 + qd * 8);
      }
      #pragma unroll
      for (int mt = 0; mt < 4; mt++)
        #pragma unroll
        for (int nt = 0; nt < 2; nt++) {
          aA[mt][nt] = __builtin_amdgcn_mfma_f32_16x16x32_bf16(af[mt], bwA[nt], aA[mt][nt], 0, 0, 0);
          aB[mt][nt] = __builtin_amdgcn_mfma_f32_16x16x32_bf16(af[mt], bwB[nt], aB[mt][nt], 0, 0, 0);
        }
    }
    #pragma unroll
    for (int mt = 0; mt < 4; mt++)
      #pragma unroll
      for (int nt = 0; nt < 2; nt++) {
        int c = cp * 128 + wv * 32 + nt * 16 + lc;
        #pragma unroll
        for (int r = 0; r < 4; r++) {
          int n = n0 + mt * 16 + qd * 4 + r;
          z1b[(size_t)n * 256 + c] = (__bf16)aA[mt][nt][r];
          z2b[(size_t)n * 256 + c] = (__bf16)aB[mt][nt][r];
        }
      }
  }
}

// ---------------- fused message kernel v8: TE=128, 512 threads, 2 blocks/CU ----------------
#define MS_EF_OFF   66560                 // s_hT 256*130*2 = 66560
#define MS_SRC_OFF  72704                 // s_ef 128*24*2 = 6144
#define MS_DST_OFF  73216
#define MS_MASK_OFF 73728
#define MS_BYTES    73744

__global__ __launch_bounds__(512, 2) void msg_mfma_kernel(
    const __bf16* __restrict__ z1b, const __bf16* __restrict__ z2b,
    const __bf16* __restrict__ efb,
    const int* __restrict__ esrc, const int* __restrict__ edst,
    const __bf16* __restrict__ B2c, float* __restrict__ aggH)
{
  __shared__ __align__(16) char smem[MS_BYTES];
  __bf16 (*s_hT)[130] = (__bf16(*)[130])(smem);        // [256 cols][128 rows + 2 pad]
  __bf16 (*s_ef)[24] = (__bf16(*)[24])(smem + MS_EF_OFF);
  int* s_src = (int*)(smem + MS_SRC_OFF);
  int* s_dst = (int*)(smem + MS_DST_OFF);
  unsigned int* s_mask = (unsigned int*)(smem + MS_MASK_OFF);

  int tid = threadIdx.x, e0 = blockIdx.x * TE;

  if (tid < TE) {
    int d = edst[e0 + tid];
    s_dst[tid] = d;
    int dp = (tid == 0) ? (d ^ 1) : edst[e0 + tid - 1];
    unsigned long long mb = __ballot(d != dp);
    if ((tid & 63) == 0) {
      int w = (tid >> 6) * 2;
      s_mask[w] = (unsigned int)mb;
      s_mask[w + 1] = (unsigned int)(mb >> 32);
    }
  } else if (tid < 2 * TE) {
    s_src[tid - TE] = esrc[e0 + tid - TE];
  }
  {
    int e = tid >> 2, t4 = tid & 3;
    if (t4 < 2)
      *(bf16x8*)&s_ef[e][t4 * 8] =
          *(const bf16x8*)(efb + (size_t)(e0 + e) * 16 + t4 * 8);
  }
  __syncthreads();

  const int wv = tid >> 6, ln = tid & 63, lc = ln & 15, qd = ln >> 4;

  bf16x8 bI;
  #pragma unroll
  for (int j = 0; j < 8; j++)
    bI[j] = (__bf16)((lc == (qd & 1) * 8 + j) ? 1.0f : 0.0f);

  const __bf16* pz[8];
  #pragma unroll
  for (int mt = 0; mt < 8; mt++) {
    int m = mt * 16 + lc;
    int row = (qd < 2) ? s_src[m] : s_dst[m];
    pz[mt] = ((qd < 2) ? z1b : z2b) + (size_t)row * 256 + (qd & 1) * 8;
  }

  // ---- wave wv owns cols cb..cb+31 (8 waves cover all 256), 8 M-tiles ----
  const int cb = wv * 32;
  bf16x8 bw[2];
  #pragma unroll
  for (int nt = 0; nt < 2; nt++)
    bw[nt] = *(const bf16x8*)(B2c + (size_t)(cb + nt * 16 + lc) * 32 + qd * 8);

  #pragma unroll
  for (int mt = 0; mt < 8; mt++) {
    bf16x8 aef = *(const bf16x8*)&s_ef[mt * 16 + lc][(qd & 1) * 8];
    #pragma unroll
    for (int nt = 0; nt < 2; nt++) {
      bf16x8 az = *(const bf16x8*)(pz[mt] + cb + nt * 16);
      f32x4 z; z[0] = 0.f; z[1] = 0.f; z[2] = 0.f; z[3] = 0.f;
      f32x4 acc = __builtin_amdgcn_mfma_f32_16x16x32_bf16(az, bI, z, 0, 0, 0);
      acc = __builtin_amdgcn_mfma_f32_16x16x32_bf16(aef, bw[nt], acc, 0, 0, 0);
      bf16x2 p0, p1;
      p0[0] = (__bf16)silu_f(acc[0]); p0[1] = (__bf16)silu_f(acc[1]);
      p1[0] = (__bf16)silu_f(acc[2]); p1[1] = (__bf16)silu_f(acc[3]);
      __bf16* wp = &s_hT[cb + nt * 16 + lc][mt * 16 + qd * 4];
      *(bf16x2*)wp = p0;
      *(bf16x2*)(wp + 2) = p1;
    }
  }
  __syncthreads();

  // ---- scan: 512 threads = 256 cols x 2 row-halves ----
  {
    int col = tid & 255, half = tid >> 8, r0 = half * 64;
    const unsigned int mlo = __builtin_amdgcn_readfirstlane(s_mask[half * 2]);
    const unsigned int mhi = __builtin_amdgcn_readfirstlane(s_mask[half * 2 + 1]);
    float acc = 0.0f;
    int cur = s_dst[r0];
    #pragma unroll 8
    for (int i = 0; i < 64; i += 2) {
      bf16x2 p = *(const bf16x2*)&s_hT[col][r0 + i];
      bool b0 = (i < 32) ? ((mlo >> i) & 1u) : ((mhi >> (i - 32)) & 1u);
      int i1 = i + 1;
      bool b1 = (i1 < 32) ? ((mlo >> i1) & 1u) : ((mhi >> (i1 - 32)) & 1u);
      if (i > 0 && b0) {
        atomicAdd(&aggH[(size_t)cur * 256 + col], acc);
        acc = 0.0f; cur = s_dst[r0 + i];
      }
      acc += (float)p[0];
      if (b1) {
        atomicAdd(&aggH[(size_t)cur * 256 + col], acc);
        acc = 0.0f; cur = s_dst[r0 + i1];
      }
      acc += (float)p[1];
    }
    atomicAdd(&aggH[(size_t)cur * 256 + col], acc);
  }
}

// ---------------- fused node update MLP v4: 512 threads, 64 nodes + next-layer zprep ----------------
__global__ __launch_bounds__(512, 2) void upd_mfma_kernel(
    float* __restrict__ h, __bf16* __restrict__ hb,
    float* __restrict__ aggH, const float* __restrict__ degf,
    const __bf16* __restrict__ uW1ft, const float* __restrict__ b1,
    const float* __restrict__ b2u,
    const __bf16* __restrict__ uW2t, const float* __restrict__ b2,
    int do_z, const float* __restrict__ nb1,
    const __bf16* __restrict__ nW1at, const __bf16* __restrict__ nW1bt,
    __bf16* __restrict__ z1b, __bf16* __restrict__ z2b)
{
  __shared__ __bf16 s_u[64][392];    // [h(128) | agg(256)] + 8 pad
  __shared__ __bf16 s_uh[64][264];   // 256 hidden cols + 8 pad
  int tid = threadIdx.x, n0 = blockIdx.x * 64;
  {
    int n = tid >> 3, t8 = tid & 7;  // 8 threads per node
    const bf16x8* hr = (const bf16x8*)(hb + (size_t)(n0 + n) * 128);
    #pragma unroll
    for (int i = 0; i < 2; i++)
      *(bf16x8*)&s_u[n][t8 * 8 + 64 * i] = hr[t8 + 8 * i];
    const float* sr = aggH + (size_t)(n0 + n) * 256;
    #pragma unroll
    for (int i = 0; i < 4; i++) {
      int col = t8 * 8 + i * 64;
      float4 a = *(const float4*)(sr + col);
      float4 b = *(const float4*)(sr + col + 4);
      bf16x8 o;
      o[0] = (__bf16)a.x; o[1] = (__bf16)a.y; o[2] = (__bf16)a.z; o[3] = (__bf16)a.w;
      o[4] = (__bf16)b.x; o[5] = (__bf16)b.y; o[6] = (__bf16)b.z; o[7] = (__bf16)b.w;
      *(bf16x8*)&s_u[n][128 + col] = o;
    }
  }
  __syncthreads();
  const int wv = tid >> 6, ln = tid & 63, lc = ln & 15, qd = ln >> 4;  // wv 0..7

  float dg[4][4];
  #pragma unroll
  for (int mt = 0; mt < 4; mt++)
    #pragma unroll
    for (int r = 0; r < 4; r++)
      dg[mt][r] = degf[n0 + mt * 16 + qd * 4 + r];

  // ---- GEMM1: K=384, wave owns cols wv*32 + nt*16 + lc ----
  {
    f32x4 acc1[4][2];
    #pragma unroll
    for (int nt = 0; nt < 2; nt++) {
      int c = wv * 32 + nt * 16 + lc;
      float bv = b1[c];
      float b2uv = b2u[c];
      #pragma unroll
      for (int mt = 0; mt < 4; mt++)
        #pragma unroll
        for (int r = 0; r < 4; r++)
          acc1[mt][nt][r] = bv + dg[mt][r] * b2uv;
    }
    #pragma unroll
    for (int kt = 0; kt < 12; kt++) {
      bf16x8 af[4];
      #pragma unroll
      for (int mt = 0; mt < 4; mt++)
        af[mt] = *(const bf16x8*)&s_u[mt * 16 + lc][kt * 32 + qd * 8];
      bf16x8 bw[2];
      #pragma unroll
      for (int nt = 0; nt < 2; nt++)
        bw[nt] = *(const bf16x8*)(uW1ft +
                 (size_t)(wv * 32 + nt * 16 + lc) * 384 + kt * 32 + qd * 8);
      #pragma unroll
      for (int mt = 0; mt < 4; mt++)
        #pragma unroll
        for (int nt = 0; nt < 2; nt++)
          acc1[mt][nt] = __builtin_amdgcn_mfma_f32_16x16x32_bf16(af[mt], bw[nt], acc1[mt][nt], 0, 0, 0);
    }
    #pragma unroll
    for (int mt = 0; mt < 4; mt++)
      #pragma unroll
      for (int nt = 0; nt < 2; nt++) {
        int cc = wv * 32 + nt * 16 + lc;
        #pragma unroll
        for (int r = 0; r < 4; r++)
          s_uh[mt * 16 + qd * 4 + r][cc] = (__bf16)silu_f(acc1[mt][nt][r]);
      }
  }
  __syncthreads();

  // ---- GEMM2: K=256, wave owns output cols ow = wv*16 + lc ----
  const int ow = wv * 16 + lc;
  f32x4 acc2[4];
  {
    float bv = b2[ow];
    #pragma unroll
    for (int mt = 0; mt < 4; mt++) {
      acc2[mt][0] = bv; acc2[mt][1] = bv; acc2[mt][2] = bv; acc2[mt][3] = bv;
    }
  }
  #pragma unroll
  for (int kt = 0; kt < 8; kt++) {
    bf16x8 a2[4];
    #pragma unroll
    for (int mt = 0; mt < 4; mt++)
      a2[mt] = *(const bf16x8*)&s_uh[mt * 16 + lc][kt * 32 + qd * 8];
    bf16x8 b2w = *(const bf16x8*)(uW2t + (size_t)ow * 256 + kt * 32 + qd * 8);
    #pragma unroll
    for (int mt = 0; mt < 4; mt++)
      acc2[mt] = __builtin_amdgcn_mfma_f32_16x16x32_bf16(a2[mt], b2w, acc2[mt], 0, 0, 0);
  }

  // residual epilogue
  #pragma unroll
  for (int mt = 0; mt < 4; mt++)
    #pragma unroll
    for (int r = 0; r < 4; r++) {
      int n = n0 + mt * 16 + qd * 4 + r;
      float v = h[(size_t)n * 128 + ow] + acc2[mt][r];
      h[(size_t)n * 128 + ow] = v;
      hb[(size_t)n * 128 + ow] = (__bf16)v;
    }

  // ---- fused zprep for next layer ----
  if (do_z) {
    __syncthreads();
    {
      float4 zz = make_float4(0.f, 0.f, 0.f, 0.f);
      float4* ap = (float4*)(aggH + (size_t)n0 * 256);
      for (int i = tid; i < 64 * 256 / 4; i += 512) ap[i] = zz;
      int n = tid >> 3, t8 = tid & 7;
      const bf16x8* hr = (const bf16x8*)(hb + (size_t)(n0 + n) * 128);
      #pragma unroll
      for (int i = 0; i < 2; i++)
        *(bf16x8*)&s_u[n][t8 * 8 + 64 * i] = hr[t8 + 8 * i];
    }
    __syncthreads();
    f32x4 aA[4][2], aB[4][2];
    #pragma unroll
    for (int nt = 0; nt < 2; nt++) {
      float bv = nb1[wv * 32 + nt * 16 + lc];
      #pragma unroll
      for (int mt = 0; mt < 4; mt++) {
        aA[mt][nt][0] = 0.f; aA[mt][nt][1] = 0.f;
        aA[mt][nt][2] = 0.f; aA[mt][nt][3] = 0.f;
        aB[mt][nt][0] = bv; aB[mt][nt][1] = bv;
        aB[mt][nt][2] = bv; aB[mt][nt][3] = bv;
      }
    }
    #pragma unroll
    for (int kt = 0; kt < 4; kt++) {
      bf16x8 af[4];
      #pragma unroll
      for (int mt = 0; mt < 4; mt++)
        af[mt] = *(const bf16x8*)&s_u[mt * 16 + lc][kt * 32 + qd * 8];
      bf16x8 bwA[2], bwB[2];
      #pragma unroll
      for (int nt = 0; nt < 2; nt++) {
        int c = wv * 32 + nt * 16 + lc;
        bwA[nt] = *(const bf16x8*)(nW1at + (size_t)c * 128 + kt * 32 + qd * 8);
        bwB[nt] = *(const bf16x8*)(nW1bt + (size_t)c * 128 + kt * 32 + qd * 8);
      }
      #pragma unroll
      for (int mt = 0; mt < 4; mt++)
        #pragma unroll
        for (int nt = 0; nt < 2; nt++) {
          aA[mt][nt] = __builtin_amdgcn_mfma_f32_16x16x32_bf16(af[mt], bwA[nt], aA[mt][nt], 0, 0, 0);
          aB[mt][nt] = __builtin_amdgcn_mfma_f32_16x16x32_bf16(af[mt], bwB[nt], aB[mt][nt], 0, 0, 0);
        }
    }
    #pragma unroll
    for (int mt = 0; mt < 4; mt++)
      #pragma unroll
      for (int nt = 0; nt < 2; nt++) {
        int c = wv * 32 + nt * 16 + lc;
        #pragma unroll
        for (int r = 0; r < 4; r++) {
          int n = n0 + mt * 16 + qd * 4 + r;
          z1b[(size_t)n * 256 + c] = (__bf16)aA[mt][nt][r];
          z2b[(size_t)n * 256 + c] = (__bf16)aB[mt][nt][r];
        }
      }
  }
}

// ---------------- readout ----------------
__global__ __launch_bounds__(128) void readout_sum_kernel(
    const float* __restrict__ h, const int* __restrict__ batch,
    float* __restrict__ gsum, float* __restrict__ gcnt)
{
  int j = threadIdx.x;
  int n0 = blockIdx.x * 128;
  float acc = 0.f, cacc = 0.f;
  int cur = batch[n0];
  for (int i = 0; i < 128; i++) {
    int b = batch[n0 + i];
    if (b != cur) {
      atomicAdd(&gsum[cur * 128 + j], acc);
      if (j == 0) atomicAdd(&gcnt[cur], cacc);
      acc = 0.f; cacc = 0.f; cur = b;
    }
    acc += h[(size_t)(n0 + i) * 128 + j];
    cacc += 1.f;
  }
  atomicAdd(&gsum[cur * 128 + j], acc);
  if (j == 0) atomicAdd(&gcnt[cur], cacc);
}

__global__ __launch_bounds__(256) void readout_mlp_kernel(
    const float* __restrict__ gsum, const float* __restrict__ gcnt,
    const float* __restrict__ W1, const float* __restrict__ b1,
    const float* __restrict__ W2, const float* __restrict__ b2,
    float* __restrict__ out)
{
  __shared__ float g[8][128];
  __shared__ float hid[8][256];
  int tid = threadIdx.x;
  for (int i = tid; i < 8 * 128; i += 256) {
    int b = i >> 7, c = i & 127;
    g[b][c] = gsum[i] / fmaxf(gcnt[b], 1.0f);
  }
  __syncthreads();
  {
    float bb = b1[tid];
    float a[8];
    #pragma unroll
    for (int b = 0; b < 8; b++) a[b] = bb;
    for (int k = 0; k < 128; k++) {
      float w = W1[k * 256 + tid];
      #pragma unroll
      for (int b = 0; b < 8; b++) a[b] += g[b][k] * w;
    }
    #pragma unroll
    for (int b = 0; b < 8; b++) hid[b][tid] = silu_f(a[b]);
  }
  __syncthreads();
  int j = tid & 63, bg = tid >> 6;
  float a0 = b2[j], a1 = b2[j];
  for (int k = 0; k < 256; k++) {
    float w = W2[k * 64 + j];
    a0 += hid[bg * 2 + 0][k] * w;
    a1 += hid[bg * 2 + 1][k] * w;
  }
  out[(bg * 2 + 0) * 64 + j] = a0;
  out[(bg * 2 + 1) * 64 + j] = a1;
}

extern "C" void kernel_launch(void* const* d_in, const int* in_sizes, int n_in,
                              void* d_out, int out_size, void* d_ws, size_t ws_size,
                              hipStream_t stream) {
  const float* pos   = (const float*)d_in[0];
  const float* xfeat = (const float*)d_in[1];
  const int*   eidx  = (const int*)d_in[2];
  const int*   batch = (const int*)d_in[3];
  const float* eW1 = (const float*)d_in[4];
  const float* eb1 = (const float*)d_in[5];
  const float* eW2 = (const float*)d_in[6];
  const float* eb2 = (const float*)d_in[7];
  const float* mW1 = (const float*)d_in[8];
  const float* mb1 = (const float*)d_in[9];
  const float* mW2 = (const float*)d_in[10];
  const float* mb2 = (const float*)d_in[11];
  const float* uW1 = (const float*)d_in[12];
  const float* ub1 = (const float*)d_in[13];
  const float* uW2 = (const float*)d_in[14];
  const float* ub2 = (const float*)d_in[15];
  const float* rW1 = (const float*)d_in[16];
  const float* rb1 = (const float*)d_in[17];
  const float* rW2 = (const float*)d_in[18];
  const float* rb2 = (const float*)d_in[19];

  const int* srcI = eidx;
  const int* dstI = eidx + NEDGES;

  char* base = (char*)d_ws;
  float* h    = (float*)base;  base += (size_t)NATOMS * 128 * 4;
  float* aggH = (float*)base;  base += (size_t)NATOMS * 256 * 4;
  __bf16* z1b = (__bf16*)base; base += (size_t)NATOMS * 256 * 2;
  __bf16* z2b = (__bf16*)base; base += (size_t)NATOMS * 256 * 2;
  __bf16* hb  = (__bf16*)base; base += (size_t)NATOMS * 128 * 2;
  __bf16* efb = (__bf16*)base; base += (size_t)NEDGES * 16 * 2;
  __bf16* W1at = (__bf16*)base; base += (size_t)NLAYERS * 256 * 128 * 2;
  __bf16* W1bt = (__bf16*)base; base += (size_t)NLAYERS * 256 * 128 * 2;
  __bf16* B2c  = (__bf16*)base; base += (size_t)NLAYERS * 256 * 32 * 2;
  __bf16* uW1ft = (__bf16*)base; base += (size_t)NLAYERS * 256 * 384 * 2;
  __bf16* uW2t = (__bf16*)base; base += (size_t)NLAYERS * 128 * 256 * 2;
  float* b2u  = (float*)base;  base += (size_t)NLAYERS * 256 * 4;
  float* degf = (float*)base;  base += (size_t)NATOMS * 4;
  float* gsum = (float*)base;  base += 8 * 128 * 4;
  float* gcnt = (float*)base;  base += 8 * 4;
  int* counts = (int*)base;    base += (size_t)NATOMS * 4;
  int* cursor = (int*)base;    base += (size_t)NATOMS * 4;
  int* esrc   = (int*)base;    base += (size_t)NEDGES * 4;
  int* edst   = (int*)base;    base += (size_t)NEDGES * 4;

  // --- CSR preprocessing ---
  hipMemsetAsync(counts, 0, NATOMS * sizeof(int), stream);
  hist_kernel<<<NEDGES / 256, 256, 0, stream>>>(dstI, counts);
  scan_kernel<<<1, 1024, 0, stream>>>(counts, cursor, degf);
  scatter_kernel<<<NEDGES / 256, 256, 0, stream>>>(srcI, dstI, cursor, esrc, edst);

  // --- merged weight prep ---
  prep_kernel<<<dim3(801, NLAYERS), 256, 0, stream>>>(
      mW1, mW2, uW1, uW2, mb2, W1at, W1bt, B2c, uW1ft, uW2t, b2u);

  embed_kernel<<<NATOMS, 128, 0, stream>>>(xfeat, eW1, eb1, eW2, eb2, h, hb);
  rbf_kernel<<<NEDGES / 256, 256, 0, stream>>>(pos, esrc, edst, efb);

  // zprep for layer 0 (also zeros aggH)
  zprep_kernel<<<NATOMS / 64, 256, 0, stream>>>(
      hb, mb1, W1at, W1bt, z1b, z2b, aggH);

  for (int l = 0; l < NLAYERS; l++) {
    int ln = (l < NLAYERS - 1) ? (l + 1) : l;
    msg_mfma_kernel<<<NEDGES / TE, 512, 0, stream>>>(
        z1b, z2b, efb, esrc, edst,
        B2c + (size_t)l * 256 * 32, aggH);
    upd_mfma_kernel<<<NATOMS / 64, 512, 0, stream>>>(
        h, hb, aggH, degf,
        uW1ft + (size_t)l * 256 * 384, ub1 + (size_t)l * 256,
        b2u + (size_t)l * 256,
        uW2t + (size_t)l * 128 * 256, ub2 + (size_t)l * 128,
        (l < NLAYERS - 1) ? 1 : 0,
        mb1 + (size_t)ln * 256,
        W1at + (size_t)ln * 256 * 128, W1bt + (size_t)ln * 256 * 128,
        z1b, z2b);
  }

  hipMemsetAsync(gsum, 0, (8 * 128 + 8) * sizeof(float), stream);
  readout_sum_kernel<<<NATOMS / 128, 128, 0, stream>>>(h, batch, gsum, gcnt);
  readout_mlp_kernel<<<1, 256, 0, stream>>>(gsum, gcnt, rW1, rb1, rW2, rb2,
                                            (float*)d_out);
}

// Round 15
// 673.139 us; speedup vs baseline: 1.1785x; 1.0169x over previous
//
#include <hip/hip_runtime.h>
#include <math.h>

#define NATOMS 16384
#define NEDGES 524288
#define NLAYERS 4
#define TE 64      // edges per block in msg kernel

typedef __bf16 bf16x8 __attribute__((ext_vector_type(8)));
typedef __bf16 bf16x4 __attribute__((ext_vector_type(4)));
typedef __bf16 bf16x2 __attribute__((ext_vector_type(2)));
typedef float f32x4 __attribute__((ext_vector_type(4)));

// fast silu: x * rcp(1+exp(-x))
__device__ __forceinline__ float silu_f(float x) {
  return x * __builtin_amdgcn_rcpf(1.0f + __expf(-x));
}

// ---------------- CSR preprocessing ----------------
__global__ __launch_bounds__(1024) void scan_kernel(
    const int* __restrict__ counts, int* __restrict__ cursor,
    float* __restrict__ degf)
{
  __shared__ int s_tot[1024];
  int tid = threadIdx.x;
  int v[16];
  {
    const int4* cp = (const int4*)(counts + tid * 16);
    int4 a = cp[0], b = cp[1], c = cp[2], d = cp[3];
    v[0]=a.x; v[1]=a.y; v[2]=a.z; v[3]=a.w;
    v[4]=b.x; v[5]=b.y; v[6]=b.z; v[7]=b.w;
    v[8]=c.x; v[9]=c.y; v[10]=c.z; v[11]=c.w;
    v[12]=d.x; v[13]=d.y; v[14]=d.z; v[15]=d.w;
  }
  int tot = 0;
  #pragma unroll
  for (int i = 0; i < 16; i++) tot += v[i];
  s_tot[tid] = tot;
  __syncthreads();
  for (int off = 1; off < 1024; off <<= 1) {
    int t = (tid >= off) ? s_tot[tid - off] : 0;
    __syncthreads();
    s_tot[tid] += t;
    __syncthreads();
  }
  int run = s_tot[tid] - tot;   // exclusive prefix
  #pragma unroll
  for (int i = 0; i < 16; i++) {
    cursor[tid * 16 + i] = run;
    degf[tid * 16 + i] = (float)v[i];
    run += v[i];
  }
}

__global__ __launch_bounds__(256) void scatter_kernel(
    const int* __restrict__ src, const int* __restrict__ dst,
    int* __restrict__ cursor, int* __restrict__ esrc, int* __restrict__ edst)
{
  int e = blockIdx.x * 256 + threadIdx.x;
  int d = dst[e];
  int p = atomicAdd(&cursor[d], 1);
  esrc[p] = src[e];
  edst[p] = d;
}

// ---------------- merged front kernel: weight prep + dst histogram + embed ----------------
// sections by flat blockIdx.x:
//   [0, 3204)        prep   (801 blocks x 4 layers)
//   [3204, 5252)     hist   (2048 blocks)
//   [5252, 13444)    embed  (8192 blocks, 2 nodes each)
#define NB_PREP (801 * NLAYERS)
#define NB_HIST (NEDGES / 256)
#define NB_EMB  (NATOMS / 2)

__global__ __launch_bounds__(256) void front_kernel(
    const float* __restrict__ mW1, const float* __restrict__ mW2,
    const float* __restrict__ uW1, const float* __restrict__ uW2,
    const float* __restrict__ mb2,
    __bf16* __restrict__ W1at, __bf16* __restrict__ W1bt,
    __bf16* __restrict__ B2c, __bf16* __restrict__ uW1ft,
    __bf16* __restrict__ uW2t, float* __restrict__ b2u,
    const int* __restrict__ dstI, int* __restrict__ counts,
    const float* __restrict__ x, const float* __restrict__ eW1,
    const float* __restrict__ eb1, const float* __restrict__ eW2,
    const float* __restrict__ eb2, float* __restrict__ h,
    __bf16* __restrict__ hb)
{
  __shared__ float xs[2][26];
  __shared__ float hid[2][132];
  int bxf = blockIdx.x, tid = threadIdx.x;

  if (bxf < NB_PREP) {
    long l = bxf / 801;
    int bx = bxf - (int)l * 801;
    if (bx < 128) {
      int i = bx * 256 + tid;              // 256*128
      int n = i >> 7, k = i & 127;
      W1at[l * (256L * 128) + i] = (__bf16)mW1[l * (272L * 256) + (size_t)k * 256 + n];
    } else if (bx < 256) {
      int i = (bx - 128) * 256 + tid;
      int n = i >> 7, k = i & 127;
      W1bt[l * (256L * 128) + i] = (__bf16)mW1[l * (272L * 256) + (size_t)(128 + k) * 256 + n];
    } else if (bx < 288) {
      int i = (bx - 256) * 256 + tid;      // 256*32
      int c = i >> 5, k = i & 31;
      float v = (k < 16) ? mW1[l * (272L * 256) + (size_t)(256 + k) * 256 + c] : 0.0f;
      B2c[l * (256L * 32) + i] = (__bf16)v;
    } else if (bx < 672) {
      int i = (bx - 288) * 256 + tid;      // 256*384
      int n = i / 384, k = i - n * 384;
      float v;
      if (k < 128) {
        v = uW1[l * 65536 + (size_t)k * 256 + n];
      } else {
        int r = k - 128;
        v = 0.0f;
        for (int j = 0; j < 128; j++)
          v += mW2[(l * 256 + r) * 128 + j] * uW1[l * 65536 + (size_t)(128 + j) * 256 + n];
      }
      uW1ft[l * (256L * 384) + i] = (__bf16)v;
    } else if (bx < 800) {
      int i = (bx - 672) * 256 + tid;      // 128*256
      int n = i >> 8, k = i & 255;
      uW2t[l * (128L * 256) + i] = (__bf16)uW2[l * (256L * 128) + (size_t)k * 128 + n];
    } else {
      int c = tid;
      float acc = 0.0f;
      for (int j = 0; j < 128; j++)
        acc += mb2[l * 128 + j] * uW1[l * 65536 + (size_t)(128 + j) * 256 + c];
      b2u[l * 256 + c] = acc;
    }
  } else if (bxf < NB_PREP + NB_HIST) {
    int e = (bxf - NB_PREP) * 256 + tid;
    atomicAdd(&counts[dstI[e]], 1);
  } else {
    int nb = bxf - (NB_PREP + NB_HIST);
    int hf = tid >> 7, j = tid & 127;
    int n = nb * 2 + hf;
    if (j < 26) xs[hf][j] = x[(size_t)n * 26 + j];
    __syncthreads();
    float acc = eb1[j];
    #pragma unroll
    for (int k = 0; k < 26; k++) acc += xs[hf][k] * eW1[k * 128 + j];
    hid[hf][j] = silu_f(acc);
    __syncthreads();
    float acc2 = eb2[j];
    #pragma unroll 8
    for (int k = 0; k < 128; k++) acc2 += hid[hf][k] * eW2[k * 128 + j];
    h[(size_t)n * 128 + j] = acc2;
    hb[(size_t)n * 128 + j] = (__bf16)acc2;
  }
}

// ---------------- edge RBF (sorted slot order) ----------------
__global__ __launch_bounds__(256) void rbf_kernel(
    const float* __restrict__ pos, const int* __restrict__ esrc,
    const int* __restrict__ edst, __bf16* __restrict__ efb)
{
  int e = blockIdx.x * 256 + threadIdx.x;
  int s = esrc[e], d = edst[e];
  float dx = pos[d * 3 + 0] - pos[s * 3 + 0];
  float dy = pos[d * 3 + 1] - pos[s * 3 + 1];
  float dz = pos[d * 3 + 2] - pos[s * 3 + 2];
  float dist = sqrtf(dx * dx + dy * dy + dz * dz + 1e-12f);
  float env = (dist < 10.0f)
                  ? 0.5f * (cosf(3.14159265358979f * dist * 0.1f) + 1.0f)
                  : 0.0f;
  bf16x8 o0, o1;
  #pragma unroll
  for (int i = 0; i < 16; i++) {
    float c = (10.0f / 15.0f) * (float)i;
    float t = dist - c;
    float v = env * __expf(-t * t * 1.28f);
    if (i < 8) o0[i] = (__bf16)v; else o1[i - 8] = (__bf16)v;
  }
  *(bf16x8*)(efb + (size_t)e * 16 + 0) = o0;
  *(bf16x8*)(efb + (size_t)e * 16 + 8) = o1;
}

// ---------------- zprep (layer 0 only): z1b, z2b; zeros aggH ----------------
__global__ __launch_bounds__(256) void zprep_kernel(
    const __bf16* __restrict__ hb, const float* __restrict__ b1,
    const __bf16* __restrict__ W1at, const __bf16* __restrict__ W1bt,
    __bf16* __restrict__ z1b, __bf16* __restrict__ z2b, float* __restrict__ aggH)
{
  __shared__ __bf16 s_n[64][136];
  int tid = threadIdx.x, n0 = blockIdx.x * 64;
  {
    int n = tid >> 2, t4 = tid & 3;
    const bf16x8* hr = (const bf16x8*)(hb + (size_t)(n0 + n) * 128);
    #pragma unroll
    for (int i = 0; i < 4; i++)
      *(bf16x8*)&s_n[n][t4 * 8 + 32 * i] = hr[t4 + 4 * i];
  }
  {
    float4 zz = make_float4(0.f, 0.f, 0.f, 0.f);
    float4* ap = (float4*)(aggH + (size_t)n0 * 256);
    for (int i = tid; i < 64 * 256 / 4; i += 256) ap[i] = zz;
  }
  __syncthreads();
  const int wv = tid >> 6, ln = tid & 63, lc = ln & 15, qd = ln >> 4;
  for (int cp = 0; cp < 2; cp++) {
    f32x4 aA[4][2], aB[4][2];
    #pragma unroll
    for (int nt = 0; nt < 2; nt++) {
      float bv = b1[cp * 128 + wv * 32 + nt * 16 + lc];
      #pragma unroll
      for (int mt = 0; mt < 4; mt++) {
        aA[mt][nt][0] = 0.f; aA[mt][nt][1] = 0.f;
        aA[mt][nt][2] = 0.f; aA[mt][nt][3] = 0.f;
        aB[mt][nt][0] = bv; aB[mt][nt][1] = bv;
        aB[mt][nt][2] = bv; aB[mt][nt][3] = bv;
      }
    }
    #pragma unroll
    for (int kt = 0; kt < 4; kt++) {
      bf16x8 af[4];
      #pragma unroll
      for (int mt = 0; mt < 4; mt++)
        af[mt] = *(const bf16x8*)&s_n[mt * 16 + lc][kt * 32 + qd * 8];
      bf16x8 bwA[2], bwB[2];
      #pragma unroll
      for (int nt = 0; nt < 2; nt++) {
        int c = cp * 128 + wv * 32 + nt * 16 + lc;
        bwA[nt] = *(const bf16x8*)(W1at + (size_t)c * 128 + kt * 32 + qd * 8);
        bwB[nt] = *(const bf16x8*)(W1bt + (size_t)c * 128 + kt * 32 + qd * 8);
      }
      #pragma unroll
      for (int mt = 0; mt < 4; mt++)
        #pragma unroll
        for (int nt = 0; nt < 2; nt++) {
          aA[mt][nt] = __builtin_amdgcn_mfma_f32_16x16x32_bf16(af[mt], bwA[nt], aA[mt][nt], 0, 0, 0);
          aB[mt][nt] = __builtin_amdgcn_mfma_f32_16x16x32_bf16(af[mt], bwB[nt], aB[mt][nt], 0, 0, 0);
        }
    }
    #pragma unroll
    for (int mt = 0; mt < 4; mt++)
      #pragma unroll
      for (int nt = 0; nt < 2; nt++) {
        int c = cp * 128 + wv * 32 + nt * 16 + lc;
        #pragma unroll
        for (int r = 0; r < 4; r++) {
          int n = n0 + mt * 16 + qd * 4 + r;
          z1b[(size_t)n * 256 + c] = (__bf16)aA[mt][nt][r];
          z2b[(size_t)n * 256 + c] = (__bf16)aB[mt][nt][r];
        }
      }
  }
}

// ---------------- fused message kernel v7b: TE=64, packed-float2 scan ----------------
#define MS_EF_OFF   33792                 // s_hT 256*66*2 = 33792
#define MS_SRC_OFF  36864                 // s_ef 64*24*2 = 3072
#define MS_DST_OFF  37120
#define MS_MASK_OFF 37376
#define MS_BYTES    37392

__global__ __launch_bounds__(256, 4) void msg_mfma_kernel(
    const __bf16* __restrict__ z1b, const __bf16* __restrict__ z2b,
    const __bf16* __restrict__ efb,
    const int* __restrict__ esrc, const int* __restrict__ edst,
    const __bf16* __restrict__ B2c, float* __restrict__ aggH)
{
  __shared__ __align__(16) char smem[MS_BYTES];
  __bf16 (*s_hT)[66] = (__bf16(*)[66])(smem);          // [256 cols][64 rows + 2 pad]
  __bf16 (*s_ef)[24] = (__bf16(*)[24])(smem + MS_EF_OFF);
  int* s_src = (int*)(smem + MS_SRC_OFF);
  int* s_dst = (int*)(smem + MS_DST_OFF);
  unsigned int* s_mask = (unsigned int*)(smem + MS_MASK_OFF);

  int tid = threadIdx.x, e0 = blockIdx.x * TE;

  if (tid < TE) {
    int d = edst[e0 + tid];
    s_dst[tid] = d;
    int dp = (tid == 0) ? (d ^ 1) : edst[e0 + tid - 1];
    unsigned long long mb = __ballot(d != dp);
    if (tid == 0) { s_mask[0] = (unsigned int)mb; s_mask[1] = (unsigned int)(mb >> 32); }
  } else if (tid < 2 * TE) {
    s_src[tid - TE] = esrc[e0 + tid - TE];
  }
  {
    int e = tid >> 2, t4 = tid & 3;
    if (t4 < 2)
      *(bf16x8*)&s_ef[e][t4 * 8] =
          *(const bf16x8*)(efb + (size_t)(e0 + e) * 16 + t4 * 8);
  }
  __syncthreads();

  const int wv = tid >> 6, ln = tid & 63, lc = ln & 15, qd = ln >> 4;

  bf16x8 bI;
  #pragma unroll
  for (int j = 0; j < 8; j++)
    bI[j] = (__bf16)((lc == (qd & 1) * 8 + j) ? 1.0f : 0.0f);

  const __bf16* pz[4];
  #pragma unroll
  for (int mt = 0; mt < 4; mt++) {
    int m = mt * 16 + lc;
    int row = (qd < 2) ? s_src[m] : s_dst[m];
    pz[mt] = ((qd < 2) ? z1b : z2b) + (size_t)row * 256 + (qd & 1) * 8;
  }

  // ---- compute both halves, no barrier between (disjoint s_hT cols) ----
  #pragma unroll
  for (int hf = 0; hf < 2; hf++) {
    const int cb = hf * 128 + wv * 32;
    bf16x8 bw[2];
    #pragma unroll
    for (int nt = 0; nt < 2; nt++)
      bw[nt] = *(const bf16x8*)(B2c + (size_t)(cb + nt * 16 + lc) * 32 + qd * 8);

    #pragma unroll
    for (int mt = 0; mt < 4; mt++) {
      bf16x8 aef = *(const bf16x8*)&s_ef[mt * 16 + lc][(qd & 1) * 8];
      #pragma unroll
      for (int nt = 0; nt < 2; nt++) {
        bf16x8 az = *(const bf16x8*)(pz[mt] + cb + nt * 16);
        f32x4 z; z[0] = 0.f; z[1] = 0.f; z[2] = 0.f; z[3] = 0.f;
        f32x4 acc = __builtin_amdgcn_mfma_f32_16x16x32_bf16(az, bI, z, 0, 0, 0);
        acc = __builtin_amdgcn_mfma_f32_16x16x32_bf16(aef, bw[nt], acc, 0, 0, 0);
        bf16x2 p0, p1;
        p0[0] = (__bf16)silu_f(acc[0]); p0[1] = (__bf16)silu_f(acc[1]);
        p1[0] = (__bf16)silu_f(acc[2]); p1[1] = (__bf16)silu_f(acc[3]);
        __bf16* wp = &s_hT[cb + nt * 16 + lc][mt * 16 + qd * 4];
        *(bf16x2*)wp = p0;
        *(bf16x2*)(wp + 2) = p1;
      }
    }
  }
  __syncthreads();

  // ---- one scan pass: 256 threads x 1 column x 64 rows, packed f32x2 acc ----
  {
    const unsigned int mlo = __builtin_amdgcn_readfirstlane(s_mask[0]);
    const unsigned int mhi = __builtin_amdgcn_readfirstlane(s_mask[1]);
    int j = tid;
    float2 accf = make_float2(0.f, 0.f);
    int cur = s_dst[0];
    #pragma unroll 8
    for (int i = 0; i < 64; i += 2) {
      bf16x2 p = *(const bf16x2*)&s_hT[j][i];
      bool b0 = (i < 32) ? ((mlo >> i) & 1u) : ((mhi >> (i - 32)) & 1u);
      int i1 = i + 1;
      bool b1 = (i1 < 32) ? ((mlo >> i1) & 1u) : ((mhi >> (i1 - 32)) & 1u);
      if ((i > 0 && b0) || b1) {          // wave-uniform slow path (rare)
        if (i > 0 && b0) {
          atomicAdd(&aggH[(size_t)cur * 256 + j], accf.x + accf.y);
          accf.x = 0.f; accf.y = 0.f; cur = s_dst[i];
        }
        accf.x += (float)p[0];
        if (b1) {
          atomicAdd(&aggH[(size_t)cur * 256 + j], accf.x + accf.y);
          accf.x = 0.f; accf.y = 0.f; cur = s_dst[i1];
        }
        accf.y += (float)p[1];
      } else {                            // fast path: packed cvt + packed add
        accf.x += (float)p[0];
        accf.y += (float)p[1];
      }
    }
    atomicAdd(&aggH[(size_t)cur * 256 + j], accf.x + accf.y);
  }
}

// ---------------- fused node update MLP v4: 512 threads, 64 nodes + next-layer zprep ----------------
__global__ __launch_bounds__(512, 2) void upd_mfma_kernel(
    float* __restrict__ h, __bf16* __restrict__ hb,
    float* __restrict__ aggH, const float* __restrict__ degf,
    const __bf16* __restrict__ uW1ft, const float* __restrict__ b1,
    const float* __restrict__ b2u,
    const __bf16* __restrict__ uW2t, const float* __restrict__ b2,
    int do_z, const float* __restrict__ nb1,
    const __bf16* __restrict__ nW1at, const __bf16* __restrict__ nW1bt,
    __bf16* __restrict__ z1b, __bf16* __restrict__ z2b)
{
  __shared__ __bf16 s_u[64][392];    // [h(128) | agg(256)] + 8 pad
  __shared__ __bf16 s_uh[64][264];   // 256 hidden cols + 8 pad
  int tid = threadIdx.x, n0 = blockIdx.x * 64;
  {
    int n = tid >> 3, t8 = tid & 7;  // 8 threads per node
    const bf16x8* hr = (const bf16x8*)(hb + (size_t)(n0 + n) * 128);
    #pragma unroll
    for (int i = 0; i < 2; i++)
      *(bf16x8*)&s_u[n][t8 * 8 + 64 * i] = hr[t8 + 8 * i];
    const float* sr = aggH + (size_t)(n0 + n) * 256;
    #pragma unroll
    for (int i = 0; i < 4; i++) {
      int col = t8 * 8 + i * 64;
      float4 a = *(const float4*)(sr + col);
      float4 b = *(const float4*)(sr + col + 4);
      bf16x8 o;
      o[0] = (__bf16)a.x; o[1] = (__bf16)a.y; o[2] = (__bf16)a.z; o[3] = (__bf16)a.w;
      o[4] = (__bf16)b.x; o[5] = (__bf16)b.y; o[6] = (__bf16)b.z; o[7] = (__bf16)b.w;
      *(bf16x8*)&s_u[n][128 + col] = o;
    }
  }
  __syncthreads();
  const int wv = tid >> 6, ln = tid & 63, lc = ln & 15, qd = ln >> 4;  // wv 0..7

  float dg[4][4];
  #pragma unroll
  for (int mt = 0; mt < 4; mt++)
    #pragma unroll
    for (int r = 0; r < 4; r++)
      dg[mt][r] = degf[n0 + mt * 16 + qd * 4 + r];

  // ---- GEMM1: K=384, wave owns cols wv*32 + nt*16 + lc ----
  {
    f32x4 acc1[4][2];
    #pragma unroll
    for (int nt = 0; nt < 2; nt++) {
      int c = wv * 32 + nt * 16 + lc;
      float bv = b1[c];
      float b2uv = b2u[c];
      #pragma unroll
      for (int mt = 0; mt < 4; mt++)
        #pragma unroll
        for (int r = 0; r < 4; r++)
          acc1[mt][nt][r] = bv + dg[mt][r] * b2uv;
    }
    #pragma unroll
    for (int kt = 0; kt < 12; kt++) {
      bf16x8 af[4];
      #pragma unroll
      for (int mt = 0; mt < 4; mt++)
        af[mt] = *(const bf16x8*)&s_u[mt * 16 + lc][kt * 32 + qd * 8];
      bf16x8 bw[2];
      #pragma unroll
      for (int nt = 0; nt < 2; nt++)
        bw[nt] = *(const bf16x8*)(uW1ft +
                 (size_t)(wv * 32 + nt * 16 + lc) * 384 + kt * 32 + qd * 8);
      #pragma unroll
      for (int mt = 0; mt < 4; mt++)
        #pragma unroll
        for (int nt = 0; nt < 2; nt++)
          acc1[mt][nt] = __builtin_amdgcn_mfma_f32_16x16x32_bf16(af[mt], bw[nt], acc1[mt][nt], 0, 0, 0);
    }
    #pragma unroll
    for (int mt = 0; mt < 4; mt++)
      #pragma unroll
      for (int nt = 0; nt < 2; nt++) {
        int cc = wv * 32 + nt * 16 + lc;
        #pragma unroll
        for (int r = 0; r < 4; r++)
          s_uh[mt * 16 + qd * 4 + r][cc] = (__bf16)silu_f(acc1[mt][nt][r]);
      }
  }
  __syncthreads();

  // ---- GEMM2: K=256, wave owns output cols ow = wv*16 + lc ----
  const int ow = wv * 16 + lc;
  f32x4 acc2[4];
  {
    float bv = b2[ow];
    #pragma unroll
    for (int mt = 0; mt < 4; mt++) {
      acc2[mt][0] = bv; acc2[mt][1] = bv; acc2[mt][2] = bv; acc2[mt][3] = bv;
    }
  }
  #pragma unroll
  for (int kt = 0; kt < 8; kt++) {
    bf16x8 a2[4];
    #pragma unroll
    for (int mt = 0; mt < 4; mt++)
      a2[mt] = *(const bf16x8*)&s_uh[mt * 16 + lc][kt * 32 + qd * 8];
    bf16x8 b2w = *(const bf16x8*)(uW2t + (size_t)ow * 256 + kt * 32 + qd * 8);
    #pragma unroll
    for (int mt = 0; mt < 4; mt++)
      acc2[mt] = __builtin_amdgcn_mfma_f32_16x16x32_bf16(a2[mt], b2w, acc2[mt], 0, 0, 0);
  }

  // residual epilogue
  #pragma unroll
  for (int mt = 0; mt < 4; mt++)
    #pragma unroll
    for (int r = 0; r < 4; r++) {
      int n = n0 + mt * 16 + qd * 4 + r;
      float v = h[(size_t)n * 128 + ow] + acc2[mt][r];
      h[(size_t)n * 128 + ow] = v;
      hb[(size_t)n * 128 + ow] = (__bf16)v;
    }

  // ---- fused zprep for next layer ----
  if (do_z) {
    __syncthreads();
    {
      float4 zz = make_float4(0.f, 0.f, 0.f, 0.f);
      float4* ap = (float4*)(aggH + (size_t)n0 * 256);
      for (int i = tid; i < 64 * 256 / 4; i += 512) ap[i] = zz;
      int n = tid >> 3, t8 = tid & 7;
      const bf16x8* hr = (const bf16x8*)(hb + (size_t)(n0 + n) * 128);
      #pragma unroll
      for (int i = 0; i < 2; i++)
        *(bf16x8*)&s_u[n][t8 * 8 + 64 * i] = hr[t8 + 8 * i];
    }
    __syncthreads();
    f32x4 aA[4][2], aB[4][2];
    #pragma unroll
    for (int nt = 0; nt < 2; nt++) {
      float bv = nb1[wv * 32 + nt * 16 + lc];
      #pragma unroll
      for (int mt = 0; mt < 4; mt++) {
        aA[mt][nt][0] = 0.f; aA[mt][nt][1] = 0.f;
        aA[mt][nt][2] = 0.f; aA[mt][nt][3] = 0.f;
        aB[mt][nt][0] = bv; aB[mt][nt][1] = bv;
        aB[mt][nt][2] = bv; aB[mt][nt][3] = bv;
      }
    }
    #pragma unroll
    for (int kt = 0; kt < 4; kt++) {
      bf16x8 af[4];
      #pragma unroll
      for (int mt = 0; mt < 4; mt++)
        af[mt] = *(const bf16x8*)&s_u[mt * 16 + lc][kt * 32 + qd * 8];
      bf16x8 bwA[2], bwB[2];
      #pragma unroll
      for (int nt = 0; nt < 2; nt++) {
        int c = wv * 32 + nt * 16 + lc;
        bwA[nt] = *(const bf16x8*)(nW1at + (size_t)c * 128 + kt * 32 + qd * 8);
        bwB[nt] = *(const bf16x8*)(nW1bt + (size_t)c * 128 + kt * 32 + qd * 8);
      }
      #pragma unroll
      for (int mt = 0; mt < 4; mt++)
        #pragma unroll
        for (int nt = 0; nt < 2; nt++) {
          aA[mt][nt] = __builtin_amdgcn_mfma_f32_16x16x32_bf16(af[mt], bwA[nt], aA[mt][nt], 0, 0, 0);
          aB[mt][nt] = __builtin_amdgcn_mfma_f32_16x16x32_bf16(af[mt], bwB[nt], aB[mt][nt], 0, 0, 0);
        }
    }
    #pragma unroll
    for (int mt = 0; mt < 4; mt++)
      #pragma unroll
      for (int nt = 0; nt < 2; nt++) {
        int c = wv * 32 + nt * 16 + lc;
        #pragma unroll
        for (int r = 0; r < 4; r++) {
          int n = n0 + mt * 16 + qd * 4 + r;
          z1b[(size_t)n * 256 + c] = (__bf16)aA[mt][nt][r];
          z2b[(size_t)n * 256 + c] = (__bf16)aB[mt][nt][r];
        }
      }
  }
}

// ---------------- readout ----------------
__global__ __launch_bounds__(128) void readout_sum_kernel(
    const float* __restrict__ h, const int* __restrict__ batch,
    float* __restrict__ gsum, float* __restrict__ gcnt)
{
  int j = threadIdx.x;
  int n0 = blockIdx.x * 128;
  float acc = 0.f, cacc = 0.f;
  int cur = batch[n0];
  for (int i = 0; i < 128; i++) {
    int b = batch[n0 + i];
    if (b != cur) {
      atomicAdd(&gsum[cur * 128 + j], acc);
      if (j == 0) atomicAdd(&gcnt[cur], cacc);
      acc = 0.f; cacc = 0.f; cur = b;
    }
    acc += h[(size_t)(n0 + i) * 128 + j];
    cacc += 1.f;
  }
  atomicAdd(&gsum[cur * 128 + j], acc);
  if (j == 0) atomicAdd(&gcnt[cur], cacc);
}

__global__ __launch_bounds__(256) void readout_mlp_kernel(
    const float* __restrict__ gsum, const float* __restrict__ gcnt,
    const float* __restrict__ W1, const float* __restrict__ b1,
    const float* __restrict__ W2, const float* __restrict__ b2,
    float* __restrict__ out)
{
  __shared__ float g[8][128];
  __shared__ float hid[8][256];
  int tid = threadIdx.x;
  for (int i = tid; i < 8 * 128; i += 256) {
    int b = i >> 7, c = i & 127;
    g[b][c] = gsum[i] / fmaxf(gcnt[b], 1.0f);
  }
  __syncthreads();
  {
    float bb = b1[tid];
    float a[8];
    #pragma unroll
    for (int b = 0; b < 8; b++) a[b] = bb;
    for (int k = 0; k < 128; k++) {
      float w = W1[k * 256 + tid];
      #pragma unroll
      for (int b = 0; b < 8; b++) a[b] += g[b][k] * w;
    }
    #pragma unroll
    for (int b = 0; b < 8; b++) hid[b][tid] = silu_f(a[b]);
  }
  __syncthreads();
  int j = tid & 63, bg = tid >> 6;
  float a0 = b2[j], a1 = b2[j];
  for (int k = 0; k < 256; k++) {
    float w = W2[k * 64 + j];
    a0 += hid[bg * 2 + 0][k] * w;
    a1 += hid[bg * 2 + 1][k] * w;
  }
  out[(bg * 2 + 0) * 64 + j] = a0;
  out[(bg * 2 + 1) * 64 + j] = a1;
}

extern "C" void kernel_launch(void* const* d_in, const int* in_sizes, int n_in,
                              void* d_out, int out_size, void* d_ws, size_t ws_size,
                              hipStream_t stream) {
  const float* pos   = (const float*)d_in[0];
  const float* xfeat = (const float*)d_in[1];
  const int*   eidx  = (const int*)d_in[2];
  const int*   batch = (const int*)d_in[3];
  const float* eW1 = (const float*)d_in[4];
  const float* eb1 = (const float*)d_in[5];
  const float* eW2 = (const float*)d_in[6];
  const float* eb2 = (const float*)d_in[7];
  const float* mW1 = (const float*)d_in[8];
  const float* mb1 = (const float*)d_in[9];
  const float* mW2 = (const float*)d_in[10];
  const float* mb2 = (const float*)d_in[11];
  const float* uW1 = (const float*)d_in[12];
  const float* ub1 = (const float*)d_in[13];
  const float* uW2 = (const float*)d_in[14];
  const float* ub2 = (const float*)d_in[15];
  const float* rW1 = (const float*)d_in[16];
  const float* rb1 = (const float*)d_in[17];
  const float* rW2 = (const float*)d_in[18];
  const float* rb2 = (const float*)d_in[19];

  const int* srcI = eidx;
  const int* dstI = eidx + NEDGES;

  char* base = (char*)d_ws;
  float* h    = (float*)base;  base += (size_t)NATOMS * 128 * 4;
  float* aggH = (float*)base;  base += (size_t)NATOMS * 256 * 4;
  __bf16* z1b = (__bf16*)base; base += (size_t)NATOMS * 256 * 2;
  __bf16* z2b = (__bf16*)base; base += (size_t)NATOMS * 256 * 2;
  __bf16* hb  = (__bf16*)base; base += (size_t)NATOMS * 128 * 2;
  __bf16* efb = (__bf16*)base; base += (size_t)NEDGES * 16 * 2;
  __bf16* W1at = (__bf16*)base; base += (size_t)NLAYERS * 256 * 128 * 2;
  __bf16* W1bt = (__bf16*)base; base += (size_t)NLAYERS * 256 * 128 * 2;
  __bf16* B2c  = (__bf16*)base; base += (size_t)NLAYERS * 256 * 32 * 2;
  __bf16* uW1ft = (__bf16*)base; base += (size_t)NLAYERS * 256 * 384 * 2;
  __bf16* uW2t = (__bf16*)base; base += (size_t)NLAYERS * 128 * 256 * 2;
  float* b2u  = (float*)base;  base += (size_t)NLAYERS * 256 * 4;
  float* degf = (float*)base;  base += (size_t)NATOMS * 4;
  float* gsum = (float*)base;  base += 8 * 128 * 4;
  float* gcnt = (float*)base;  base += 8 * 4;
  int* counts = (int*)base;    base += (size_t)NATOMS * 4;
  int* cursor = (int*)base;    base += (size_t)NATOMS * 4;
  int* esrc   = (int*)base;    base += (size_t)NEDGES * 4;
  int* edst   = (int*)base;    base += (size_t)NEDGES * 4;

  // counts must be zeroed before front_kernel's hist section
  hipMemsetAsync(counts, 0, NATOMS * sizeof(int), stream);

  // merged front: weight prep + dst histogram + embedding
  front_kernel<<<NB_PREP + NB_HIST + NB_EMB, 256, 0, stream>>>(
      mW1, mW2, uW1, uW2, mb2, W1at, W1bt, B2c, uW1ft, uW2t, b2u,
      dstI, counts, xfeat, eW1, eb1, eW2, eb2, h, hb);

  scan_kernel<<<1, 1024, 0, stream>>>(counts, cursor, degf);
  scatter_kernel<<<NEDGES / 256, 256, 0, stream>>>(srcI, dstI, cursor, esrc, edst);
  rbf_kernel<<<NEDGES / 256, 256, 0, stream>>>(pos, esrc, edst, efb);

  // zprep for layer 0 (also zeros aggH)
  zprep_kernel<<<NATOMS / 64, 256, 0, stream>>>(
      hb, mb1, W1at, W1bt, z1b, z2b, aggH);

  for (int l = 0; l < NLAYERS; l++) {
    int ln = (l < NLAYERS - 1) ? (l + 1) : l;
    msg_mfma_kernel<<<NEDGES / TE, 256, 0, stream>>>(
        z1b, z2b, efb, esrc, edst,
        B2c + (size_t)l * 256 * 32, aggH);
    upd_mfma_kernel<<<NATOMS / 64, 512, 0, stream>>>(
        h, hb, aggH, degf,
        uW1ft + (size_t)l * 256 * 384, ub1 + (size_t)l * 256,
        b2u + (size_t)l * 256,
        uW2t + (size_t)l * 128 * 256, ub2 + (size_t)l * 128,
        (l < NLAYERS - 1) ? 1 : 0,
        mb1 + (size_t)ln * 256,
        W1at + (size_t)ln * 256 * 128, W1bt + (size_t)ln * 256 * 128,
        z1b, z2b);
  }

  hipMemsetAsync(gsum, 0, (8 * 128 + 8) * sizeof(float), stream);
  readout_sum_kernel<<<NATOMS / 128, 128, 0, stream>>>(h, batch, gsum, gcnt);
  readout_mlp_kernel<<<1, 256, 0, stream>>>(gsum, gcnt, rW1, rb1, rW2, rb2,
                                            (float*)d_out);
}

// Round 16
// 667.341 us; speedup vs baseline: 1.1888x; 1.0087x over previous
//
#include <hip/hip_runtime.h>
#include <math.h>

#define NATOMS 16384
#define NEDGES 524288
#define NLAYERS 4
#define TE 64      // edges per block in msg kernel

typedef __bf16 bf16x8 __attribute__((ext_vector_type(8)));
typedef __bf16 bf16x4 __attribute__((ext_vector_type(4)));
typedef __bf16 bf16x2 __attribute__((ext_vector_type(2)));
typedef float f32x4 __attribute__((ext_vector_type(4)));

// fast silu: x * rcp(1+exp(-x))
__device__ __forceinline__ float silu_f(float x) {
  return x * __builtin_amdgcn_rcpf(1.0f + __expf(-x));
}

// ---------------- CSR preprocessing ----------------
__global__ __launch_bounds__(1024) void scan_kernel(
    const int* __restrict__ counts, int* __restrict__ cursor,
    float* __restrict__ degf)
{
  __shared__ int s_tot[1024];
  int tid = threadIdx.x;
  int v[16];
  {
    const int4* cp = (const int4*)(counts + tid * 16);
    int4 a = cp[0], b = cp[1], c = cp[2], d = cp[3];
    v[0]=a.x; v[1]=a.y; v[2]=a.z; v[3]=a.w;
    v[4]=b.x; v[5]=b.y; v[6]=b.z; v[7]=b.w;
    v[8]=c.x; v[9]=c.y; v[10]=c.z; v[11]=c.w;
    v[12]=d.x; v[13]=d.y; v[14]=d.z; v[15]=d.w;
  }
  int tot = 0;
  #pragma unroll
  for (int i = 0; i < 16; i++) tot += v[i];
  s_tot[tid] = tot;
  __syncthreads();
  for (int off = 1; off < 1024; off <<= 1) {
    int t = (tid >= off) ? s_tot[tid - off] : 0;
    __syncthreads();
    s_tot[tid] += t;
    __syncthreads();
  }
  int run = s_tot[tid] - tot;   // exclusive prefix
  #pragma unroll
  for (int i = 0; i < 16; i++) {
    cursor[tid * 16 + i] = run;
    degf[tid * 16 + i] = (float)v[i];
    run += v[i];
  }
}

__global__ __launch_bounds__(256) void scatter_kernel(
    const int* __restrict__ src, const int* __restrict__ dst,
    int* __restrict__ cursor, int* __restrict__ esrc, int* __restrict__ edst)
{
  int e = blockIdx.x * 256 + threadIdx.x;
  int d = dst[e];
  int p = atomicAdd(&cursor[d], 1);
  esrc[p] = src[e];
  edst[p] = d;
}

// ---------------- merged front kernel: weight prep + dst histogram + embed ----------------
// sections by flat blockIdx.x:
//   [0, 3204)        prep   (801 blocks x 4 layers)
//   [3204, 5252)     hist   (2048 blocks)
//   [5252, 13444)    embed  (8192 blocks, 2 nodes each)
#define NB_PREP (801 * NLAYERS)
#define NB_HIST (NEDGES / 256)
#define NB_EMB  (NATOMS / 2)

__global__ __launch_bounds__(256) void front_kernel(
    const float* __restrict__ mW1, const float* __restrict__ mW2,
    const float* __restrict__ uW1, const float* __restrict__ uW2,
    const float* __restrict__ mb2,
    __bf16* __restrict__ W1at, __bf16* __restrict__ W1bt,
    __bf16* __restrict__ B2c, __bf16* __restrict__ uW1ft,
    __bf16* __restrict__ uW2t, float* __restrict__ b2u,
    const int* __restrict__ dstI, int* __restrict__ counts,
    const float* __restrict__ x, const float* __restrict__ eW1,
    const float* __restrict__ eb1, const float* __restrict__ eW2,
    const float* __restrict__ eb2, float* __restrict__ h,
    __bf16* __restrict__ hb)
{
  __shared__ float xs[2][26];
  __shared__ float hid[2][132];
  int bxf = blockIdx.x, tid = threadIdx.x;

  if (bxf < NB_PREP) {
    long l = bxf / 801;
    int bx = bxf - (int)l * 801;
    if (bx < 128) {
      int i = bx * 256 + tid;              // 256*128
      int n = i >> 7, k = i & 127;
      W1at[l * (256L * 128) + i] = (__bf16)mW1[l * (272L * 256) + (size_t)k * 256 + n];
    } else if (bx < 256) {
      int i = (bx - 128) * 256 + tid;
      int n = i >> 7, k = i & 127;
      W1bt[l * (256L * 128) + i] = (__bf16)mW1[l * (272L * 256) + (size_t)(128 + k) * 256 + n];
    } else if (bx < 288) {
      int i = (bx - 256) * 256 + tid;      // 256*32
      int c = i >> 5, k = i & 31;
      float v = (k < 16) ? mW1[l * (272L * 256) + (size_t)(256 + k) * 256 + c] : 0.0f;
      B2c[l * (256L * 32) + i] = (__bf16)v;
    } else if (bx < 672) {
      // block = one k (384 per layer), threads = n: coalesced reads, scalar mW2
      int k = bx - 288;                    // 0..383
      int n = tid;                         // 0..255
      float v;
      if (k < 128) {
        v = uW1[l * 65536 + (size_t)k * 256 + n];
      } else {
        int r = k - 128;
        v = 0.0f;
        for (int j = 0; j < 128; j++)
          v += mW2[(l * 256 + r) * 128 + j] * uW1[l * 65536 + (size_t)(128 + j) * 256 + n];
      }
      uW1ft[l * (256L * 384) + (size_t)n * 384 + k] = (__bf16)v;
    } else if (bx < 800) {
      int i = (bx - 672) * 256 + tid;      // 128*256
      int n = i >> 8, k = i & 255;
      uW2t[l * (128L * 256) + i] = (__bf16)uW2[l * (256L * 128) + (size_t)k * 128 + n];
    } else {
      int c = tid;
      float acc = 0.0f;
      for (int j = 0; j < 128; j++)
        acc += mb2[l * 128 + j] * uW1[l * 65536 + (size_t)(128 + j) * 256 + c];
      b2u[l * 256 + c] = acc;
    }
  } else if (bxf < NB_PREP + NB_HIST) {
    int e = (bxf - NB_PREP) * 256 + tid;
    atomicAdd(&counts[dstI[e]], 1);
  } else {
    int nb = bxf - (NB_PREP + NB_HIST);
    int hf = tid >> 7, j = tid & 127;
    int n = nb * 2 + hf;
    if (j < 26) xs[hf][j] = x[(size_t)n * 26 + j];
    __syncthreads();
    float acc = eb1[j];
    #pragma unroll
    for (int k = 0; k < 26; k++) acc += xs[hf][k] * eW1[k * 128 + j];
    hid[hf][j] = silu_f(acc);
    __syncthreads();
    float acc2 = eb2[j];
    #pragma unroll 8
    for (int k = 0; k < 128; k++) acc2 += hid[hf][k] * eW2[k * 128 + j];
    h[(size_t)n * 128 + j] = acc2;
    hb[(size_t)n * 128 + j] = (__bf16)acc2;
  }
}

// ---------------- edge RBF (sorted slot order) ----------------
__global__ __launch_bounds__(256) void rbf_kernel(
    const float* __restrict__ pos, const int* __restrict__ esrc,
    const int* __restrict__ edst, __bf16* __restrict__ efb)
{
  int e = blockIdx.x * 256 + threadIdx.x;
  int s = esrc[e], d = edst[e];
  float dx = pos[d * 3 + 0] - pos[s * 3 + 0];
  float dy = pos[d * 3 + 1] - pos[s * 3 + 1];
  float dz = pos[d * 3 + 2] - pos[s * 3 + 2];
  float dist = sqrtf(dx * dx + dy * dy + dz * dz + 1e-12f);
  float env = (dist < 10.0f)
                  ? 0.5f * (cosf(3.14159265358979f * dist * 0.1f) + 1.0f)
                  : 0.0f;
  bf16x8 o0, o1;
  #pragma unroll
  for (int i = 0; i < 16; i++) {
    float c = (10.0f / 15.0f) * (float)i;
    float t = dist - c;
    float v = env * __expf(-t * t * 1.28f);
    if (i < 8) o0[i] = (__bf16)v; else o1[i - 8] = (__bf16)v;
  }
  *(bf16x8*)(efb + (size_t)e * 16 + 0) = o0;
  *(bf16x8*)(efb + (size_t)e * 16 + 8) = o1;
}

// ---------------- zprep (layer 0 only): z1b, z2b; zeros aggH ----------------
__global__ __launch_bounds__(256) void zprep_kernel(
    const __bf16* __restrict__ hb, const float* __restrict__ b1,
    const __bf16* __restrict__ W1at, const __bf16* __restrict__ W1bt,
    __bf16* __restrict__ z1b, __bf16* __restrict__ z2b, float* __restrict__ aggH)
{
  __shared__ __bf16 s_n[64][136];
  int tid = threadIdx.x, n0 = blockIdx.x * 64;
  {
    int n = tid >> 2, t4 = tid & 3;
    const bf16x8* hr = (const bf16x8*)(hb + (size_t)(n0 + n) * 128);
    #pragma unroll
    for (int i = 0; i < 4; i++)
      *(bf16x8*)&s_n[n][t4 * 8 + 32 * i] = hr[t4 + 4 * i];
  }
  {
    float4 zz = make_float4(0.f, 0.f, 0.f, 0.f);
    float4* ap = (float4*)(aggH + (size_t)n0 * 256);
    for (int i = tid; i < 64 * 256 / 4; i += 256) ap[i] = zz;
  }
  __syncthreads();
  const int wv = tid >> 6, ln = tid & 63, lc = ln & 15, qd = ln >> 4;
  for (int cp = 0; cp < 2; cp++) {
    f32x4 aA[4][2], aB[4][2];
    #pragma unroll
    for (int nt = 0; nt < 2; nt++) {
      float bv = b1[cp * 128 + wv * 32 + nt * 16 + lc];
      #pragma unroll
      for (int mt = 0; mt < 4; mt++) {
        aA[mt][nt][0] = 0.f; aA[mt][nt][1] = 0.f;
        aA[mt][nt][2] = 0.f; aA[mt][nt][3] = 0.f;
        aB[mt][nt][0] = bv; aB[mt][nt][1] = bv;
        aB[mt][nt][2] = bv; aB[mt][nt][3] = bv;
      }
    }
    #pragma unroll
    for (int kt = 0; kt < 4; kt++) {
      bf16x8 af[4];
      #pragma unroll
      for (int mt = 0; mt < 4; mt++)
        af[mt] = *(const bf16x8*)&s_n[mt * 16 + lc][kt * 32 + qd * 8];
      bf16x8 bwA[2], bwB[2];
      #pragma unroll
      for (int nt = 0; nt < 2; nt++) {
        int c = cp * 128 + wv * 32 + nt * 16 + lc;
        bwA[nt] = *(const bf16x8*)(W1at + (size_t)c * 128 + kt * 32 + qd * 8);
        bwB[nt] = *(const bf16x8*)(W1bt + (size_t)c * 128 + kt * 32 + qd * 8);
      }
      #pragma unroll
      for (int mt = 0; mt < 4; mt++)
        #pragma unroll
        for (int nt = 0; nt < 2; nt++) {
          aA[mt][nt] = __builtin_amdgcn_mfma_f32_16x16x32_bf16(af[mt], bwA[nt], aA[mt][nt], 0, 0, 0);
          aB[mt][nt] = __builtin_amdgcn_mfma_f32_16x16x32_bf16(af[mt], bwB[nt], aB[mt][nt], 0, 0, 0);
        }
    }
    #pragma unroll
    for (int mt = 0; mt < 4; mt++)
      #pragma unroll
      for (int nt = 0; nt < 2; nt++) {
        int c = cp * 128 + wv * 32 + nt * 16 + lc;
        #pragma unroll
        for (int r = 0; r < 4; r++) {
          int n = n0 + mt * 16 + qd * 4 + r;
          z1b[(size_t)n * 256 + c] = (__bf16)aA[mt][nt][r];
          z2b[(size_t)n * 256 + c] = (__bf16)aB[mt][nt][r];
        }
      }
  }
}

// ---------------- fused message kernel v7b: TE=64, packed-float2 scan ----------------
#define MS_EF_OFF   33792                 // s_hT 256*66*2 = 33792
#define MS_SRC_OFF  36864                 // s_ef 64*24*2 = 3072
#define MS_DST_OFF  37120
#define MS_MASK_OFF 37376
#define MS_BYTES    37392

__global__ __launch_bounds__(256, 4) void msg_mfma_kernel(
    const __bf16* __restrict__ z1b, const __bf16* __restrict__ z2b,
    const __bf16* __restrict__ efb,
    const int* __restrict__ esrc, const int* __restrict__ edst,
    const __bf16* __restrict__ B2c, float* __restrict__ aggH)
{
  __shared__ __align__(16) char smem[MS_BYTES];
  __bf16 (*s_hT)[66] = (__bf16(*)[66])(smem);          // [256 cols][64 rows + 2 pad]
  __bf16 (*s_ef)[24] = (__bf16(*)[24])(smem + MS_EF_OFF);
  int* s_src = (int*)(smem + MS_SRC_OFF);
  int* s_dst = (int*)(smem + MS_DST_OFF);
  unsigned int* s_mask = (unsigned int*)(smem + MS_MASK_OFF);

  int tid = threadIdx.x, e0 = blockIdx.x * TE;

  if (tid < TE) {
    int d = edst[e0 + tid];
    s_dst[tid] = d;
    int dp = (tid == 0) ? (d ^ 1) : edst[e0 + tid - 1];
    unsigned long long mb = __ballot(d != dp);
    if (tid == 0) { s_mask[0] = (unsigned int)mb; s_mask[1] = (unsigned int)(mb >> 32); }
  } else if (tid < 2 * TE) {
    s_src[tid - TE] = esrc[e0 + tid - TE];
  }
  {
    int e = tid >> 2, t4 = tid & 3;
    if (t4 < 2)
      *(bf16x8*)&s_ef[e][t4 * 8] =
          *(const bf16x8*)(efb + (size_t)(e0 + e) * 16 + t4 * 8);
  }
  __syncthreads();

  const int wv = tid >> 6, ln = tid & 63, lc = ln & 15, qd = ln >> 4;

  bf16x8 bI;
  #pragma unroll
  for (int j = 0; j < 8; j++)
    bI[j] = (__bf16)((lc == (qd & 1) * 8 + j) ? 1.0f : 0.0f);

  const __bf16* pz[4];
  #pragma unroll
  for (int mt = 0; mt < 4; mt++) {
    int m = mt * 16 + lc;
    int row = (qd < 2) ? s_src[m] : s_dst[m];
    pz[mt] = ((qd < 2) ? z1b : z2b) + (size_t)row * 256 + (qd & 1) * 8;
  }

  // ---- compute both halves, no barrier between (disjoint s_hT cols) ----
  #pragma unroll
  for (int hf = 0; hf < 2; hf++) {
    const int cb = hf * 128 + wv * 32;
    bf16x8 bw[2];
    #pragma unroll
    for (int nt = 0; nt < 2; nt++)
      bw[nt] = *(const bf16x8*)(B2c + (size_t)(cb + nt * 16 + lc) * 32 + qd * 8);

    #pragma unroll
    for (int mt = 0; mt < 4; mt++) {
      bf16x8 aef = *(const bf16x8*)&s_ef[mt * 16 + lc][(qd & 1) * 8];
      #pragma unroll
      for (int nt = 0; nt < 2; nt++) {
        bf16x8 az = *(const bf16x8*)(pz[mt] + cb + nt * 16);
        f32x4 z; z[0] = 0.f; z[1] = 0.f; z[2] = 0.f; z[3] = 0.f;
        f32x4 acc = __builtin_amdgcn_mfma_f32_16x16x32_bf16(az, bI, z, 0, 0, 0);
        acc = __builtin_amdgcn_mfma_f32_16x16x32_bf16(aef, bw[nt], acc, 0, 0, 0);
        bf16x2 p0, p1;
        p0[0] = (__bf16)silu_f(acc[0]); p0[1] = (__bf16)silu_f(acc[1]);
        p1[0] = (__bf16)silu_f(acc[2]); p1[1] = (__bf16)silu_f(acc[3]);
        __bf16* wp = &s_hT[cb + nt * 16 + lc][mt * 16 + qd * 4];
        *(bf16x2*)wp = p0;
        *(bf16x2*)(wp + 2) = p1;
      }
    }
  }
  __syncthreads();

  // ---- one scan pass: 256 threads x 1 column x 64 rows, packed f32x2 acc ----
  {
    const unsigned int mlo = __builtin_amdgcn_readfirstlane(s_mask[0]);
    const unsigned int mhi = __builtin_amdgcn_readfirstlane(s_mask[1]);
    int j = tid;
    float2 accf = make_float2(0.f, 0.f);
    int cur = s_dst[0];
    #pragma unroll 8
    for (int i = 0; i < 64; i += 2) {
      bf16x2 p = *(const bf16x2*)&s_hT[j][i];
      bool b0 = (i < 32) ? ((mlo >> i) & 1u) : ((mhi >> (i - 32)) & 1u);
      int i1 = i + 1;
      bool b1 = (i1 < 32) ? ((mlo >> i1) & 1u) : ((mhi >> (i1 - 32)) & 1u);
      if ((i > 0 && b0) || b1) {          // wave-uniform slow path (rare)
        if (i > 0 && b0) {
          atomicAdd(&aggH[(size_t)cur * 256 + j], accf.x + accf.y);
          accf.x = 0.f; accf.y = 0.f; cur = s_dst[i];
        }
        accf.x += (float)p[0];
        if (b1) {
          atomicAdd(&aggH[(size_t)cur * 256 + j], accf.x + accf.y);
          accf.x = 0.f; accf.y = 0.f; cur = s_dst[i1];
        }
        accf.y += (float)p[1];
      } else {                            // fast path: packed cvt + packed add
        accf.x += (float)p[0];
        accf.y += (float)p[1];
      }
    }
    atomicAdd(&aggH[(size_t)cur * 256 + j], accf.x + accf.y);
  }
}

// ---------------- fused node update MLP v4: 512 threads, 64 nodes + next-layer zprep ----------------
__global__ __launch_bounds__(512, 2) void upd_mfma_kernel(
    float* __restrict__ h, __bf16* __restrict__ hb,
    float* __restrict__ aggH, const float* __restrict__ degf,
    const __bf16* __restrict__ uW1ft, const float* __restrict__ b1,
    const float* __restrict__ b2u,
    const __bf16* __restrict__ uW2t, const float* __restrict__ b2,
    int do_z, const float* __restrict__ nb1,
    const __bf16* __restrict__ nW1at, const __bf16* __restrict__ nW1bt,
    __bf16* __restrict__ z1b, __bf16* __restrict__ z2b)
{
  __shared__ __bf16 s_u[64][392];    // [h(128) | agg(256)] + 8 pad
  __shared__ __bf16 s_uh[64][264];   // 256 hidden cols + 8 pad
  int tid = threadIdx.x, n0 = blockIdx.x * 64;
  {
    int n = tid >> 3, t8 = tid & 7;  // 8 threads per node
    const bf16x8* hr = (const bf16x8*)(hb + (size_t)(n0 + n) * 128);
    #pragma unroll
    for (int i = 0; i < 2; i++)
      *(bf16x8*)&s_u[n][t8 * 8 + 64 * i] = hr[t8 + 8 * i];
    const float* sr = aggH + (size_t)(n0 + n) * 256;
    #pragma unroll
    for (int i = 0; i < 4; i++) {
      int col = t8 * 8 + i * 64;
      float4 a = *(const float4*)(sr + col);
      float4 b = *(const float4*)(sr + col + 4);
      bf16x8 o;
      o[0] = (__bf16)a.x; o[1] = (__bf16)a.y; o[2] = (__bf16)a.z; o[3] = (__bf16)a.w;
      o[4] = (__bf16)b.x; o[5] = (__bf16)b.y; o[6] = (__bf16)b.z; o[7] = (__bf16)b.w;
      *(bf16x8*)&s_u[n][128 + col] = o;
    }
  }
  __syncthreads();
  const int wv = tid >> 6, ln = tid & 63, lc = ln & 15, qd = ln >> 4;  // wv 0..7

  float dg[4][4];
  #pragma unroll
  for (int mt = 0; mt < 4; mt++)
    #pragma unroll
    for (int r = 0; r < 4; r++)
      dg[mt][r] = degf[n0 + mt * 16 + qd * 4 + r];

  // ---- GEMM1: K=384, wave owns cols wv*32 + nt*16 + lc ----
  {
    f32x4 acc1[4][2];
    #pragma unroll
    for (int nt = 0; nt < 2; nt++) {
      int c = wv * 32 + nt * 16 + lc;
      float bv = b1[c];
      float b2uv = b2u[c];
      #pragma unroll
      for (int mt = 0; mt < 4; mt++)
        #pragma unroll
        for (int r = 0; r < 4; r++)
          acc1[mt][nt][r] = bv + dg[mt][r] * b2uv;
    }
    #pragma unroll
    for (int kt = 0; kt < 12; kt++) {
      bf16x8 af[4];
      #pragma unroll
      for (int mt = 0; mt < 4; mt++)
        af[mt] = *(const bf16x8*)&s_u[mt * 16 + lc][kt * 32 + qd * 8];
      bf16x8 bw[2];
      #pragma unroll
      for (int nt = 0; nt < 2; nt++)
        bw[nt] = *(const bf16x8*)(uW1ft +
                 (size_t)(wv * 32 + nt * 16 + lc) * 384 + kt * 32 + qd * 8);
      #pragma unroll
      for (int mt = 0; mt < 4; mt++)
        #pragma unroll
        for (int nt = 0; nt < 2; nt++)
          acc1[mt][nt] = __builtin_amdgcn_mfma_f32_16x16x32_bf16(af[mt], bw[nt], acc1[mt][nt], 0, 0, 0);
    }
    #pragma unroll
    for (int mt = 0; mt < 4; mt++)
      #pragma unroll
      for (int nt = 0; nt < 2; nt++) {
        int cc = wv * 32 + nt * 16 + lc;
        #pragma unroll
        for (int r = 0; r < 4; r++)
          s_uh[mt * 16 + qd * 4 + r][cc] = (__bf16)silu_f(acc1[mt][nt][r]);
      }
  }
  __syncthreads();

  // ---- GEMM2: K=256, wave owns output cols ow = wv*16 + lc ----
  const int ow = wv * 16 + lc;
  f32x4 acc2[4];
  {
    float bv = b2[ow];
    #pragma unroll
    for (int mt = 0; mt < 4; mt++) {
      acc2[mt][0] = bv; acc2[mt][1] = bv; acc2[mt][2] = bv; acc2[mt][3] = bv;
    }
  }
  #pragma unroll
  for (int kt = 0; kt < 8; kt++) {
    bf16x8 a2[4];
    #pragma unroll
    for (int mt = 0; mt < 4; mt++)
      a2[mt] = *(const bf16x8*)&s_uh[mt * 16 + lc][kt * 32 + qd * 8];
    bf16x8 b2w = *(const bf16x8*)(uW2t + (size_t)ow * 256 + kt * 32 + qd * 8);
    #pragma unroll
    for (int mt = 0; mt < 4; mt++)
      acc2[mt] = __builtin_amdgcn_mfma_f32_16x16x32_bf16(a2[mt], b2w, acc2[mt], 0, 0, 0);
  }

  // residual epilogue
  #pragma unroll
  for (int mt = 0; mt < 4; mt++)
    #pragma unroll
    for (int r = 0; r < 4; r++) {
      int n = n0 + mt * 16 + qd * 4 + r;
      float v = h[(size_t)n * 128 + ow] + acc2[mt][r];
      h[(size_t)n * 128 + ow] = v;
      hb[(size_t)n * 128 + ow] = (__bf16)v;
    }

  // ---- fused zprep for next layer ----
  if (do_z) {
    __syncthreads();
    {
      float4 zz = make_float4(0.f, 0.f, 0.f, 0.f);
      float4* ap = (float4*)(aggH + (size_t)n0 * 256);
      for (int i = tid; i < 64 * 256 / 4; i += 512) ap[i] = zz;
      int n = tid >> 3, t8 = tid & 7;
      const bf16x8* hr = (const bf16x8*)(hb + (size_t)(n0 + n) * 128);
      #pragma unroll
      for (int i = 0; i < 2; i++)
        *(bf16x8*)&s_u[n][t8 * 8 + 64 * i] = hr[t8 + 8 * i];
    }
    __syncthreads();
    f32x4 aA[4][2], aB[4][2];
    #pragma unroll
    for (int nt = 0; nt < 2; nt++) {
      float bv = nb1[wv * 32 + nt * 16 + lc];
      #pragma unroll
      for (int mt = 0; mt < 4; mt++) {
        aA[mt][nt][0] = 0.f; aA[mt][nt][1] = 0.f;
        aA[mt][nt][2] = 0.f; aA[mt][nt][3] = 0.f;
        aB[mt][nt][0] = bv; aB[mt][nt][1] = bv;
        aB[mt][nt][2] = bv; aB[mt][nt][3] = bv;
      }
    }
    #pragma unroll
    for (int kt = 0; kt < 4; kt++) {
      bf16x8 af[4];
      #pragma unroll
      for (int mt = 0; mt < 4; mt++)
        af[mt] = *(const bf16x8*)&s_u[mt * 16 + lc][kt * 32 + qd * 8];
      bf16x8 bwA[2], bwB[2];
      #pragma unroll
      for (int nt = 0; nt < 2; nt++) {
        int c = wv * 32 + nt * 16 + lc;
        bwA[nt] = *(const bf16x8*)(nW1at + (size_t)c * 128 + kt * 32 + qd * 8);
        bwB[nt] = *(const bf16x8*)(nW1bt + (size_t)c * 128 + kt * 32 + qd * 8);
      }
      #pragma unroll
      for (int mt = 0; mt < 4; mt++)
        #pragma unroll
        for (int nt = 0; nt < 2; nt++) {
          aA[mt][nt] = __builtin_amdgcn_mfma_f32_16x16x32_bf16(af[mt], bwA[nt], aA[mt][nt], 0, 0, 0);
          aB[mt][nt] = __builtin_amdgcn_mfma_f32_16x16x32_bf16(af[mt], bwB[nt], aB[mt][nt], 0, 0, 0);
        }
    }
    #pragma unroll
    for (int mt = 0; mt < 4; mt++)
      #pragma unroll
      for (int nt = 0; nt < 2; nt++) {
        int c = wv * 32 + nt * 16 + lc;
        #pragma unroll
        for (int r = 0; r < 4; r++) {
          int n = n0 + mt * 16 + qd * 4 + r;
          z1b[(size_t)n * 256 + c] = (__bf16)aA[mt][nt][r];
          z2b[(size_t)n * 256 + c] = (__bf16)aB[mt][nt][r];
        }
      }
  }
}

// ---------------- readout ----------------
__global__ __launch_bounds__(128) void readout_sum_kernel(
    const float* __restrict__ h, const int* __restrict__ batch,
    float* __restrict__ gsum, float* __restrict__ gcnt)
{
  int j = threadIdx.x;
  int n0 = blockIdx.x * 128;
  float acc = 0.f, cacc = 0.f;
  int cur = batch[n0];
  for (int i = 0; i < 128; i++) {
    int b = batch[n0 + i];
    if (b != cur) {
      atomicAdd(&gsum[cur * 128 + j], acc);
      if (j == 0) atomicAdd(&gcnt[cur], cacc);
      acc = 0.f; cacc = 0.f; cur = b;
    }
    acc += h[(size_t)(n0 + i) * 128 + j];
    cacc += 1.f;
  }
  atomicAdd(&gsum[cur * 128 + j], acc);
  if (j == 0) atomicAdd(&gcnt[cur], cacc);
}

__global__ __launch_bounds__(256) void readout_mlp_kernel(
    const float* __restrict__ gsum, const float* __restrict__ gcnt,
    const float* __restrict__ W1, const float* __restrict__ b1,
    const float* __restrict__ W2, const float* __restrict__ b2,
    float* __restrict__ out)
{
  __shared__ float g[8][128];
  __shared__ float hid[8][256];
  int tid = threadIdx.x;
  for (int i = tid; i < 8 * 128; i += 256) {
    int b = i >> 7, c = i & 127;
    g[b][c] = gsum[i] / fmaxf(gcnt[b], 1.0f);
  }
  __syncthreads();
  {
    float bb = b1[tid];
    float a[8];
    #pragma unroll
    for (int b = 0; b < 8; b++) a[b] = bb;
    for (int k = 0; k < 128; k++) {
      float w = W1[k * 256 + tid];
      #pragma unroll
      for (int b = 0; b < 8; b++) a[b] += g[b][k] * w;
    }
    #pragma unroll
    for (int b = 0; b < 8; b++) hid[b][tid] = silu_f(a[b]);
  }
  __syncthreads();
  int j = tid & 63, bg = tid >> 6;
  float a0 = b2[j], a1 = b2[j];
  for (int k = 0; k < 256; k++) {
    float w = W2[k * 64 + j];
    a0 += hid[bg * 2 + 0][k] * w;
    a1 += hid[bg * 2 + 1][k] * w;
  }
  out[(bg * 2 + 0) * 64 + j] = a0;
  out[(bg * 2 + 1) * 64 + j] = a1;
}

extern "C" void kernel_launch(void* const* d_in, const int* in_sizes, int n_in,
                              void* d_out, int out_size, void* d_ws, size_t ws_size,
                              hipStream_t stream) {
  const float* pos   = (const float*)d_in[0];
  const float* xfeat = (const float*)d_in[1];
  const int*   eidx  = (const int*)d_in[2];
  const int*   batch = (const int*)d_in[3];
  const float* eW1 = (const float*)d_in[4];
  const float* eb1 = (const float*)d_in[5];
  const float* eW2 = (const float*)d_in[6];
  const float* eb2 = (const float*)d_in[7];
  const float* mW1 = (const float*)d_in[8];
  const float* mb1 = (const float*)d_in[9];
  const float* mW2 = (const float*)d_in[10];
  const float* mb2 = (const float*)d_in[11];
  const float* uW1 = (const float*)d_in[12];
  const float* ub1 = (const float*)d_in[13];
  const float* uW2 = (const float*)d_in[14];
  const float* ub2 = (const float*)d_in[15];
  const float* rW1 = (const float*)d_in[16];
  const float* rb1 = (const float*)d_in[17];
  const float* rW2 = (const float*)d_in[18];
  const float* rb2 = (const float*)d_in[19];

  const int* srcI = eidx;
  const int* dstI = eidx + NEDGES;

  char* base = (char*)d_ws;
  float* h    = (float*)base;  base += (size_t)NATOMS * 128 * 4;
  float* aggH = (float*)base;  base += (size_t)NATOMS * 256 * 4;
  __bf16* z1b = (__bf16*)base; base += (size_t)NATOMS * 256 * 2;
  __bf16* z2b = (__bf16*)base; base += (size_t)NATOMS * 256 * 2;
  __bf16* hb  = (__bf16*)base; base += (size_t)NATOMS * 128 * 2;
  __bf16* efb = (__bf16*)base; base += (size_t)NEDGES * 16 * 2;
  __bf16* W1at = (__bf16*)base; base += (size_t)NLAYERS * 256 * 128 * 2;
  __bf16* W1bt = (__bf16*)base; base += (size_t)NLAYERS * 256 * 128 * 2;
  __bf16* B2c  = (__bf16*)base; base += (size_t)NLAYERS * 256 * 32 * 2;
  __bf16* uW1ft = (__bf16*)base; base += (size_t)NLAYERS * 256 * 384 * 2;
  __bf16* uW2t = (__bf16*)base; base += (size_t)NLAYERS * 128 * 256 * 2;
  float* b2u  = (float*)base;  base += (size_t)NLAYERS * 256 * 4;
  float* degf = (float*)base;  base += (size_t)NATOMS * 4;
  float* gsum = (float*)base;  base += 8 * 128 * 4;
  float* gcnt = (float*)base;  base += 8 * 4;
  int* counts = (int*)base;    base += (size_t)NATOMS * 4;
  int* cursor = (int*)base;    base += (size_t)NATOMS * 4;
  int* esrc   = (int*)base;    base += (size_t)NEDGES * 4;
  int* edst   = (int*)base;    base += (size_t)NEDGES * 4;

  // counts must be zeroed before front_kernel's hist section
  hipMemsetAsync(counts, 0, NATOMS * sizeof(int), stream);

  // merged front: weight prep + dst histogram + embedding
  front_kernel<<<NB_PREP + NB_HIST + NB_EMB, 256, 0, stream>>>(
      mW1, mW2, uW1, uW2, mb2, W1at, W1bt, B2c, uW1ft, uW2t, b2u,
      dstI, counts, xfeat, eW1, eb1, eW2, eb2, h, hb);

  scan_kernel<<<1, 1024, 0, stream>>>(counts, cursor, degf);
  scatter_kernel<<<NEDGES / 256, 256, 0, stream>>>(srcI, dstI, cursor, esrc, edst);
  rbf_kernel<<<NEDGES / 256, 256, 0, stream>>>(pos, esrc, edst, efb);

  // zprep for layer 0 (also zeros aggH)
  zprep_kernel<<<NATOMS / 64, 256, 0, stream>>>(
      hb, mb1, W1at, W1bt, z1b, z2b, aggH);

  for (int l = 0; l < NLAYERS; l++) {
    int ln = (l < NLAYERS - 1) ? (l + 1) : l;
    msg_mfma_kernel<<<NEDGES / TE, 256, 0, stream>>>(
        z1b, z2b, efb, esrc, edst,
        B2c + (size_t)l * 256 * 32, aggH);
    upd_mfma_kernel<<<NATOMS / 64, 512, 0, stream>>>(
        h, hb, aggH, degf,
        uW1ft + (size_t)l * 256 * 384, ub1 + (size_t)l * 256,
        b2u + (size_t)l * 256,
        uW2t + (size_t)l * 128 * 256, ub2 + (size_t)l * 128,
        (l < NLAYERS - 1) ? 1 : 0,
        mb1 + (size_t)ln * 256,
        W1at + (size_t)ln * 256 * 128, W1bt + (size_t)ln * 256 * 128,
        z1b, z2b);
  }

  hipMemsetAsync(gsum, 0, (8 * 128 + 8) * sizeof(float), stream);
  readout_sum_kernel<<<NATOMS / 128, 128, 0, stream>>>(h, batch, gsum, gcnt);
  readout_mlp_kernel<<<1, 256, 0, stream>>>(gsum, gcnt, rW1, rb1, rW2, rb2,
                                            (float*)d_out);
}

// Round 17
// 649.527 us; speedup vs baseline: 1.2214x; 1.0274x over previous
//
#include <hip/hip_runtime.h>
#include <math.h>

#define NATOMS 16384
#define NEDGES 524288
#define NLAYERS 4
#define TE 64      // edges per block in msg kernel

typedef __bf16 bf16x8 __attribute__((ext_vector_type(8)));
typedef __bf16 bf16x4 __attribute__((ext_vector_type(4)));
typedef __bf16 bf16x2 __attribute__((ext_vector_type(2)));
typedef float f32x4 __attribute__((ext_vector_type(4)));

// fast silu: x * rcp(1+exp(-x))
__device__ __forceinline__ float silu_f(float x) {
  return x * __builtin_amdgcn_rcpf(1.0f + __expf(-x));
}

// ---------------- CSR preprocessing ----------------
__global__ __launch_bounds__(1024) void scan_kernel(
    const int* __restrict__ counts, int* __restrict__ cursor,
    float* __restrict__ degf)
{
  __shared__ int s_tot[1024];
  int tid = threadIdx.x;
  int v[16];
  {
    const int4* cp = (const int4*)(counts + tid * 16);
    int4 a = cp[0], b = cp[1], c = cp[2], d = cp[3];
    v[0]=a.x; v[1]=a.y; v[2]=a.z; v[3]=a.w;
    v[4]=b.x; v[5]=b.y; v[6]=b.z; v[7]=b.w;
    v[8]=c.x; v[9]=c.y; v[10]=c.z; v[11]=c.w;
    v[12]=d.x; v[13]=d.y; v[14]=d.z; v[15]=d.w;
  }
  int tot = 0;
  #pragma unroll
  for (int i = 0; i < 16; i++) tot += v[i];
  s_tot[tid] = tot;
  __syncthreads();
  for (int off = 1; off < 1024; off <<= 1) {
    int t = (tid >= off) ? s_tot[tid - off] : 0;
    __syncthreads();
    s_tot[tid] += t;
    __syncthreads();
  }
  int run = s_tot[tid] - tot;   // exclusive prefix
  #pragma unroll
  for (int i = 0; i < 16; i++) {
    cursor[tid * 16 + i] = run;
    degf[tid * 16 + i] = (float)v[i];
    run += v[i];
  }
}

__global__ __launch_bounds__(256) void scatter_kernel(
    const int* __restrict__ src, const int* __restrict__ dst,
    int* __restrict__ cursor, int* __restrict__ esrc, int* __restrict__ edst)
{
  int e = blockIdx.x * 256 + threadIdx.x;
  int d = dst[e];
  int p = atomicAdd(&cursor[d], 1);
  esrc[p] = src[e];
  edst[p] = d;
}

// ---------------- merged front kernel: weight prep + dst histogram + embed ----------------
#define NB_PREP (801 * NLAYERS)
#define NB_HIST (NEDGES / 256)
#define NB_EMB  (NATOMS / 2)

__global__ __launch_bounds__(256) void front_kernel(
    const float* __restrict__ mW1, const float* __restrict__ mW2,
    const float* __restrict__ uW1, const float* __restrict__ uW2,
    const float* __restrict__ mb2,
    __bf16* __restrict__ W1at, __bf16* __restrict__ W1bt,
    __bf16* __restrict__ B2c, __bf16* __restrict__ uW1ft,
    __bf16* __restrict__ uW2t, float* __restrict__ b2u,
    const int* __restrict__ dstI, int* __restrict__ counts,
    const float* __restrict__ x, const float* __restrict__ eW1,
    const float* __restrict__ eb1, const float* __restrict__ eW2,
    const float* __restrict__ eb2, float* __restrict__ h,
    __bf16* __restrict__ hb)
{
  __shared__ float xs[2][26];
  __shared__ float hid[2][132];
  int bxf = blockIdx.x, tid = threadIdx.x;

  if (bxf < NB_PREP) {
    long l = bxf / 801;
    int bx = bxf - (int)l * 801;
    if (bx < 128) {
      int i = bx * 256 + tid;              // 256*128
      int n = i >> 7, k = i & 127;
      W1at[l * (256L * 128) + i] = (__bf16)mW1[l * (272L * 256) + (size_t)k * 256 + n];
    } else if (bx < 256) {
      int i = (bx - 128) * 256 + tid;
      int n = i >> 7, k = i & 127;
      W1bt[l * (256L * 128) + i] = (__bf16)mW1[l * (272L * 256) + (size_t)(128 + k) * 256 + n];
    } else if (bx < 288) {
      int i = (bx - 256) * 256 + tid;      // 256*32
      int c = i >> 5, k = i & 31;
      float v = (k < 16) ? mW1[l * (272L * 256) + (size_t)(256 + k) * 256 + c] : 0.0f;
      B2c[l * (256L * 32) + i] = (__bf16)v;
    } else if (bx < 672) {
      // block = one k (384 per layer), threads = n: coalesced reads, scalar mW2
      int k = bx - 288;                    // 0..383
      int n = tid;                         // 0..255
      float v;
      if (k < 128) {
        v = uW1[l * 65536 + (size_t)k * 256 + n];
      } else {
        int r = k - 128;
        v = 0.0f;
        for (int j = 0; j < 128; j++)
          v += mW2[(l * 256 + r) * 128 + j] * uW1[l * 65536 + (size_t)(128 + j) * 256 + n];
      }
      uW1ft[l * (256L * 384) + (size_t)n * 384 + k] = (__bf16)v;
    } else if (bx < 800) {
      int i = (bx - 672) * 256 + tid;      // 128*256
      int n = i >> 8, k = i & 255;
      uW2t[l * (128L * 256) + i] = (__bf16)uW2[l * (256L * 128) + (size_t)k * 128 + n];
    } else {
      int c = tid;
      float acc = 0.0f;
      for (int j = 0; j < 128; j++)
        acc += mb2[l * 128 + j] * uW1[l * 65536 + (size_t)(128 + j) * 256 + c];
      b2u[l * 256 + c] = acc;
    }
  } else if (bxf < NB_PREP + NB_HIST) {
    int e = (bxf - NB_PREP) * 256 + tid;
    atomicAdd(&counts[dstI[e]], 1);
  } else {
    int nb = bxf - (NB_PREP + NB_HIST);
    int hf = tid >> 7, j = tid & 127;
    int n = nb * 2 + hf;
    if (j < 26) xs[hf][j] = x[(size_t)n * 26 + j];
    __syncthreads();
    float acc = eb1[j];
    #pragma unroll
    for (int k = 0; k < 26; k++) acc += xs[hf][k] * eW1[k * 128 + j];
    hid[hf][j] = silu_f(acc);
    __syncthreads();
    float acc2 = eb2[j];
    #pragma unroll 8
    for (int k = 0; k < 128; k++) acc2 += hid[hf][k] * eW2[k * 128 + j];
    h[(size_t)n * 128 + j] = acc2;
    hb[(size_t)n * 128 + j] = (__bf16)acc2;
  }
}

// ---------------- edge RBF (sorted slot order) ----------------
__global__ __launch_bounds__(256) void rbf_kernel(
    const float* __restrict__ pos, const int* __restrict__ esrc,
    const int* __restrict__ edst, __bf16* __restrict__ efb)
{
  int e = blockIdx.x * 256 + threadIdx.x;
  int s = esrc[e], d = edst[e];
  float dx = pos[d * 3 + 0] - pos[s * 3 + 0];
  float dy = pos[d * 3 + 1] - pos[s * 3 + 1];
  float dz = pos[d * 3 + 2] - pos[s * 3 + 2];
  float dist = sqrtf(dx * dx + dy * dy + dz * dz + 1e-12f);
  float env = (dist < 10.0f)
                  ? 0.5f * (cosf(3.14159265358979f * dist * 0.1f) + 1.0f)
                  : 0.0f;
  bf16x8 o0, o1;
  #pragma unroll
  for (int i = 0; i < 16; i++) {
    float c = (10.0f / 15.0f) * (float)i;
    float t = dist - c;
    float v = env * __expf(-t * t * 1.28f);
    if (i < 8) o0[i] = (__bf16)v; else o1[i - 8] = (__bf16)v;
  }
  *(bf16x8*)(efb + (size_t)e * 16 + 0) = o0;
  *(bf16x8*)(efb + (size_t)e * 16 + 8) = o1;
}

// ---------------- zprep (layer 0 only): z1b, z2b; zeros aggH ----------------
__global__ __launch_bounds__(256) void zprep_kernel(
    const __bf16* __restrict__ hb, const float* __restrict__ b1,
    const __bf16* __restrict__ W1at, const __bf16* __restrict__ W1bt,
    __bf16* __restrict__ z1b, __bf16* __restrict__ z2b, float* __restrict__ aggH)
{
  __shared__ __bf16 s_n[64][136];
  int tid = threadIdx.x, n0 = blockIdx.x * 64;
  {
    int n = tid >> 2, t4 = tid & 3;
    const bf16x8* hr = (const bf16x8*)(hb + (size_t)(n0 + n) * 128);
    #pragma unroll
    for (int i = 0; i < 4; i++)
      *(bf16x8*)&s_n[n][t4 * 8 + 32 * i] = hr[t4 + 4 * i];
  }
  {
    float4 zz = make_float4(0.f, 0.f, 0.f, 0.f);
    float4* ap = (float4*)(aggH + (size_t)n0 * 256);
    for (int i = tid; i < 64 * 256 / 4; i += 256) ap[i] = zz;
  }
  __syncthreads();
  const int wv = tid >> 6, ln = tid & 63, lc = ln & 15, qd = ln >> 4;
  for (int cp = 0; cp < 2; cp++) {
    f32x4 aA[4][2], aB[4][2];
    #pragma unroll
    for (int nt = 0; nt < 2; nt++) {
      float bv = b1[cp * 128 + wv * 32 + nt * 16 + lc];
      #pragma unroll
      for (int mt = 0; mt < 4; mt++) {
        aA[mt][nt][0] = 0.f; aA[mt][nt][1] = 0.f;
        aA[mt][nt][2] = 0.f; aA[mt][nt][3] = 0.f;
        aB[mt][nt][0] = bv; aB[mt][nt][1] = bv;
        aB[mt][nt][2] = bv; aB[mt][nt][3] = bv;
      }
    }
    #pragma unroll
    for (int kt = 0; kt < 4; kt++) {
      bf16x8 af[4];
      #pragma unroll
      for (int mt = 0; mt < 4; mt++)
        af[mt] = *(const bf16x8*)&s_n[mt * 16 + lc][kt * 32 + qd * 8];
      bf16x8 bwA[2], bwB[2];
      #pragma unroll
      for (int nt = 0; nt < 2; nt++) {
        int c = cp * 128 + wv * 32 + nt * 16 + lc;
        bwA[nt] = *(const bf16x8*)(W1at + (size_t)c * 128 + kt * 32 + qd * 8);
        bwB[nt] = *(const bf16x8*)(W1bt + (size_t)c * 128 + kt * 32 + qd * 8);
      }
      #pragma unroll
      for (int mt = 0; mt < 4; mt++)
        #pragma unroll
        for (int nt = 0; nt < 2; nt++) {
          aA[mt][nt] = __builtin_amdgcn_mfma_f32_16x16x32_bf16(af[mt], bwA[nt], aA[mt][nt], 0, 0, 0);
          aB[mt][nt] = __builtin_amdgcn_mfma_f32_16x16x32_bf16(af[mt], bwB[nt], aB[mt][nt], 0, 0, 0);
        }
    }
    #pragma unroll
    for (int mt = 0; mt < 4; mt++)
      #pragma unroll
      for (int nt = 0; nt < 2; nt++) {
        int c = cp * 128 + wv * 32 + nt * 16 + lc;
        #pragma unroll
        for (int r = 0; r < 4; r++) {
          int n = n0 + mt * 16 + qd * 4 + r;
          z1b[(size_t)n * 256 + c] = (__bf16)aA[mt][nt][r];
          z2b[(size_t)n * 256 + c] = (__bf16)aB[mt][nt][r];
        }
      }
  }
}

// ---------------- fused message kernel v7 (round-12 scan, measured best) ----------------
#define MS_EF_OFF   33792                 // s_hT 256*66*2 = 33792
#define MS_SRC_OFF  36864                 // s_ef 64*24*2 = 3072
#define MS_DST_OFF  37120
#define MS_MASK_OFF 37376
#define MS_BYTES    37392

__global__ __launch_bounds__(256, 4) void msg_mfma_kernel(
    const __bf16* __restrict__ z1b, const __bf16* __restrict__ z2b,
    const __bf16* __restrict__ efb,
    const int* __restrict__ esrc, const int* __restrict__ edst,
    const __bf16* __restrict__ B2c, float* __restrict__ aggH)
{
  __shared__ __align__(16) char smem[MS_BYTES];
  __bf16 (*s_hT)[66] = (__bf16(*)[66])(smem);          // [256 cols][64 rows + 2 pad]
  __bf16 (*s_ef)[24] = (__bf16(*)[24])(smem + MS_EF_OFF);
  int* s_src = (int*)(smem + MS_SRC_OFF);
  int* s_dst = (int*)(smem + MS_DST_OFF);
  unsigned int* s_mask = (unsigned int*)(smem + MS_MASK_OFF);

  int tid = threadIdx.x, e0 = blockIdx.x * TE;

  if (tid < TE) {
    int d = edst[e0 + tid];
    s_dst[tid] = d;
    int dp = (tid == 0) ? (d ^ 1) : edst[e0 + tid - 1];
    unsigned long long mb = __ballot(d != dp);
    if (tid == 0) { s_mask[0] = (unsigned int)mb; s_mask[1] = (unsigned int)(mb >> 32); }
  } else if (tid < 2 * TE) {
    s_src[tid - TE] = esrc[e0 + tid - TE];
  }
  {
    int e = tid >> 2, t4 = tid & 3;
    if (t4 < 2)
      *(bf16x8*)&s_ef[e][t4 * 8] =
          *(const bf16x8*)(efb + (size_t)(e0 + e) * 16 + t4 * 8);
  }
  __syncthreads();

  const int wv = tid >> 6, ln = tid & 63, lc = ln & 15, qd = ln >> 4;

  bf16x8 bI;
  #pragma unroll
  for (int j = 0; j < 8; j++)
    bI[j] = (__bf16)((lc == (qd & 1) * 8 + j) ? 1.0f : 0.0f);

  const __bf16* pz[4];
  #pragma unroll
  for (int mt = 0; mt < 4; mt++) {
    int m = mt * 16 + lc;
    int row = (qd < 2) ? s_src[m] : s_dst[m];
    pz[mt] = ((qd < 2) ? z1b : z2b) + (size_t)row * 256 + (qd & 1) * 8;
  }

  // ---- compute both halves, no barrier between (disjoint s_hT cols) ----
  #pragma unroll
  for (int hf = 0; hf < 2; hf++) {
    const int cb = hf * 128 + wv * 32;
    bf16x8 bw[2];
    #pragma unroll
    for (int nt = 0; nt < 2; nt++)
      bw[nt] = *(const bf16x8*)(B2c + (size_t)(cb + nt * 16 + lc) * 32 + qd * 8);

    #pragma unroll
    for (int mt = 0; mt < 4; mt++) {
      bf16x8 aef = *(const bf16x8*)&s_ef[mt * 16 + lc][(qd & 1) * 8];
      #pragma unroll
      for (int nt = 0; nt < 2; nt++) {
        bf16x8 az = *(const bf16x8*)(pz[mt] + cb + nt * 16);
        f32x4 z; z[0] = 0.f; z[1] = 0.f; z[2] = 0.f; z[3] = 0.f;
        f32x4 acc = __builtin_amdgcn_mfma_f32_16x16x32_bf16(az, bI, z, 0, 0, 0);
        acc = __builtin_amdgcn_mfma_f32_16x16x32_bf16(aef, bw[nt], acc, 0, 0, 0);
        bf16x2 p0, p1;
        p0[0] = (__bf16)silu_f(acc[0]); p0[1] = (__bf16)silu_f(acc[1]);
        p1[0] = (__bf16)silu_f(acc[2]); p1[1] = (__bf16)silu_f(acc[3]);
        __bf16* wp = &s_hT[cb + nt * 16 + lc][mt * 16 + qd * 4];
        *(bf16x2*)wp = p0;
        *(bf16x2*)(wp + 2) = p1;
      }
    }
  }
  __syncthreads();

  // ---- one scan pass: 256 threads x 1 column x 64 rows (round-12 form) ----
  {
    const unsigned int mlo = __builtin_amdgcn_readfirstlane(s_mask[0]);
    const unsigned int mhi = __builtin_amdgcn_readfirstlane(s_mask[1]);
    int j = tid;
    float acc = 0.0f;
    int cur = s_dst[0];
    #pragma unroll 8
    for (int i = 0; i < 64; i += 2) {
      bf16x2 p = *(const bf16x2*)&s_hT[j][i];
      bool b0 = (i < 32) ? ((mlo >> i) & 1u) : ((mhi >> (i - 32)) & 1u);
      int i1 = i + 1;
      bool b1 = (i1 < 32) ? ((mlo >> i1) & 1u) : ((mhi >> (i1 - 32)) & 1u);
      if (i > 0 && b0) {
        atomicAdd(&aggH[(size_t)cur * 256 + j], acc);
        acc = 0.0f; cur = s_dst[i];
      }
      acc += (float)p[0];
      if (b1) {
        atomicAdd(&aggH[(size_t)cur * 256 + j], acc);
        acc = 0.0f; cur = s_dst[i1];
      }
      acc += (float)p[1];
    }
    atomicAdd(&aggH[(size_t)cur * 256 + j], acc);
  }
}

// ---------------- fused node update MLP v4: 512 threads, 64 nodes + next-layer zprep ----------------
__global__ __launch_bounds__(512, 2) void upd_mfma_kernel(
    float* __restrict__ h, __bf16* __restrict__ hb,
    float* __restrict__ aggH, const float* __restrict__ degf,
    const __bf16* __restrict__ uW1ft, const float* __restrict__ b1,
    const float* __restrict__ b2u,
    const __bf16* __restrict__ uW2t, const float* __restrict__ b2,
    int do_z, const float* __restrict__ nb1,
    const __bf16* __restrict__ nW1at, const __bf16* __restrict__ nW1bt,
    __bf16* __restrict__ z1b, __bf16* __restrict__ z2b)
{
  __shared__ __bf16 s_u[64][392];    // [h(128) | agg(256)] + 8 pad
  __shared__ __bf16 s_uh[64][264];   // 256 hidden cols + 8 pad
  int tid = threadIdx.x, n0 = blockIdx.x * 64;
  {
    int n = tid >> 3, t8 = tid & 7;  // 8 threads per node
    const bf16x8* hr = (const bf16x8*)(hb + (size_t)(n0 + n) * 128);
    #pragma unroll
    for (int i = 0; i < 2; i++)
      *(bf16x8*)&s_u[n][t8 * 8 + 64 * i] = hr[t8 + 8 * i];
    const float* sr = aggH + (size_t)(n0 + n) * 256;
    #pragma unroll
    for (int i = 0; i < 4; i++) {
      int col = t8 * 8 + i * 64;
      float4 a = *(const float4*)(sr + col);
      float4 b = *(const float4*)(sr + col + 4);
      bf16x8 o;
      o[0] = (__bf16)a.x; o[1] = (__bf16)a.y; o[2] = (__bf16)a.z; o[3] = (__bf16)a.w;
      o[4] = (__bf16)b.x; o[5] = (__bf16)b.y; o[6] = (__bf16)b.z; o[7] = (__bf16)b.w;
      *(bf16x8*)&s_u[n][128 + col] = o;
    }
  }
  __syncthreads();
  const int wv = tid >> 6, ln = tid & 63, lc = ln & 15, qd = ln >> 4;  // wv 0..7

  float dg[4][4];
  #pragma unroll
  for (int mt = 0; mt < 4; mt++)
    #pragma unroll
    for (int r = 0; r < 4; r++)
      dg[mt][r] = degf[n0 + mt * 16 + qd * 4 + r];

  // ---- GEMM1: K=384, wave owns cols wv*32 + nt*16 + lc ----
  {
    f32x4 acc1[4][2];
    #pragma unroll
    for (int nt = 0; nt < 2; nt++) {
      int c = wv * 32 + nt * 16 + lc;
      float bv = b1[c];
      float b2uv = b2u[c];
      #pragma unroll
      for (int mt = 0; mt < 4; mt++)
        #pragma unroll
        for (int r = 0; r < 4; r++)
          acc1[mt][nt][r] = bv + dg[mt][r] * b2uv;
    }
    #pragma unroll
    for (int kt = 0; kt < 12; kt++) {
      bf16x8 af[4];
      #pragma unroll
      for (int mt = 0; mt < 4; mt++)
        af[mt] = *(const bf16x8*)&s_u[mt * 16 + lc][kt * 32 + qd * 8];
      bf16x8 bw[2];
      #pragma unroll
      for (int nt = 0; nt < 2; nt++)
        bw[nt] = *(const bf16x8*)(uW1ft +
                 (size_t)(wv * 32 + nt * 16 + lc) * 384 + kt * 32 + qd * 8);
      #pragma unroll
      for (int mt = 0; mt < 4; mt++)
        #pragma unroll
        for (int nt = 0; nt < 2; nt++)
          acc1[mt][nt] = __builtin_amdgcn_mfma_f32_16x16x32_bf16(af[mt], bw[nt], acc1[mt][nt], 0, 0, 0);
    }
    #pragma unroll
    for (int mt = 0; mt < 4; mt++)
      #pragma unroll
      for (int nt = 0; nt < 2; nt++) {
        int cc = wv * 32 + nt * 16 + lc;
        #pragma unroll
        for (int r = 0; r < 4; r++)
          s_uh[mt * 16 + qd * 4 + r][cc] = (__bf16)silu_f(acc1[mt][nt][r]);
      }
  }
  __syncthreads();

  // ---- GEMM2: K=256, wave owns output cols ow = wv*16 + lc ----
  const int ow = wv * 16 + lc;
  f32x4 acc2[4];
  {
    float bv = b2[ow];
    #pragma unroll
    for (int mt = 0; mt < 4; mt++) {
      acc2[mt][0] = bv; acc2[mt][1] = bv; acc2[mt][2] = bv; acc2[mt][3] = bv;
    }
  }
  #pragma unroll
  for (int kt = 0; kt < 8; kt++) {
    bf16x8 a2[4];
    #pragma unroll
    for (int mt = 0; mt < 4; mt++)
      a2[mt] = *(const bf16x8*)&s_uh[mt * 16 + lc][kt * 32 + qd * 8];
    bf16x8 b2w = *(const bf16x8*)(uW2t + (size_t)ow * 256 + kt * 32 + qd * 8);
    #pragma unroll
    for (int mt = 0; mt < 4; mt++)
      acc2[mt] = __builtin_amdgcn_mfma_f32_16x16x32_bf16(a2[mt], b2w, acc2[mt], 0, 0, 0);
  }

  // residual epilogue
  #pragma unroll
  for (int mt = 0; mt < 4; mt++)
    #pragma unroll
    for (int r = 0; r < 4; r++) {
      int n = n0 + mt * 16 + qd * 4 + r;
      float v = h[(size_t)n * 128 + ow] + acc2[mt][r];
      h[(size_t)n * 128 + ow] = v;
      hb[(size_t)n * 128 + ow] = (__bf16)v;
    }

  // ---- fused zprep for next layer ----
  if (do_z) {
    __syncthreads();
    {
      float4 zz = make_float4(0.f, 0.f, 0.f, 0.f);
      float4* ap = (float4*)(aggH + (size_t)n0 * 256);
      for (int i = tid; i < 64 * 256 / 4; i += 512) ap[i] = zz;
      int n = tid >> 3, t8 = tid & 7;
      const bf16x8* hr = (const bf16x8*)(hb + (size_t)(n0 + n) * 128);
      #pragma unroll
      for (int i = 0; i < 2; i++)
        *(bf16x8*)&s_u[n][t8 * 8 + 64 * i] = hr[t8 + 8 * i];
    }
    __syncthreads();
    f32x4 aA[4][2], aB[4][2];
    #pragma unroll
    for (int nt = 0; nt < 2; nt++) {
      float bv = nb1[wv * 32 + nt * 16 + lc];
      #pragma unroll
      for (int mt = 0; mt < 4; mt++) {
        aA[mt][nt][0] = 0.f; aA[mt][nt][1] = 0.f;
        aA[mt][nt][2] = 0.f; aA[mt][nt][3] = 0.f;
        aB[mt][nt][0] = bv; aB[mt][nt][1] = bv;
        aB[mt][nt][2] = bv; aB[mt][nt][3] = bv;
      }
    }
    #pragma unroll
    for (int kt = 0; kt < 4; kt++) {
      bf16x8 af[4];
      #pragma unroll
      for (int mt = 0; mt < 4; mt++)
        af[mt] = *(const bf16x8*)&s_u[mt * 16 + lc][kt * 32 + qd * 8];
      bf16x8 bwA[2], bwB[2];
      #pragma unroll
      for (int nt = 0; nt < 2; nt++) {
        int c = wv * 32 + nt * 16 + lc;
        bwA[nt] = *(const bf16x8*)(nW1at + (size_t)c * 128 + kt * 32 + qd * 8);
        bwB[nt] = *(const bf16x8*)(nW1bt + (size_t)c * 128 + kt * 32 + qd * 8);
      }
      #pragma unroll
      for (int mt = 0; mt < 4; mt++)
        #pragma unroll
        for (int nt = 0; nt < 2; nt++) {
          aA[mt][nt] = __builtin_amdgcn_mfma_f32_16x16x32_bf16(af[mt], bwA[nt], aA[mt][nt], 0, 0, 0);
          aB[mt][nt] = __builtin_amdgcn_mfma_f32_16x16x32_bf16(af[mt], bwB[nt], aB[mt][nt], 0, 0, 0);
        }
    }
    #pragma unroll
    for (int mt = 0; mt < 4; mt++)
      #pragma unroll
      for (int nt = 0; nt < 2; nt++) {
        int c = wv * 32 + nt * 16 + lc;
        #pragma unroll
        for (int r = 0; r < 4; r++) {
          int n = n0 + mt * 16 + qd * 4 + r;
          z1b[(size_t)n * 256 + c] = (__bf16)aA[mt][nt][r];
          z2b[(size_t)n * 256 + c] = (__bf16)aB[mt][nt][r];
        }
      }
  }
}

// ---------------- readout ----------------
__global__ __launch_bounds__(128) void readout_sum_kernel(
    const float* __restrict__ h, const int* __restrict__ batch,
    float* __restrict__ gsum, float* __restrict__ gcnt)
{
  int j = threadIdx.x;
  int n0 = blockIdx.x * 128;
  float acc = 0.f, cacc = 0.f;
  int cur = batch[n0];
  for (int i = 0; i < 128; i++) {
    int b = batch[n0 + i];
    if (b != cur) {
      atomicAdd(&gsum[cur * 128 + j], acc);
      if (j == 0) atomicAdd(&gcnt[cur], cacc);
      acc = 0.f; cacc = 0.f; cur = b;
    }
    acc += h[(size_t)(n0 + i) * 128 + j];
    cacc += 1.f;
  }
  atomicAdd(&gsum[cur * 128 + j], acc);
  if (j == 0) atomicAdd(&gcnt[cur], cacc);
}

__global__ __launch_bounds__(256) void readout_mlp_kernel(
    const float* __restrict__ gsum, const float* __restrict__ gcnt,
    const float* __restrict__ W1, const float* __restrict__ b1,
    const float* __restrict__ W2, const float* __restrict__ b2,
    float* __restrict__ out)
{
  __shared__ float g[8][128];
  __shared__ float hid[8][256];
  int tid = threadIdx.x;
  for (int i = tid; i < 8 * 128; i += 256) {
    int b = i >> 7, c = i & 127;
    g[b][c] = gsum[i] / fmaxf(gcnt[b], 1.0f);
  }
  __syncthreads();
  {
    float bb = b1[tid];
    float a[8];
    #pragma unroll
    for (int b = 0; b < 8; b++) a[b] = bb;
    for (int k = 0; k < 128; k++) {
      float w = W1[k * 256 + tid];
      #pragma unroll
      for (int b = 0; b < 8; b++) a[b] += g[b][k] * w;
    }
    #pragma unroll
    for (int b = 0; b < 8; b++) hid[b][tid] = silu_f(a[b]);
  }
  __syncthreads();
  int j = tid & 63, bg = tid >> 6;
  float a0 = b2[j], a1 = b2[j];
  for (int k = 0; k < 256; k++) {
    float w = W2[k * 64 + j];
    a0 += hid[bg * 2 + 0][k] * w;
    a1 += hid[bg * 2 + 1][k] * w;
  }
  out[(bg * 2 + 0) * 64 + j] = a0;
  out[(bg * 2 + 1) * 64 + j] = a1;
}

extern "C" void kernel_launch(void* const* d_in, const int* in_sizes, int n_in,
                              void* d_out, int out_size, void* d_ws, size_t ws_size,
                              hipStream_t stream) {
  const float* pos   = (const float*)d_in[0];
  const float* xfeat = (const float*)d_in[1];
  const int*   eidx  = (const int*)d_in[2];
  const int*   batch = (const int*)d_in[3];
  const float* eW1 = (const float*)d_in[4];
  const float* eb1 = (const float*)d_in[5];
  const float* eW2 = (const float*)d_in[6];
  const float* eb2 = (const float*)d_in[7];
  const float* mW1 = (const float*)d_in[8];
  const float* mb1 = (const float*)d_in[9];
  const float* mW2 = (const float*)d_in[10];
  const float* mb2 = (const float*)d_in[11];
  const float* uW1 = (const float*)d_in[12];
  const float* ub1 = (const float*)d_in[13];
  const float* uW2 = (const float*)d_in[14];
  const float* ub2 = (const float*)d_in[15];
  const float* rW1 = (const float*)d_in[16];
  const float* rb1 = (const float*)d_in[17];
  const float* rW2 = (const float*)d_in[18];
  const float* rb2 = (const float*)d_in[19];

  const int* srcI = eidx;
  const int* dstI = eidx + NEDGES;

  char* base = (char*)d_ws;
  float* h    = (float*)base;  base += (size_t)NATOMS * 128 * 4;
  float* aggH = (float*)base;  base += (size_t)NATOMS * 256 * 4;
  __bf16* z1b = (__bf16*)base; base += (size_t)NATOMS * 256 * 2;
  __bf16* z2b = (__bf16*)base; base += (size_t)NATOMS * 256 * 2;
  __bf16* hb  = (__bf16*)base; base += (size_t)NATOMS * 128 * 2;
  __bf16* efb = (__bf16*)base; base += (size_t)NEDGES * 16 * 2;
  __bf16* W1at = (__bf16*)base; base += (size_t)NLAYERS * 256 * 128 * 2;
  __bf16* W1bt = (__bf16*)base; base += (size_t)NLAYERS * 256 * 128 * 2;
  __bf16* B2c  = (__bf16*)base; base += (size_t)NLAYERS * 256 * 32 * 2;
  __bf16* uW1ft = (__bf16*)base; base += (size_t)NLAYERS * 256 * 384 * 2;
  __bf16* uW2t = (__bf16*)base; base += (size_t)NLAYERS * 128 * 256 * 2;
  float* b2u  = (float*)base;  base += (size_t)NLAYERS * 256 * 4;
  float* degf = (float*)base;  base += (size_t)NATOMS * 4;
  float* gsum = (float*)base;  base += 8 * 128 * 4;
  float* gcnt = (float*)base;  base += 8 * 4;
  int* counts = (int*)base;    base += (size_t)NATOMS * 4;
  int* cursor = (int*)base;    base += (size_t)NATOMS * 4;
  int* esrc   = (int*)base;    base += (size_t)NEDGES * 4;
  int* edst   = (int*)base;    base += (size_t)NEDGES * 4;

  // counts must be zeroed before front_kernel's hist section
  hipMemsetAsync(counts, 0, NATOMS * sizeof(int), stream);

  // merged front: weight prep + dst histogram + embedding
  front_kernel<<<NB_PREP + NB_HIST + NB_EMB, 256, 0, stream>>>(
      mW1, mW2, uW1, uW2, mb2, W1at, W1bt, B2c, uW1ft, uW2t, b2u,
      dstI, counts, xfeat, eW1, eb1, eW2, eb2, h, hb);

  scan_kernel<<<1, 1024, 0, stream>>>(counts, cursor, degf);
  scatter_kernel<<<NEDGES / 256, 256, 0, stream>>>(srcI, dstI, cursor, esrc, edst);
  rbf_kernel<<<NEDGES / 256, 256, 0, stream>>>(pos, esrc, edst, efb);

  // zprep for layer 0 (also zeros aggH)
  zprep_kernel<<<NATOMS / 64, 256, 0, stream>>>(
      hb, mb1, W1at, W1bt, z1b, z2b, aggH);

  for (int l = 0; l < NLAYERS; l++) {
    int ln = (l < NLAYERS - 1) ? (l + 1) : l;
    msg_mfma_kernel<<<NEDGES / TE, 256, 0, stream>>>(
        z1b, z2b, efb, esrc, edst,
        B2c + (size_t)l * 256 * 32, aggH);
    upd_mfma_kernel<<<NATOMS / 64, 512, 0, stream>>>(
        h, hb, aggH, degf,
        uW1ft + (size_t)l * 256 * 384, ub1 + (size_t)l * 256,
        b2u + (size_t)l * 256,
        uW2t + (size_t)l * 128 * 256, ub2 + (size_t)l * 128,
        (l < NLAYERS - 1) ? 1 : 0,
        mb1 + (size_t)ln * 256,
        W1at + (size_t)ln * 256 * 128, W1bt + (size_t)ln * 256 * 128,
        z1b, z2b);
  }

  hipMemsetAsync(gsum, 0, (8 * 128 + 8) * sizeof(float), stream);
  readout_sum_kernel<<<NATOMS / 128, 128, 0, stream>>>(h, batch, gsum, gcnt);
  readout_mlp_kernel<<<1, 256, 0, stream>>>(gsum, gcnt, rW1, rb1, rW2, rb2,
                                            (float*)d_out);
}

// Round 18
// 638.939 us; speedup vs baseline: 1.2416x; 1.0166x over previous
//
#include <hip/hip_runtime.h>
#include <math.h>

#define NATOMS 16384
#define NEDGES 524288
#define NLAYERS 4
#define TE 64      // edges per block in msg kernel

typedef __bf16 bf16x8 __attribute__((ext_vector_type(8)));
typedef __bf16 bf16x4 __attribute__((ext_vector_type(4)));
typedef __bf16 bf16x2 __attribute__((ext_vector_type(2)));
typedef float f32x4 __attribute__((ext_vector_type(4)));

// fast silu: x * rcp(1+exp(-x))
__device__ __forceinline__ float silu_f(float x) {
  return x * __builtin_amdgcn_rcpf(1.0f + __expf(-x));
}

// ---------------- CSR preprocessing ----------------
__global__ __launch_bounds__(1024) void scan_kernel(
    const int* __restrict__ counts, int* __restrict__ cursor,
    float* __restrict__ degf)
{
  __shared__ int s_tot[1024];
  int tid = threadIdx.x;
  int v[16];
  {
    const int4* cp = (const int4*)(counts + tid * 16);
    int4 a = cp[0], b = cp[1], c = cp[2], d = cp[3];
    v[0]=a.x; v[1]=a.y; v[2]=a.z; v[3]=a.w;
    v[4]=b.x; v[5]=b.y; v[6]=b.z; v[7]=b.w;
    v[8]=c.x; v[9]=c.y; v[10]=c.z; v[11]=c.w;
    v[12]=d.x; v[13]=d.y; v[14]=d.z; v[15]=d.w;
  }
  int tot = 0;
  #pragma unroll
  for (int i = 0; i < 16; i++) tot += v[i];
  s_tot[tid] = tot;
  __syncthreads();
  for (int off = 1; off < 1024; off <<= 1) {
    int t = (tid >= off) ? s_tot[tid - off] : 0;
    __syncthreads();
    s_tot[tid] += t;
    __syncthreads();
  }
  int run = s_tot[tid] - tot;   // exclusive prefix
  #pragma unroll
  for (int i = 0; i < 16; i++) {
    cursor[tid * 16 + i] = run;
    degf[tid * 16 + i] = (float)v[i];
    run += v[i];
  }
}

// scatter + RBF fused: each edge computes its sorted slot p, writes esrc/edst
// AND its RBF features directly to efb[p].
__global__ __launch_bounds__(256) void scatter_rbf_kernel(
    const int* __restrict__ src, const int* __restrict__ dst,
    int* __restrict__ cursor, const float* __restrict__ pos,
    int* __restrict__ esrc, int* __restrict__ edst,
    __bf16* __restrict__ efb)
{
  int e = blockIdx.x * 256 + threadIdx.x;
  int s = src[e], d = dst[e];
  int p = atomicAdd(&cursor[d], 1);
  esrc[p] = s;
  edst[p] = d;
  float dx = pos[d * 3 + 0] - pos[s * 3 + 0];
  float dy = pos[d * 3 + 1] - pos[s * 3 + 1];
  float dz = pos[d * 3 + 2] - pos[s * 3 + 2];
  float dist = sqrtf(dx * dx + dy * dy + dz * dz + 1e-12f);
  float env = (dist < 10.0f)
                  ? 0.5f * (cosf(3.14159265358979f * dist * 0.1f) + 1.0f)
                  : 0.0f;
  bf16x8 o0, o1;
  #pragma unroll
  for (int i = 0; i < 16; i++) {
    float c = (10.0f / 15.0f) * (float)i;
    float t = dist - c;
    float v = env * __expf(-t * t * 1.28f);
    if (i < 8) o0[i] = (__bf16)v; else o1[i - 8] = (__bf16)v;
  }
  *(bf16x8*)(efb + (size_t)p * 16 + 0) = o0;
  *(bf16x8*)(efb + (size_t)p * 16 + 8) = o1;
}

// ---------------- merged front kernel: weight prep + dst histogram + embed ----------------
#define NB_PREP (801 * NLAYERS)
#define NB_HIST (NEDGES / 256)
#define NB_EMB  (NATOMS / 2)

__global__ __launch_bounds__(256) void front_kernel(
    const float* __restrict__ mW1, const float* __restrict__ mW2,
    const float* __restrict__ uW1, const float* __restrict__ uW2,
    const float* __restrict__ mb2,
    __bf16* __restrict__ W1at, __bf16* __restrict__ W1bt,
    __bf16* __restrict__ B2c, __bf16* __restrict__ uW1ft,
    __bf16* __restrict__ uW2t, float* __restrict__ b2u,
    const int* __restrict__ dstI, int* __restrict__ counts,
    const float* __restrict__ x, const float* __restrict__ eW1,
    const float* __restrict__ eb1, const float* __restrict__ eW2,
    const float* __restrict__ eb2, float* __restrict__ h,
    __bf16* __restrict__ hb)
{
  __shared__ float xs[2][26];
  __shared__ float hid[2][132];
  int bxf = blockIdx.x, tid = threadIdx.x;

  if (bxf < NB_PREP) {
    long l = bxf / 801;
    int bx = bxf - (int)l * 801;
    if (bx < 128) {
      int i = bx * 256 + tid;              // 256*128
      int n = i >> 7, k = i & 127;
      W1at[l * (256L * 128) + i] = (__bf16)mW1[l * (272L * 256) + (size_t)k * 256 + n];
    } else if (bx < 256) {
      int i = (bx - 128) * 256 + tid;
      int n = i >> 7, k = i & 127;
      W1bt[l * (256L * 128) + i] = (__bf16)mW1[l * (272L * 256) + (size_t)(128 + k) * 256 + n];
    } else if (bx < 288) {
      int i = (bx - 256) * 256 + tid;      // 256*32
      int c = i >> 5, k = i & 31;
      float v = (k < 16) ? mW1[l * (272L * 256) + (size_t)(256 + k) * 256 + c] : 0.0f;
      B2c[l * (256L * 32) + i] = (__bf16)v;
    } else if (bx < 672) {
      // block = one k (384 per layer), threads = n: coalesced reads, scalar mW2
      int k = bx - 288;                    // 0..383
      int n = tid;                         // 0..255
      float v;
      if (k < 128) {
        v = uW1[l * 65536 + (size_t)k * 256 + n];
      } else {
        int r = k - 128;
        v = 0.0f;
        for (int j = 0; j < 128; j++)
          v += mW2[(l * 256 + r) * 128 + j] * uW1[l * 65536 + (size_t)(128 + j) * 256 + n];
      }
      uW1ft[l * (256L * 384) + (size_t)n * 384 + k] = (__bf16)v;
    } else if (bx < 800) {
      int i = (bx - 672) * 256 + tid;      // 128*256
      int n = i >> 8, k = i & 255;
      uW2t[l * (128L * 256) + i] = (__bf16)uW2[l * (256L * 128) + (size_t)k * 128 + n];
    } else {
      int c = tid;
      float acc = 0.0f;
      for (int j = 0; j < 128; j++)
        acc += mb2[l * 128 + j] * uW1[l * 65536 + (size_t)(128 + j) * 256 + c];
      b2u[l * 256 + c] = acc;
    }
  } else if (bxf < NB_PREP + NB_HIST) {
    int e = (bxf - NB_PREP) * 256 + tid;
    atomicAdd(&counts[dstI[e]], 1);
  } else {
    int nb = bxf - (NB_PREP + NB_HIST);
    int hf = tid >> 7, j = tid & 127;
    int n = nb * 2 + hf;
    if (j < 26) xs[hf][j] = x[(size_t)n * 26 + j];
    __syncthreads();
    float acc = eb1[j];
    #pragma unroll
    for (int k = 0; k < 26; k++) acc += xs[hf][k] * eW1[k * 128 + j];
    hid[hf][j] = silu_f(acc);
    __syncthreads();
    float acc2 = eb2[j];
    #pragma unroll 8
    for (int k = 0; k < 128; k++) acc2 += hid[hf][k] * eW2[k * 128 + j];
    h[(size_t)n * 128 + j] = acc2;
    hb[(size_t)n * 128 + j] = (__bf16)acc2;
  }
}

// ---------------- zprep (layer 0 only): z1b, z2b; zeros aggH ----------------
__global__ __launch_bounds__(256) void zprep_kernel(
    const __bf16* __restrict__ hb, const float* __restrict__ b1,
    const __bf16* __restrict__ W1at, const __bf16* __restrict__ W1bt,
    __bf16* __restrict__ z1b, __bf16* __restrict__ z2b, float* __restrict__ aggH)
{
  __shared__ __bf16 s_n[64][136];
  int tid = threadIdx.x, n0 = blockIdx.x * 64;
  {
    int n = tid >> 2, t4 = tid & 3;
    const bf16x8* hr = (const bf16x8*)(hb + (size_t)(n0 + n) * 128);
    #pragma unroll
    for (int i = 0; i < 4; i++)
      *(bf16x8*)&s_n[n][t4 * 8 + 32 * i] = hr[t4 + 4 * i];
  }
  {
    float4 zz = make_float4(0.f, 0.f, 0.f, 0.f);
    float4* ap = (float4*)(aggH + (size_t)n0 * 256);
    for (int i = tid; i < 64 * 256 / 4; i += 256) ap[i] = zz;
  }
  __syncthreads();
  const int wv = tid >> 6, ln = tid & 63, lc = ln & 15, qd = ln >> 4;
  for (int cp = 0; cp < 2; cp++) {
    f32x4 aA[4][2], aB[4][2];
    #pragma unroll
    for (int nt = 0; nt < 2; nt++) {
      float bv = b1[cp * 128 + wv * 32 + nt * 16 + lc];
      #pragma unroll
      for (int mt = 0; mt < 4; mt++) {
        aA[mt][nt][0] = 0.f; aA[mt][nt][1] = 0.f;
        aA[mt][nt][2] = 0.f; aA[mt][nt][3] = 0.f;
        aB[mt][nt][0] = bv; aB[mt][nt][1] = bv;
        aB[mt][nt][2] = bv; aB[mt][nt][3] = bv;
      }
    }
    #pragma unroll
    for (int kt = 0; kt < 4; kt++) {
      bf16x8 af[4];
      #pragma unroll
      for (int mt = 0; mt < 4; mt++)
        af[mt] = *(const bf16x8*)&s_n[mt * 16 + lc][kt * 32 + qd * 8];
      bf16x8 bwA[2], bwB[2];
      #pragma unroll
      for (int nt = 0; nt < 2; nt++) {
        int c = cp * 128 + wv * 32 + nt * 16 + lc;
        bwA[nt] = *(const bf16x8*)(W1at + (size_t)c * 128 + kt * 32 + qd * 8);
        bwB[nt] = *(const bf16x8*)(W1bt + (size_t)c * 128 + kt * 32 + qd * 8);
      }
      #pragma unroll
      for (int mt = 0; mt < 4; mt++)
        #pragma unroll
        for (int nt = 0; nt < 2; nt++) {
          aA[mt][nt] = __builtin_amdgcn_mfma_f32_16x16x32_bf16(af[mt], bwA[nt], aA[mt][nt], 0, 0, 0);
          aB[mt][nt] = __builtin_amdgcn_mfma_f32_16x16x32_bf16(af[mt], bwB[nt], aB[mt][nt], 0, 0, 0);
        }
    }
    #pragma unroll
    for (int mt = 0; mt < 4; mt++)
      #pragma unroll
      for (int nt = 0; nt < 2; nt++) {
        int c = cp * 128 + wv * 32 + nt * 16 + lc;
        #pragma unroll
        for (int r = 0; r < 4; r++) {
          int n = n0 + mt * 16 + qd * 4 + r;
          z1b[(size_t)n * 256 + c] = (__bf16)aA[mt][nt][r];
          z2b[(size_t)n * 256 + c] = (__bf16)aB[mt][nt][r];
        }
      }
  }
}

// ---------------- fused message kernel v7 (round-12 scan, measured best) ----------------
#define MS_EF_OFF   33792                 // s_hT 256*66*2 = 33792
#define MS_SRC_OFF  36864                 // s_ef 64*24*2 = 3072
#define MS_DST_OFF  37120
#define MS_MASK_OFF 37376
#define MS_BYTES    37392

__global__ __launch_bounds__(256, 4) void msg_mfma_kernel(
    const __bf16* __restrict__ z1b, const __bf16* __restrict__ z2b,
    const __bf16* __restrict__ efb,
    const int* __restrict__ esrc, const int* __restrict__ edst,
    const __bf16* __restrict__ B2c, float* __restrict__ aggH)
{
  __shared__ __align__(16) char smem[MS_BYTES];
  __bf16 (*s_hT)[66] = (__bf16(*)[66])(smem);          // [256 cols][64 rows + 2 pad]
  __bf16 (*s_ef)[24] = (__bf16(*)[24])(smem + MS_EF_OFF);
  int* s_src = (int*)(smem + MS_SRC_OFF);
  int* s_dst = (int*)(smem + MS_DST_OFF);
  unsigned int* s_mask = (unsigned int*)(smem + MS_MASK_OFF);

  int tid = threadIdx.x, e0 = blockIdx.x * TE;

  if (tid < TE) {
    int d = edst[e0 + tid];
    s_dst[tid] = d;
    int dp = (tid == 0) ? (d ^ 1) : edst[e0 + tid - 1];
    unsigned long long mb = __ballot(d != dp);
    if (tid == 0) { s_mask[0] = (unsigned int)mb; s_mask[1] = (unsigned int)(mb >> 32); }
  } else if (tid < 2 * TE) {
    s_src[tid - TE] = esrc[e0 + tid - TE];
  }
  {
    int e = tid >> 2, t4 = tid & 3;
    if (t4 < 2)
      *(bf16x8*)&s_ef[e][t4 * 8] =
          *(const bf16x8*)(efb + (size_t)(e0 + e) * 16 + t4 * 8);
  }
  __syncthreads();

  const int wv = tid >> 6, ln = tid & 63, lc = ln & 15, qd = ln >> 4;

  bf16x8 bI;
  #pragma unroll
  for (int j = 0; j < 8; j++)
    bI[j] = (__bf16)((lc == (qd & 1) * 8 + j) ? 1.0f : 0.0f);

  const __bf16* pz[4];
  #pragma unroll
  for (int mt = 0; mt < 4; mt++) {
    int m = mt * 16 + lc;
    int row = (qd < 2) ? s_src[m] : s_dst[m];
    pz[mt] = ((qd < 2) ? z1b : z2b) + (size_t)row * 256 + (qd & 1) * 8;
  }

  // ---- compute both halves, no barrier between (disjoint s_hT cols) ----
  #pragma unroll
  for (int hf = 0; hf < 2; hf++) {
    const int cb = hf * 128 + wv * 32;
    bf16x8 bw[2];
    #pragma unroll
    for (int nt = 0; nt < 2; nt++)
      bw[nt] = *(const bf16x8*)(B2c + (size_t)(cb + nt * 16 + lc) * 32 + qd * 8);

    #pragma unroll
    for (int mt = 0; mt < 4; mt++) {
      bf16x8 aef = *(const bf16x8*)&s_ef[mt * 16 + lc][(qd & 1) * 8];
      #pragma unroll
      for (int nt = 0; nt < 2; nt++) {
        bf16x8 az = *(const bf16x8*)(pz[mt] + cb + nt * 16);
        f32x4 z; z[0] = 0.f; z[1] = 0.f; z[2] = 0.f; z[3] = 0.f;
        f32x4 acc = __builtin_amdgcn_mfma_f32_16x16x32_bf16(az, bI, z, 0, 0, 0);
        acc = __builtin_amdgcn_mfma_f32_16x16x32_bf16(aef, bw[nt], acc, 0, 0, 0);
        bf16x2 p0, p1;
        p0[0] = (__bf16)silu_f(acc[0]); p0[1] = (__bf16)silu_f(acc[1]);
        p1[0] = (__bf16)silu_f(acc[2]); p1[1] = (__bf16)silu_f(acc[3]);
        __bf16* wp = &s_hT[cb + nt * 16 + lc][mt * 16 + qd * 4];
        *(bf16x2*)wp = p0;
        *(bf16x2*)(wp + 2) = p1;
      }
    }
  }
  __syncthreads();

  // ---- one scan pass: 256 threads x 1 column x 64 rows ----
  {
    const unsigned int mlo = __builtin_amdgcn_readfirstlane(s_mask[0]);
    const unsigned int mhi = __builtin_amdgcn_readfirstlane(s_mask[1]);
    int j = tid;
    float acc = 0.0f;
    int cur = s_dst[0];
    #pragma unroll 8
    for (int i = 0; i < 64; i += 2) {
      bf16x2 p = *(const bf16x2*)&s_hT[j][i];
      bool b0 = (i < 32) ? ((mlo >> i) & 1u) : ((mhi >> (i - 32)) & 1u);
      int i1 = i + 1;
      bool b1 = (i1 < 32) ? ((mlo >> i1) & 1u) : ((mhi >> (i1 - 32)) & 1u);
      if (i > 0 && b0) {
        atomicAdd(&aggH[(size_t)cur * 256 + j], acc);
        acc = 0.0f; cur = s_dst[i];
      }
      acc += (float)p[0];
      if (b1) {
        atomicAdd(&aggH[(size_t)cur * 256 + j], acc);
        acc = 0.0f; cur = s_dst[i1];
      }
      acc += (float)p[1];
    }
    atomicAdd(&aggH[(size_t)cur * 256 + j], acc);
  }
}

// ---------------- fused node update MLP v4: 512 threads, 64 nodes + next-layer zprep ----------------
__global__ __launch_bounds__(512, 2) void upd_mfma_kernel(
    float* __restrict__ h, __bf16* __restrict__ hb,
    float* __restrict__ aggH, const float* __restrict__ degf,
    const __bf16* __restrict__ uW1ft, const float* __restrict__ b1,
    const float* __restrict__ b2u,
    const __bf16* __restrict__ uW2t, const float* __restrict__ b2,
    int do_z, const float* __restrict__ nb1,
    const __bf16* __restrict__ nW1at, const __bf16* __restrict__ nW1bt,
    __bf16* __restrict__ z1b, __bf16* __restrict__ z2b)
{
  __shared__ __bf16 s_u[64][392];    // [h(128) | agg(256)] + 8 pad
  __shared__ __bf16 s_uh[64][264];   // 256 hidden cols + 8 pad
  int tid = threadIdx.x, n0 = blockIdx.x * 64;
  {
    int n = tid >> 3, t8 = tid & 7;  // 8 threads per node
    const bf16x8* hr = (const bf16x8*)(hb + (size_t)(n0 + n) * 128);
    #pragma unroll
    for (int i = 0; i < 2; i++)
      *(bf16x8*)&s_u[n][t8 * 8 + 64 * i] = hr[t8 + 8 * i];
    const float* sr = aggH + (size_t)(n0 + n) * 256;
    #pragma unroll
    for (int i = 0; i < 4; i++) {
      int col = t8 * 8 + i * 64;
      float4 a = *(const float4*)(sr + col);
      float4 b = *(const float4*)(sr + col + 4);
      bf16x8 o;
      o[0] = (__bf16)a.x; o[1] = (__bf16)a.y; o[2] = (__bf16)a.z; o[3] = (__bf16)a.w;
      o[4] = (__bf16)b.x; o[5] = (__bf16)b.y; o[6] = (__bf16)b.z; o[7] = (__bf16)b.w;
      *(bf16x8*)&s_u[n][128 + col] = o;
    }
  }
  __syncthreads();
  const int wv = tid >> 6, ln = tid & 63, lc = ln & 15, qd = ln >> 4;  // wv 0..7

  float dg[4][4];
  #pragma unroll
  for (int mt = 0; mt < 4; mt++)
    #pragma unroll
    for (int r = 0; r < 4; r++)
      dg[mt][r] = degf[n0 + mt * 16 + qd * 4 + r];

  // ---- GEMM1: K=384, wave owns cols wv*32 + nt*16 + lc ----
  {
    f32x4 acc1[4][2];
    #pragma unroll
    for (int nt = 0; nt < 2; nt++) {
      int c = wv * 32 + nt * 16 + lc;
      float bv = b1[c];
      float b2uv = b2u[c];
      #pragma unroll
      for (int mt = 0; mt < 4; mt++)
        #pragma unroll
        for (int r = 0; r < 4; r++)
          acc1[mt][nt][r] = bv + dg[mt][r] * b2uv;
    }
    #pragma unroll
    for (int kt = 0; kt < 12; kt++) {
      bf16x8 af[4];
      #pragma unroll
      for (int mt = 0; mt < 4; mt++)
        af[mt] = *(const bf16x8*)&s_u[mt * 16 + lc][kt * 32 + qd * 8];
      bf16x8 bw[2];
      #pragma unroll
      for (int nt = 0; nt < 2; nt++)
        bw[nt] = *(const bf16x8*)(uW1ft +
                 (size_t)(wv * 32 + nt * 16 + lc) * 384 + kt * 32 + qd * 8);
      #pragma unroll
      for (int mt = 0; mt < 4; mt++)
        #pragma unroll
        for (int nt = 0; nt < 2; nt++)
          acc1[mt][nt] = __builtin_amdgcn_mfma_f32_16x16x32_bf16(af[mt], bw[nt], acc1[mt][nt], 0, 0, 0);
    }
    #pragma unroll
    for (int mt = 0; mt < 4; mt++)
      #pragma unroll
      for (int nt = 0; nt < 2; nt++) {
        int cc = wv * 32 + nt * 16 + lc;
        #pragma unroll
        for (int r = 0; r < 4; r++)
          s_uh[mt * 16 + qd * 4 + r][cc] = (__bf16)silu_f(acc1[mt][nt][r]);
      }
  }
  __syncthreads();

  // ---- GEMM2: K=256, wave owns output cols ow = wv*16 + lc ----
  const int ow = wv * 16 + lc;
  f32x4 acc2[4];
  {
    float bv = b2[ow];
    #pragma unroll
    for (int mt = 0; mt < 4; mt++) {
      acc2[mt][0] = bv; acc2[mt][1] = bv; acc2[mt][2] = bv; acc2[mt][3] = bv;
    }
  }
  #pragma unroll
  for (int kt = 0; kt < 8; kt++) {
    bf16x8 a2[4];
    #pragma unroll
    for (int mt = 0; mt < 4; mt++)
      a2[mt] = *(const bf16x8*)&s_uh[mt * 16 + lc][kt * 32 + qd * 8];
    bf16x8 b2w = *(const bf16x8*)(uW2t + (size_t)ow * 256 + kt * 32 + qd * 8);
    #pragma unroll
    for (int mt = 0; mt < 4; mt++)
      acc2[mt] = __builtin_amdgcn_mfma_f32_16x16x32_bf16(a2[mt], b2w, acc2[mt], 0, 0, 0);
  }

  // residual epilogue
  #pragma unroll
  for (int mt = 0; mt < 4; mt++)
    #pragma unroll
    for (int r = 0; r < 4; r++) {
      int n = n0 + mt * 16 + qd * 4 + r;
      float v = h[(size_t)n * 128 + ow] + acc2[mt][r];
      h[(size_t)n * 128 + ow] = v;
      hb[(size_t)n * 128 + ow] = (__bf16)v;
    }

  // ---- fused zprep for next layer ----
  if (do_z) {
    __syncthreads();
    {
      float4 zz = make_float4(0.f, 0.f, 0.f, 0.f);
      float4* ap = (float4*)(aggH + (size_t)n0 * 256);
      for (int i = tid; i < 64 * 256 / 4; i += 512) ap[i] = zz;
      int n = tid >> 3, t8 = tid & 7;
      const bf16x8* hr = (const bf16x8*)(hb + (size_t)(n0 + n) * 128);
      #pragma unroll
      for (int i = 0; i < 2; i++)
        *(bf16x8*)&s_u[n][t8 * 8 + 64 * i] = hr[t8 + 8 * i];
    }
    __syncthreads();
    f32x4 aA[4][2], aB[4][2];
    #pragma unroll
    for (int nt = 0; nt < 2; nt++) {
      float bv = nb1[wv * 32 + nt * 16 + lc];
      #pragma unroll
      for (int mt = 0; mt < 4; mt++) {
        aA[mt][nt][0] = 0.f; aA[mt][nt][1] = 0.f;
        aA[mt][nt][2] = 0.f; aA[mt][nt][3] = 0.f;
        aB[mt][nt][0] = bv; aB[mt][nt][1] = bv;
        aB[mt][nt][2] = bv; aB[mt][nt][3] = bv;
      }
    }
    #pragma unroll
    for (int kt = 0; kt < 4; kt++) {
      bf16x8 af[4];
      #pragma unroll
      for (int mt = 0; mt < 4; mt++)
        af[mt] = *(const bf16x8*)&s_u[mt * 16 + lc][kt * 32 + qd * 8];
      bf16x8 bwA[2], bwB[2];
      #pragma unroll
      for (int nt = 0; nt < 2; nt++) {
        int c = wv * 32 + nt * 16 + lc;
        bwA[nt] = *(const bf16x8*)(nW1at + (size_t)c * 128 + kt * 32 + qd * 8);
        bwB[nt] = *(const bf16x8*)(nW1bt + (size_t)c * 128 + kt * 32 + qd * 8);
      }
      #pragma unroll
      for (int mt = 0; mt < 4; mt++)
        #pragma unroll
        for (int nt = 0; nt < 2; nt++) {
          aA[mt][nt] = __builtin_amdgcn_mfma_f32_16x16x32_bf16(af[mt], bwA[nt], aA[mt][nt], 0, 0, 0);
          aB[mt][nt] = __builtin_amdgcn_mfma_f32_16x16x32_bf16(af[mt], bwB[nt], aB[mt][nt], 0, 0, 0);
        }
    }
    #pragma unroll
    for (int mt = 0; mt < 4; mt++)
      #pragma unroll
      for (int nt = 0; nt < 2; nt++) {
        int c = wv * 32 + nt * 16 + lc;
        #pragma unroll
        for (int r = 0; r < 4; r++) {
          int n = n0 + mt * 16 + qd * 4 + r;
          z1b[(size_t)n * 256 + c] = (__bf16)aA[mt][nt][r];
          z2b[(size_t)n * 256 + c] = (__bf16)aB[mt][nt][r];
        }
      }
  }
}

// ---------------- readout ----------------
__global__ __launch_bounds__(128) void readout_sum_kernel(
    const float* __restrict__ h, const int* __restrict__ batch,
    float* __restrict__ gsum, float* __restrict__ gcnt)
{
  int j = threadIdx.x;
  int n0 = blockIdx.x * 128;
  float acc = 0.f, cacc = 0.f;
  int cur = batch[n0];
  for (int i = 0; i < 128; i++) {
    int b = batch[n0 + i];
    if (b != cur) {
      atomicAdd(&gsum[cur * 128 + j], acc);
      if (j == 0) atomicAdd(&gcnt[cur], cacc);
      acc = 0.f; cacc = 0.f; cur = b;
    }
    acc += h[(size_t)(n0 + i) * 128 + j];
    cacc += 1.f;
  }
  atomicAdd(&gsum[cur * 128 + j], acc);
  if (j == 0) atomicAdd(&gcnt[cur], cacc);
}

__global__ __launch_bounds__(256) void readout_mlp_kernel(
    const float* __restrict__ gsum, const float* __restrict__ gcnt,
    const float* __restrict__ W1, const float* __restrict__ b1,
    const float* __restrict__ W2, const float* __restrict__ b2,
    float* __restrict__ out)
{
  __shared__ float g[8][128];
  __shared__ float hid[8][256];
  int tid = threadIdx.x;
  for (int i = tid; i < 8 * 128; i += 256) {
    int b = i >> 7, c = i & 127;
    g[b][c] = gsum[i] / fmaxf(gcnt[b], 1.0f);
  }
  __syncthreads();
  {
    float bb = b1[tid];
    float a[8];
    #pragma unroll
    for (int b = 0; b < 8; b++) a[b] = bb;
    for (int k = 0; k < 128; k++) {
      float w = W1[k * 256 + tid];
      #pragma unroll
      for (int b = 0; b < 8; b++) a[b] += g[b][k] * w;
    }
    #pragma unroll
    for (int b = 0; b < 8; b++) hid[b][tid] = silu_f(a[b]);
  }
  __syncthreads();
  int j = tid & 63, bg = tid >> 6;
  float a0 = b2[j], a1 = b2[j];
  for (int k = 0; k < 256; k++) {
    float w = W2[k * 64 + j];
    a0 += hid[bg * 2 + 0][k] * w;
    a1 += hid[bg * 2 + 1][k] * w;
  }
  out[(bg * 2 + 0) * 64 + j] = a0;
  out[(bg * 2 + 1) * 64 + j] = a1;
}

extern "C" void kernel_launch(void* const* d_in, const int* in_sizes, int n_in,
                              void* d_out, int out_size, void* d_ws, size_t ws_size,
                              hipStream_t stream) {
  const float* pos   = (const float*)d_in[0];
  const float* xfeat = (const float*)d_in[1];
  const int*   eidx  = (const int*)d_in[2];
  const int*   batch = (const int*)d_in[3];
  const float* eW1 = (const float*)d_in[4];
  const float* eb1 = (const float*)d_in[5];
  const float* eW2 = (const float*)d_in[6];
  const float* eb2 = (const float*)d_in[7];
  const float* mW1 = (const float*)d_in[8];
  const float* mb1 = (const float*)d_in[9];
  const float* mW2 = (const float*)d_in[10];
  const float* mb2 = (const float*)d_in[11];
  const float* uW1 = (const float*)d_in[12];
  const float* ub1 = (const float*)d_in[13];
  const float* uW2 = (const float*)d_in[14];
  const float* ub2 = (const float*)d_in[15];
  const float* rW1 = (const float*)d_in[16];
  const float* rb1 = (const float*)d_in[17];
  const float* rW2 = (const float*)d_in[18];
  const float* rb2 = (const float*)d_in[19];

  const int* srcI = eidx;
  const int* dstI = eidx + NEDGES;

  char* base = (char*)d_ws;
  float* h    = (float*)base;  base += (size_t)NATOMS * 128 * 4;
  float* aggH = (float*)base;  base += (size_t)NATOMS * 256 * 4;
  __bf16* z1b = (__bf16*)base; base += (size_t)NATOMS * 256 * 2;
  __bf16* z2b = (__bf16*)base; base += (size_t)NATOMS * 256 * 2;
  __bf16* hb  = (__bf16*)base; base += (size_t)NATOMS * 128 * 2;
  __bf16* efb = (__bf16*)base; base += (size_t)NEDGES * 16 * 2;
  __bf16* W1at = (__bf16*)base; base += (size_t)NLAYERS * 256 * 128 * 2;
  __bf16* W1bt = (__bf16*)base; base += (size_t)NLAYERS * 256 * 128 * 2;
  __bf16* B2c  = (__bf16*)base; base += (size_t)NLAYERS * 256 * 32 * 2;
  __bf16* uW1ft = (__bf16*)base; base += (size_t)NLAYERS * 256 * 384 * 2;
  __bf16* uW2t = (__bf16*)base; base += (size_t)NLAYERS * 128 * 256 * 2;
  float* b2u  = (float*)base;  base += (size_t)NLAYERS * 256 * 4;
  float* degf = (float*)base;  base += (size_t)NATOMS * 4;
  float* gsum = (float*)base;  base += 8 * 128 * 4;
  float* gcnt = (float*)base;  base += 8 * 4;
  int* counts = (int*)base;    base += (size_t)NATOMS * 4;
  int* cursor = (int*)base;    base += (size_t)NATOMS * 4;
  int* esrc   = (int*)base;    base += (size_t)NEDGES * 4;
  int* edst   = (int*)base;    base += (size_t)NEDGES * 4;

  // counts must be zeroed before front_kernel's hist section
  hipMemsetAsync(counts, 0, NATOMS * sizeof(int), stream);

  // merged front: weight prep + dst histogram + embedding
  front_kernel<<<NB_PREP + NB_HIST + NB_EMB, 256, 0, stream>>>(
      mW1, mW2, uW1, uW2, mb2, W1at, W1bt, B2c, uW1ft, uW2t, b2u,
      dstI, counts, xfeat, eW1, eb1, eW2, eb2, h, hb);

  scan_kernel<<<1, 1024, 0, stream>>>(counts, cursor, degf);
  scatter_rbf_kernel<<<NEDGES / 256, 256, 0, stream>>>(
      srcI, dstI, cursor, pos, esrc, edst, efb);

  // zprep for layer 0 (also zeros aggH)
  zprep_kernel<<<NATOMS / 64, 256, 0, stream>>>(
      hb, mb1, W1at, W1bt, z1b, z2b, aggH);

  for (int l = 0; l < NLAYERS; l++) {
    int ln = (l < NLAYERS - 1) ? (l + 1) : l;
    msg_mfma_kernel<<<NEDGES / TE, 256, 0, stream>>>(
        z1b, z2b, efb, esrc, edst,
        B2c + (size_t)l * 256 * 32, aggH);
    upd_mfma_kernel<<<NATOMS / 64, 512, 0, stream>>>(
        h, hb, aggH, degf,
        uW1ft + (size_t)l * 256 * 384, ub1 + (size_t)l * 256,
        b2u + (size_t)l * 256,
        uW2t + (size_t)l * 128 * 256, ub2 + (size_t)l * 128,
        (l < NLAYERS - 1) ? 1 : 0,
        mb1 + (size_t)ln * 256,
        W1at + (size_t)ln * 256 * 128, W1bt + (size_t)ln * 256 * 128,
        z1b, z2b);
  }

  hipMemsetAsync(gsum, 0, (8 * 128 + 8) * sizeof(float), stream);
  readout_sum_kernel<<<NATOMS / 128, 128, 0, stream>>>(h, batch, gsum, gcnt);
  readout_mlp_kernel<<<1, 256, 0, stream>>>(gsum, gcnt, rW1, rb1, rW2, rb2,
                                            (float*)d_out);
}